// Round 4
// baseline (2903.444 us; speedup 1.0000x reference)
//
#include <hip/hip_runtime.h>

#define TT 128
#define NB 64
#define NSZ 32
#define MSZ 8
#define PSZ 16
#define LD 36
#define LDC 20

__device__ __forceinline__ void fma4(float4& a, float s, const float4 v){
  a.x = fmaf(s, v.x, a.x);
  a.y = fmaf(s, v.y, a.y);
  a.z = fmaf(s, v.z, a.z);
  a.w = fmaf(s, v.w, a.w);
}
__device__ __forceinline__ float frcp(float x){ return __builtin_amdgcn_rcpf(x); }

// ===== Forward Kalman filter: 1 WAVE handles TWO batches (ILP x2), no barriers =====
__global__ __launch_bounds__(64) void kf_forward(
    const float* __restrict__ Yg, const float* __restrict__ Ug,
    const float* __restrict__ Ag, const float* __restrict__ Bg,
    const float* __restrict__ Cg, const float* __restrict__ mu0g,
    const float* __restrict__ Sig0g,
    float* __restrict__ outg, float* __restrict__ wsSig, float* __restrict__ wsMu)
{
  const int l = threadIdx.x;
  const int rt = l >> 3, ct = l & 7;
  const int r0 = rt << 2, c0 = ct << 2;     // 4x4 tile for 32x32 outputs
  const int rt2 = l >> 3;                   // rows 2*rt2,2*rt2+1 for 16-row outputs
  const int rp = l >> 3, cp = l & 7;        // 2x2 tile for 16x16 S
  const int row = l & 15, g = l >> 4;       // GJ mapping
  const int rA = l >> 1, cA = (l & 1) << 4; // A/Sig load: half-row per lane
  const int rC = l >> 2, cC = (l & 3) << 3; // C load: quarter-row per lane
  const int rB = l >> 1, cB = (l & 1) << 2; // B load

  __shared__ float SigL [2][NSZ][LD];
  __shared__ float ATs  [2][NSZ][LD];
  __shared__ float T1T  [2][NSZ][LD];
  __shared__ float SigpL[2][NSZ][LD];
  __shared__ float CT   [2][NSZ][LDC];
  __shared__ float CST  [2][NSZ][LDC];
  __shared__ float CSL  [2][PSZ][LD];
  __shared__ float KtL  [2][PSZ][LD];
  __shared__ float SL   [2][PSZ][LDC];
  __shared__ float BsL  [2][NSZ][12];
  __shared__ float muv[2][NSZ], mupv[2][NSZ], rv[2][PSZ], yv[2][PSZ], uvv[2][MSZ];

  size_t btb[2];
  btb[0] = (size_t)(blockIdx.x*2 + 0) * TT;
  btb[1] = (size_t)(blockIdx.x*2 + 1) * TT;

  // ---- init: Sigma0, mu0, t=0 inputs for both batches ----
  #pragma unroll
  for (int bb = 0; bb < 2; ++bb){
    const size_t q0 = btb[bb];
    #pragma unroll
    for (int q = 0; q < 4; ++q)
      *(float4*)&SigL[bb][rA][cA + 4*q] = *(const float4*)(Sig0g + rA*32 + cA + 4*q);
    if (l < 32) muv[bb][l] = mu0g[l];
    #pragma unroll
    for (int q = 0; q < 4; ++q){
      float4 v = *(const float4*)(Ag + q0*1024 + rA*32 + cA + 4*q);
      ATs[bb][cA+4*q+0][rA]=v.x; ATs[bb][cA+4*q+1][rA]=v.y;
      ATs[bb][cA+4*q+2][rA]=v.z; ATs[bb][cA+4*q+3][rA]=v.w;
    }
    #pragma unroll
    for (int q = 0; q < 2; ++q){
      float4 v = *(const float4*)(Cg + q0*512 + rC*32 + cC + 4*q);
      CT[bb][cC+4*q+0][rC]=v.x; CT[bb][cC+4*q+1][rC]=v.y;
      CT[bb][cC+4*q+2][rC]=v.z; CT[bb][cC+4*q+3][rC]=v.w;
    }
    *(float4*)&BsL[bb][rB][cB] = *(const float4*)(Bg + q0*256 + rB*8 + cB);
    if (l < 16) yv[bb][l] = Yg[q0*16 + l];
    if (l < 8)  uvv[bb][l] = Ug[q0*8 + l];
  }

  float4 sp[2][4];

  for (int t = 0; t < TT; ++t) {
    // ---- Phase 1: T1 = A*Sig (store transposed) ; mu_p = A*mu + B*u ----
    #pragma unroll
    for (int bb = 0; bb < 2; ++bb){
      float4 t0=make_float4(0.f,0.f,0.f,0.f), t1=t0, t2=t0, t3=t0;
      #pragma unroll
      for (int k=0;k<32;++k){
        float4 a = *(const float4*)&ATs[bb][k][r0];   // A[r0+i][k]
        float4 s = *(const float4*)&SigL[bb][k][c0];  // Sig[k][c0+j]
        fma4(t0,a.x,s); fma4(t1,a.y,s); fma4(t2,a.z,s); fma4(t3,a.w,s);
      }
      T1T[bb][c0+0][r0+0]=t0.x; T1T[bb][c0+1][r0+0]=t0.y; T1T[bb][c0+2][r0+0]=t0.z; T1T[bb][c0+3][r0+0]=t0.w;
      T1T[bb][c0+0][r0+1]=t1.x; T1T[bb][c0+1][r0+1]=t1.y; T1T[bb][c0+2][r0+1]=t1.z; T1T[bb][c0+3][r0+1]=t1.w;
      T1T[bb][c0+0][r0+2]=t2.x; T1T[bb][c0+1][r0+2]=t2.y; T1T[bb][c0+2][r0+2]=t2.z; T1T[bb][c0+3][r0+2]=t2.w;
      T1T[bb][c0+0][r0+3]=t3.x; T1T[bb][c0+1][r0+3]=t3.y; T1T[bb][c0+2][r0+3]=t3.z; T1T[bb][c0+3][r0+3]=t3.w;
      if (l < 32){
        float m = 0.f;
        #pragma unroll
        for (int k=0;k<32;++k) m = fmaf(ATs[bb][k][l], muv[bb][k], m);
        #pragma unroll
        for (int k=0;k<8;++k)  m = fmaf(BsL[bb][l][k], uvv[bb][k], m);
        mupv[bb][l] = m;
      }
    }

    // ---- Phase 2: Sig_p = T1*A^T + Q ; keep in regs ; store LDS + workspace ----
    #pragma unroll
    for (int bb = 0; bb < 2; ++bb){
      float4 a0=make_float4(0.f,0.f,0.f,0.f), a1=a0, a2=a0, a3=a0;
      #pragma unroll
      for (int k=0;k<32;++k){
        float4 tv = *(const float4*)&T1T[bb][k][r0];  // T1[r0+i][k]
        float4 av = *(const float4*)&ATs[bb][k][c0];  // A[c0+j][k]
        fma4(a0,tv.x,av); fma4(a1,tv.y,av); fma4(a2,tv.z,av); fma4(a3,tv.w,av);
      }
      if (rt == ct){ a0.x += 0.01f; a1.y += 0.01f; a2.z += 0.01f; a3.w += 0.01f; }
      sp[bb][0]=a0; sp[bb][1]=a1; sp[bb][2]=a2; sp[bb][3]=a3;
      *(float4*)&SigpL[bb][r0+0][c0]=a0; *(float4*)&SigpL[bb][r0+1][c0]=a1;
      *(float4*)&SigpL[bb][r0+2][c0]=a2; *(float4*)&SigpL[bb][r0+3][c0]=a3;
      float* wp = wsSig + ((btb[bb]+t)*32 + r0)*32 + c0;
      *(float4*)(wp)    = a0; *(float4*)(wp+32) = a1;
      *(float4*)(wp+64) = a2; *(float4*)(wp+96) = a3;
      if (l < 32) wsMu[(btb[bb]+t)*32 + l] = mupv[bb][l];
    }

    // ---- Phase 3: CS = C*Sig_p ; r = y - C*mu_p ----
    #pragma unroll
    for (int bb = 0; bb < 2; ++bb){
      float4 cs0=make_float4(0.f,0.f,0.f,0.f), cs1=cs0;
      #pragma unroll
      for (int k=0;k<32;++k){
        float2 cc = *(const float2*)&CT[bb][k][2*rt2];  // C[2rt2+i][k]
        float4 s  = *(const float4*)&SigpL[bb][k][c0];
        fma4(cs0,cc.x,s); fma4(cs1,cc.y,s);
      }
      *(float4*)&CSL[bb][2*rt2+0][c0] = cs0;
      *(float4*)&CSL[bb][2*rt2+1][c0] = cs1;
      *(float2*)&CST[bb][c0+0][2*rt2] = make_float2(cs0.x, cs1.x);
      *(float2*)&CST[bb][c0+1][2*rt2] = make_float2(cs0.y, cs1.y);
      *(float2*)&CST[bb][c0+2][2*rt2] = make_float2(cs0.z, cs1.z);
      *(float2*)&CST[bb][c0+3][2*rt2] = make_float2(cs0.w, cs1.w);
      if (l < 16){
        float r = yv[bb][l];
        #pragma unroll
        for (int k=0;k<32;++k) r = fmaf(-CT[bb][k][l], mupv[bb][k], r);
        rv[bb][l] = r;
      }
    }

    // ---- Phase 4: S = CS*C^T + R (16x16, 2x2 tiles) ----
    #pragma unroll
    for (int bb = 0; bb < 2; ++bb){
      float sa=0.f, sb=0.f, sc=0.f, sd=0.f;
      #pragma unroll
      for (int k=0;k<32;++k){
        float2 a = *(const float2*)&CST[bb][k][2*rp];  // CS[2rp+i][k]
        float2 c = *(const float2*)&CT [bb][k][2*cp];  // C[2cp+j][k]
        sa=fmaf(a.x,c.x,sa); sb=fmaf(a.x,c.y,sb);
        sc=fmaf(a.y,c.x,sc); sd=fmaf(a.y,c.y,sd);
      }
      if (rp == cp){ sa += 0.01f; sd += 0.01f; }
      SL[bb][2*rp+0][2*cp+0]=sa; SL[bb][2*rp+0][2*cp+1]=sb;
      SL[bb][2*rp+1][2*cp+0]=sc; SL[bb][2*rp+1][2*cp+1]=sd;
    }

    // ---- Phase 5: register Gauss-Jordan on [sym(S) | CS] (16x48), shuffles only ----
    #pragma unroll
    for (int bb = 0; bb < 2; ++bb){
      float aug[16];
      if (g == 0){
        float tmp[16];
        #pragma unroll
        for (int q=0;q<4;++q){
          float4 v = *(const float4*)&SL[bb][row][4*q];
          tmp[4*q]=v.x; tmp[4*q+1]=v.y; tmp[4*q+2]=v.z; tmp[4*q+3]=v.w;
        }
        #pragma unroll
        for (int c2=0;c2<16;++c2) aug[c2] = 0.5f*(tmp[c2] + SL[bb][c2][row]);
      } else if (g <= 2){
        #pragma unroll
        for (int q=0;q<4;++q){
          float4 v = *(const float4*)&CSL[bb][row][(g-1)*16 + 4*q];
          aug[4*q]=v.x; aug[4*q+1]=v.y; aug[4*q+2]=v.z; aug[4*q+3]=v.w;
        }
      } else {
        #pragma unroll
        for (int c2=0;c2<16;++c2) aug[c2] = 0.f;
      }
      const int psrc = g << 4;
      #pragma unroll
      for (int k=0;k<16;++k){
        float f   = __shfl(aug[k], row);
        float piv = __shfl(aug[k], k);
        float prc = frcp(piv);
        float pr[16];
        #pragma unroll
        for (int c2=0;c2<16;++c2) pr[c2] = __shfl(aug[c2], k + psrc);
        float fn = f * prc;
        #pragma unroll
        for (int c2=0;c2<16;++c2){
          float upd = fmaf(-fn, pr[c2], aug[c2]);
          aug[c2] = (row == k) ? aug[c2]*prc : upd;
        }
      }
      if (g == 1){
        #pragma unroll
        for (int q=0;q<4;++q)
          *(float4*)&KtL[bb][row][4*q] = make_float4(aug[4*q],aug[4*q+1],aug[4*q+2],aug[4*q+3]);
      } else if (g == 2){
        #pragma unroll
        for (int q=0;q<4;++q)
          *(float4*)&KtL[bb][row][16+4*q] = make_float4(aug[4*q],aug[4*q+1],aug[4*q+2],aug[4*q+3]);
      }
    }

    // ---- prefetch next-step inputs (issued here; latency covered by Phase 6) ----
    float4 pa[2][4], pc[2][2], pb[2]; float py[2], pu[2];
    if (t + 1 < TT) {
      #pragma unroll
      for (int bb = 0; bb < 2; ++bb){
        const size_t q1 = btb[bb] + t + 1;
        #pragma unroll
        for (int q=0;q<4;++q) pa[bb][q] = *(const float4*)(Ag + q1*1024 + rA*32 + cA + 4*q);
        #pragma unroll
        for (int q=0;q<2;++q) pc[bb][q] = *(const float4*)(Cg + q1*512 + rC*32 + cC + 4*q);
        pb[bb] = *(const float4*)(Bg + q1*256 + rB*8 + cB);
        py[bb] = (l < 16) ? Yg[q1*16 + l] : 0.f;
        pu[bb] = (l < 8)  ? Ug[q1*8 + l]  : 0.f;
      }
    } else {
      #pragma unroll
      for (int bb = 0; bb < 2; ++bb){
        pa[bb][0]=pa[bb][1]=pa[bb][2]=pa[bb][3]=make_float4(0.f,0.f,0.f,0.f);
        pc[bb][0]=pc[bb][1]=make_float4(0.f,0.f,0.f,0.f);
        pb[bb]=make_float4(0.f,0.f,0.f,0.f); py[bb]=0.f; pu[bb]=0.f;
      }
    }

    // ---- Phase 6: Sig_f = sym(Sig_p - K*CS) ; mu_f ; outputs ----
    #pragma unroll
    for (int bb = 0; bb < 2; ++bb){
      float4 f0=sp[bb][0], f1=sp[bb][1], f2=sp[bb][2], f3=sp[bb][3];
      #pragma unroll
      for (int p=0;p<16;++p){
        float4 kt = *(const float4*)&KtL[bb][p][r0];  // K[r0+i][p]
        float4 cs = *(const float4*)&CSL[bb][p][c0];  // CS[p][c0+j]
        fma4(f0,-kt.x,cs); fma4(f1,-kt.y,cs); fma4(f2,-kt.z,cs); fma4(f3,-kt.w,cs);
      }
      *(float4*)&T1T[bb][r0+0][c0]=f0; *(float4*)&T1T[bb][r0+1][c0]=f1;
      *(float4*)&T1T[bb][r0+2][c0]=f2; *(float4*)&T1T[bb][r0+3][c0]=f3;
      float4 w0,w1,w2,w3;
      w0.x=0.5f*(f0.x+T1T[bb][c0+0][r0+0]); w0.y=0.5f*(f0.y+T1T[bb][c0+1][r0+0]);
      w0.z=0.5f*(f0.z+T1T[bb][c0+2][r0+0]); w0.w=0.5f*(f0.w+T1T[bb][c0+3][r0+0]);
      w1.x=0.5f*(f1.x+T1T[bb][c0+0][r0+1]); w1.y=0.5f*(f1.y+T1T[bb][c0+1][r0+1]);
      w1.z=0.5f*(f1.z+T1T[bb][c0+2][r0+1]); w1.w=0.5f*(f1.w+T1T[bb][c0+3][r0+1]);
      w2.x=0.5f*(f2.x+T1T[bb][c0+0][r0+2]); w2.y=0.5f*(f2.y+T1T[bb][c0+1][r0+2]);
      w2.z=0.5f*(f2.z+T1T[bb][c0+2][r0+2]); w2.w=0.5f*(f2.w+T1T[bb][c0+3][r0+2]);
      w3.x=0.5f*(f3.x+T1T[bb][c0+0][r0+3]); w3.y=0.5f*(f3.y+T1T[bb][c0+1][r0+3]);
      w3.z=0.5f*(f3.z+T1T[bb][c0+2][r0+3]); w3.w=0.5f*(f3.w+T1T[bb][c0+3][r0+3]);
      *(float4*)&SigL[bb][r0+0][c0]=w0; *(float4*)&SigL[bb][r0+1][c0]=w1;
      *(float4*)&SigL[bb][r0+2][c0]=w2; *(float4*)&SigL[bb][r0+3][c0]=w3;
      float* op = outg + ((btb[bb]+t)*32 + r0)*33 + 1 + c0;
      op[0]=w0.x; op[1]=w0.y; op[2]=w0.z; op[3]=w0.w; op+=33;
      op[0]=w1.x; op[1]=w1.y; op[2]=w1.z; op[3]=w1.w; op+=33;
      op[0]=w2.x; op[1]=w2.y; op[2]=w2.z; op[3]=w2.w; op+=33;
      op[0]=w3.x; op[1]=w3.y; op[2]=w3.z; op[3]=w3.w;
      if (l < 32){
        float m = mupv[bb][l];
        #pragma unroll
        for (int p=0;p<16;++p) m = fmaf(KtL[bb][p][l], rv[bb][p], m);
        muv[bb][l] = m;
        outg[((btb[bb]+t)*32 + l)*33] = m;
      }
    }

    // ---- Phase 7: stage next-step inputs into LDS ----
    if (t + 1 < TT){
      #pragma unroll
      for (int bb = 0; bb < 2; ++bb){
        #pragma unroll
        for (int q=0;q<4;++q){
          float4 v = pa[bb][q];
          ATs[bb][cA+4*q+0][rA]=v.x; ATs[bb][cA+4*q+1][rA]=v.y;
          ATs[bb][cA+4*q+2][rA]=v.z; ATs[bb][cA+4*q+3][rA]=v.w;
        }
        #pragma unroll
        for (int q=0;q<2;++q){
          float4 v = pc[bb][q];
          CT[bb][cC+4*q+0][rC]=v.x; CT[bb][cC+4*q+1][rC]=v.y;
          CT[bb][cC+4*q+2][rC]=v.z; CT[bb][cC+4*q+3][rC]=v.w;
        }
        *(float4*)&BsL[bb][rB][cB] = pb[bb];
        if (l < 16) yv[bb][l] = py[bb];
        if (l < 8)  uvv[bb][l] = pu[bb];
      }
    }
  }
}

// ------- Parallel smoother precompute: J_t, E_t, e_t for t=0..T-2 (unchanged) -------
__global__ __launch_bounds__(256) void kf_precomp(
    const float* __restrict__ Ag, float* __restrict__ outg,
    float* __restrict__ wsSig, float* __restrict__ wsMu)
{
  const int t = blockIdx.x;
  const int b = blockIdx.y;
  const int tid = threadIdx.x;
  const int i32 = tid >> 3;
  const int j4 = (tid & 7) << 2;
  __shared__ __align__(16) float Sf[NSZ][LD];
  __shared__ __align__(16) float AT2[NSZ][LD];
  __shared__ __align__(16) float Mm[NSZ][LD];
  __shared__ __align__(16) float Pm[NSZ][LD];
  __shared__ __align__(16) float V[NSZ][LD];
  __shared__ __align__(16) float Jl[NSZ][LD];
  __shared__ __align__(16) float JTs[NSZ][LD];
  __shared__ __align__(16) float prow[NSZ];
  __shared__ __align__(16) float vrow[NSZ];
  __shared__ float mfv[NSZ], mp1[NSZ];
  const size_t bt = (size_t)b*TT + t;
  {
    const float* os = outg + bt*NSZ*(NSZ+1);
    #pragma unroll
    for (int r = 0; r < 4; ++r) {
      int e = tid + 256*r; int i = e >> 5, j = e & 31;
      Sf[i][j] = os[i*(NSZ+1) + 1 + j];
    }
    if (tid < NSZ) mfv[tid] = os[tid*(NSZ+1)];
    float4 a4 = *(const float4*)(Ag + bt*(NSZ*NSZ) + tid*4);
    AT2[j4+0][i32]=a4.x; AT2[j4+1][i32]=a4.y; AT2[j4+2][i32]=a4.z; AT2[j4+3][i32]=a4.w;
    *(float4*)&Pm[i32][j4] = *(const float4*)(wsSig + ((bt+1)*NSZ + i32)*NSZ + j4);
    if (tid < NSZ) mp1[tid] = wsMu[(bt+1)*NSZ + tid];
    float4 vi;
    vi.x = (i32 == j4+0) ? 1.f : 0.f;
    vi.y = (i32 == j4+1) ? 1.f : 0.f;
    vi.z = (i32 == j4+2) ? 1.f : 0.f;
    vi.w = (i32 == j4+3) ? 1.f : 0.f;
    *(float4*)&V[i32][j4] = vi;
  }
  __syncthreads();
  {
    float4 acc = make_float4(0.f,0.f,0.f,0.f);
    #pragma unroll
    for (int k0 = 0; k0 < NSZ; k0 += 4) {
      float4 s = *(const float4*)&Sf[i32][k0];
      fma4(acc, s.x, *(const float4*)&AT2[k0+0][j4]);
      fma4(acc, s.y, *(const float4*)&AT2[k0+1][j4]);
      fma4(acc, s.z, *(const float4*)&AT2[k0+2][j4]);
      fma4(acc, s.w, *(const float4*)&AT2[k0+3][j4]);
    }
    *(float4*)&Mm[i32][j4] = acc;
  }
  __syncthreads();
  for (int k = 0; k < NSZ; ++k) {
    float f = Pm[i32][k];
    if (tid < 8) {
      float rd = frcp(Pm[k][k]);
      #pragma unroll
      for (int m = 0; m < 4; ++m) prow[tid*4+m] = Pm[k][tid*4+m] * rd;
    } else if (tid < 16) {
      float rd = frcp(Pm[k][k]);
      const int c0 = (tid-8)*4;
      #pragma unroll
      for (int m = 0; m < 4; ++m) vrow[c0+m] = V[k][c0+m] * rd;
    }
    __syncthreads();
    if (i32 == k) {
      *(float4*)&Pm[k][j4] = *(const float4*)&prow[j4];
      *(float4*)&V[k][j4] = *(const float4*)&vrow[j4];
    } else {
      float4 p = *(const float4*)&Pm[i32][j4];
      float4 v = *(const float4*)&V[i32][j4];
      fma4(p, -f, *(const float4*)&prow[j4]);
      fma4(v, -f, *(const float4*)&vrow[j4]);
      *(float4*)&Pm[i32][j4] = p;
      *(float4*)&V[i32][j4] = v;
    }
    __syncthreads();
  }
  {
    float4 acc = make_float4(0.f,0.f,0.f,0.f);
    #pragma unroll
    for (int k0 = 0; k0 < NSZ; k0 += 4) {
      float4 m4 = *(const float4*)&Mm[i32][k0];
      fma4(acc, m4.x, *(const float4*)&V[k0+0][j4]);
      fma4(acc, m4.y, *(const float4*)&V[k0+1][j4]);
      fma4(acc, m4.z, *(const float4*)&V[k0+2][j4]);
      fma4(acc, m4.w, *(const float4*)&V[k0+3][j4]);
    }
    *(float4*)&Jl[i32][j4] = acc;
    JTs[j4+0][i32]=acc.x; JTs[j4+1][i32]=acc.y; JTs[j4+2][i32]=acc.z; JTs[j4+3][i32]=acc.w;
    *(float4*)(wsSig + ((bt+1)*NSZ + i32)*NSZ + j4) = acc;
  }
  __syncthreads();
  {
    float4 acc = make_float4(0.f,0.f,0.f,0.f);
    #pragma unroll
    for (int k0 = 0; k0 < NSZ; k0 += 4) {
      float4 m4 = *(const float4*)&Mm[i32][k0];
      fma4(acc, m4.x, *(const float4*)&JTs[k0+0][j4]);
      fma4(acc, m4.y, *(const float4*)&JTs[k0+1][j4]);
      fma4(acc, m4.z, *(const float4*)&JTs[k0+2][j4]);
      fma4(acc, m4.w, *(const float4*)&JTs[k0+3][j4]);
    }
    float* os = outg + bt*NSZ*(NSZ+1);
    os[i32*(NSZ+1)+1+j4+0] = Sf[i32][j4+0] - acc.x;
    os[i32*(NSZ+1)+1+j4+1] = Sf[i32][j4+1] - acc.y;
    os[i32*(NSZ+1)+1+j4+2] = Sf[i32][j4+2] - acc.z;
    os[i32*(NSZ+1)+1+j4+3] = Sf[i32][j4+3] - acc.w;
    if (tid < NSZ) {
      float e2 = mfv[tid];
      #pragma unroll
      for (int k = 0; k < NSZ; ++k) e2 = fmaf(-Jl[tid][k], mp1[k], e2);
      os[tid*(NSZ+1)] = e2;
    }
  }
}

// ===== Backward smoother: 1 WAVE handles TWO batches (ILP x2), no barriers =====
__global__ __launch_bounds__(64) void kf_backward(
    float* __restrict__ outg, const float* __restrict__ wsSig)
{
  const int l = threadIdx.x;
  const int rt = l >> 3, ct = l & 7;
  const int r0 = rt << 2, c0 = ct << 2;
  const int rA = l >> 1, cA = (l & 1) << 4;
  __shared__ float SigsL[2][NSZ][LD];
  __shared__ float JT [2][NSZ][LD];
  __shared__ float WT [2][NSZ][LD];
  __shared__ float Tt [2][NSZ][LD];
  __shared__ float muv[2][NSZ], evv[2][NSZ];
  size_t base[2];
  base[0] = (size_t)(blockIdx.x*2 + 0) * TT;
  base[1] = (size_t)(blockIdx.x*2 + 1) * TT;

  float er[2][4][4];
  #pragma unroll
  for (int bb = 0; bb < 2; ++bb){
    const float* os = outg + (base[bb] + TT - 1)*32*33;
    #pragma unroll
    for (int c = 0; c < 16; ++c) SigsL[bb][rA][cA + c] = os[rA*33 + 1 + cA + c];
    if (l < 32) muv[bb][l] = os[l*33];
    #pragma unroll
    for (int q = 0; q < 4; ++q){
      float4 v = *(const float4*)(wsSig + ((base[bb] + TT - 1)*32 + rA)*32 + cA + 4*q);
      JT[bb][cA+4*q+0][rA]=v.x; JT[bb][cA+4*q+1][rA]=v.y;
      JT[bb][cA+4*q+2][rA]=v.z; JT[bb][cA+4*q+3][rA]=v.w;
    }
    const float* oe = outg + (base[bb] + TT - 2)*32*33;
    #pragma unroll
    for (int i=0;i<4;++i)
      #pragma unroll
      for (int j=0;j<4;++j) er[bb][i][j] = oe[(r0+i)*33 + 1 + c0 + j];
    if (l < 32) evv[bb][l] = oe[l*33];
  }

  for (int t = TT - 2; t >= 0; --t) {
    // prefetch next iteration's J and E/e of t-1
    float4 pj[2][4]; float ne[2][4][4]; float nev[2];
    if (t > 0) {
      #pragma unroll
      for (int bb = 0; bb < 2; ++bb){
        #pragma unroll
        for (int q=0;q<4;++q)
          pj[bb][q] = *(const float4*)(wsSig + ((base[bb] + t)*32 + rA)*32 + cA + 4*q);
        const float* oe = outg + (base[bb] + t - 1)*32*33;
        #pragma unroll
        for (int i=0;i<4;++i)
          #pragma unroll
          for (int j=0;j<4;++j) ne[bb][i][j] = oe[(r0+i)*33 + 1 + c0 + j];
        nev[bb] = (l < 32) ? oe[l*33] : 0.f;
      }
    } else {
      #pragma unroll
      for (int bb = 0; bb < 2; ++bb){
        pj[bb][0]=pj[bb][1]=pj[bb][2]=pj[bb][3]=make_float4(0.f,0.f,0.f,0.f);
        #pragma unroll
        for (int i=0;i<4;++i)
          #pragma unroll
          for (int j=0;j<4;++j) ne[bb][i][j] = 0.f;
        nev[bb] = 0.f;
      }
    }

    // W = J * Sigs (store transposed)
    #pragma unroll
    for (int bb = 0; bb < 2; ++bb){
      float4 w0=make_float4(0.f,0.f,0.f,0.f), w1=w0, w2=w0, w3=w0;
      #pragma unroll
      for (int k=0;k<32;++k){
        float4 jv = *(const float4*)&JT[bb][k][r0];
        float4 sv = *(const float4*)&SigsL[bb][k][c0];
        fma4(w0,jv.x,sv); fma4(w1,jv.y,sv); fma4(w2,jv.z,sv); fma4(w3,jv.w,sv);
      }
      WT[bb][c0+0][r0+0]=w0.x; WT[bb][c0+1][r0+0]=w0.y; WT[bb][c0+2][r0+0]=w0.z; WT[bb][c0+3][r0+0]=w0.w;
      WT[bb][c0+0][r0+1]=w1.x; WT[bb][c0+1][r0+1]=w1.y; WT[bb][c0+2][r0+1]=w1.z; WT[bb][c0+3][r0+1]=w1.w;
      WT[bb][c0+0][r0+2]=w2.x; WT[bb][c0+1][r0+2]=w2.y; WT[bb][c0+2][r0+2]=w2.z; WT[bb][c0+3][r0+2]=w2.w;
      WT[bb][c0+0][r0+3]=w3.x; WT[bb][c0+1][r0+3]=w3.y; WT[bb][c0+2][r0+3]=w3.z; WT[bb][c0+3][r0+3]=w3.w;
    }

    // G = E + W*J^T ; sym ; mu update ; stores ; stage next
    #pragma unroll
    for (int bb = 0; bb < 2; ++bb){
      float4 g0=make_float4(0.f,0.f,0.f,0.f), g1=g0, g2=g0, g3=g0;
      #pragma unroll
      for (int k=0;k<32;++k){
        float4 wv = *(const float4*)&WT[bb][k][r0];
        float4 ju = *(const float4*)&JT[bb][k][c0];
        fma4(g0,wv.x,ju); fma4(g1,wv.y,ju); fma4(g2,wv.z,ju); fma4(g3,wv.w,ju);
      }
      g0.x+=er[bb][0][0]; g0.y+=er[bb][0][1]; g0.z+=er[bb][0][2]; g0.w+=er[bb][0][3];
      g1.x+=er[bb][1][0]; g1.y+=er[bb][1][1]; g1.z+=er[bb][1][2]; g1.w+=er[bb][1][3];
      g2.x+=er[bb][2][0]; g2.y+=er[bb][2][1]; g2.z+=er[bb][2][2]; g2.w+=er[bb][2][3];
      g3.x+=er[bb][3][0]; g3.y+=er[bb][3][1]; g3.z+=er[bb][3][2]; g3.w+=er[bb][3][3];
      *(float4*)&Tt[bb][r0+0][c0]=g0; *(float4*)&Tt[bb][r0+1][c0]=g1;
      *(float4*)&Tt[bb][r0+2][c0]=g2; *(float4*)&Tt[bb][r0+3][c0]=g3;

      float mn = 0.f;
      if (l < 32){
        mn = evv[bb][l];
        #pragma unroll
        for (int k=0;k<32;++k) mn = fmaf(JT[bb][k][l], muv[bb][k], mn);
      }

      float4 o0,o1,o2,o3;
      o0.x=0.5f*(g0.x+Tt[bb][c0+0][r0+0]); o0.y=0.5f*(g0.y+Tt[bb][c0+1][r0+0]);
      o0.z=0.5f*(g0.z+Tt[bb][c0+2][r0+0]); o0.w=0.5f*(g0.w+Tt[bb][c0+3][r0+0]);
      o1.x=0.5f*(g1.x+Tt[bb][c0+0][r0+1]); o1.y=0.5f*(g1.y+Tt[bb][c0+1][r0+1]);
      o1.z=0.5f*(g1.z+Tt[bb][c0+2][r0+1]); o1.w=0.5f*(g1.w+Tt[bb][c0+3][r0+1]);
      o2.x=0.5f*(g2.x+Tt[bb][c0+0][r0+2]); o2.y=0.5f*(g2.y+Tt[bb][c0+1][r0+2]);
      o2.z=0.5f*(g2.z+Tt[bb][c0+2][r0+2]); o2.w=0.5f*(g2.w+Tt[bb][c0+3][r0+2]);
      o3.x=0.5f*(g3.x+Tt[bb][c0+0][r0+3]); o3.y=0.5f*(g3.y+Tt[bb][c0+1][r0+3]);
      o3.z=0.5f*(g3.z+Tt[bb][c0+2][r0+3]); o3.w=0.5f*(g3.w+Tt[bb][c0+3][r0+3]);
      *(float4*)&SigsL[bb][r0+0][c0]=o0; *(float4*)&SigsL[bb][r0+1][c0]=o1;
      *(float4*)&SigsL[bb][r0+2][c0]=o2; *(float4*)&SigsL[bb][r0+3][c0]=o3;
      float* op = outg + ((base[bb] + t)*32 + r0)*33 + 1 + c0;
      op[0]=o0.x; op[1]=o0.y; op[2]=o0.z; op[3]=o0.w; op+=33;
      op[0]=o1.x; op[1]=o1.y; op[2]=o1.z; op[3]=o1.w; op+=33;
      op[0]=o2.x; op[1]=o2.y; op[2]=o2.z; op[3]=o2.w; op+=33;
      op[0]=o3.x; op[1]=o3.y; op[2]=o3.z; op[3]=o3.w;
      if (l < 32){
        muv[bb][l] = mn;
        outg[((base[bb] + t)*32 + l)*33] = mn;
      }
      if (t > 0){
        #pragma unroll
        for (int q=0;q<4;++q){
          float4 v = pj[bb][q];
          JT[bb][cA+4*q+0][rA]=v.x; JT[bb][cA+4*q+1][rA]=v.y;
          JT[bb][cA+4*q+2][rA]=v.z; JT[bb][cA+4*q+3][rA]=v.w;
        }
        #pragma unroll
        for (int i=0;i<4;++i)
          #pragma unroll
          for (int j=0;j<4;++j) er[bb][i][j] = ne[bb][i][j];
        if (l < 32) evv[bb][l] = nev[bb];
      }
    }
  }
}

extern "C" void kernel_launch(void* const* d_in, const int* in_sizes, int n_in,
                              void* d_out, int out_size, void* d_ws, size_t ws_size,
                              hipStream_t stream) {
  (void)in_sizes; (void)n_in; (void)out_size; (void)ws_size;
  const float* Yg   = (const float*)d_in[0];
  const float* Ug   = (const float*)d_in[1];
  const float* Ag   = (const float*)d_in[2];
  const float* Bg   = (const float*)d_in[3];
  const float* Cg   = (const float*)d_in[4];
  const float* mu0g = (const float*)d_in[5];
  const float* S0g  = (const float*)d_in[6];
  float* outg = (float*)d_out;
  float* wsSig = (float*)d_ws;                              // B*T*N*N floats
  float* wsMu  = wsSig + (size_t)NB*TT*NSZ*NSZ;             // B*T*N floats

  hipLaunchKernelGGL(kf_forward, dim3(NB/2), dim3(64), 0, stream,
                     Yg, Ug, Ag, Bg, Cg, mu0g, S0g, outg, wsSig, wsMu);
  hipLaunchKernelGGL(kf_precomp, dim3(TT-1, NB), dim3(256), 0, stream,
                     Ag, outg, wsSig, wsMu);
  hipLaunchKernelGGL(kf_backward, dim3(NB/2), dim3(64), 0, stream,
                     outg, wsSig);
}

// Round 5
// 1189.867 us; speedup vs baseline: 2.4401x; 2.4401x over previous
//
#include <hip/hip_runtime.h>

#define TT 128
#define NB 64
#define NSZ 32
#define MSZ 8
#define PSZ 16
#define LD 36
#define LDC 20

typedef __attribute__((ext_vector_type(8)))  short bf16x8;
typedef __attribute__((ext_vector_type(16))) float f32x16;
typedef __attribute__((ext_vector_type(4)))  float f32x4;
typedef __attribute__((ext_vector_type(4)))  unsigned int uint4v;
typedef __attribute__((ext_vector_type(2)))  unsigned int uint2v;

union U8 { uint4v u; bf16x8 b; };

__device__ __forceinline__ void fma4(float4& a, float s, const float4 v){
  a.x = fmaf(s, v.x, a.x); a.y = fmaf(s, v.y, a.y);
  a.z = fmaf(s, v.z, a.z); a.w = fmaf(s, v.w, a.w);
}
__device__ __forceinline__ float frcp(float x){ return __builtin_amdgcn_rcpf(x); }
__device__ __forceinline__ void bar(){
  asm volatile("s_waitcnt lgkmcnt(0)" ::: "memory");
  __builtin_amdgcn_s_barrier();
  asm volatile("" ::: "memory");
}

// bf16 split helpers: hi = truncated top-16 of f32; lo = bf16(x - f32(hi)).
__device__ __forceinline__ unsigned int hipack(float x0, float x1){
  // [x0_hi | x1_hi] with x0 in low half
  return __builtin_amdgcn_perm(__float_as_uint(x1), __float_as_uint(x0), 0x07060302u);
}
__device__ __forceinline__ unsigned int lopack(float x0, float x1){
  float l0 = x0 - __uint_as_float(__float_as_uint(x0) & 0xFFFF0000u);
  float l1 = x1 - __uint_as_float(__float_as_uint(x1) & 0xFFFF0000u);
  return __builtin_amdgcn_perm(__float_as_uint(l1), __float_as_uint(l0), 0x07060302u);
}
__device__ __forceinline__ unsigned int packhl(float x){
  unsigned int u = __float_as_uint(x);
  unsigned int h = u & 0xFFFF0000u;
  float xl = x - __uint_as_float(h);
  return h | (__float_as_uint(xl) >> 16);      // hi in top half, lo in bottom half
}
__device__ __forceinline__ uint4v frag_hi(uint4v a, uint4v b){
  uint4v r;
  r.x = __builtin_amdgcn_perm(a.y, a.x, 0x07060302u);
  r.y = __builtin_amdgcn_perm(a.w, a.z, 0x07060302u);
  r.z = __builtin_amdgcn_perm(b.y, b.x, 0x07060302u);
  r.w = __builtin_amdgcn_perm(b.w, b.z, 0x07060302u);
  return r;
}
__device__ __forceinline__ uint4v frag_lo(uint4v a, uint4v b){
  uint4v r;
  r.x = __builtin_amdgcn_perm(a.y, a.x, 0x05040100u);
  r.y = __builtin_amdgcn_perm(a.w, a.z, 0x05040100u);
  r.z = __builtin_amdgcn_perm(b.y, b.x, 0x05040100u);
  r.w = __builtin_amdgcn_perm(b.w, b.z, 0x05040100u);
  return r;
}
__device__ __forceinline__ float blof(unsigned int h, unsigned int l){
  return __uint_as_float(h << 16) + __uint_as_float(l << 16);
}
__device__ __forceinline__ float bhif(unsigned int h, unsigned int l){
  return __uint_as_float(h & 0xFFFF0000u) + __uint_as_float(l & 0xFFFF0000u);
}
__device__ __forceinline__ f32x16 mfma32(bf16x8 a, bf16x8 b, f32x16 c){
  return __builtin_amdgcn_mfma_f32_32x32x16_bf16(a, b, c, 0, 0, 0);
}
__device__ __forceinline__ f32x4 mfma16(bf16x8 a, bf16x8 b, f32x4 c){
  return __builtin_amdgcn_mfma_f32_16x16x32_bf16(a, b, c, 0, 0, 0);
}
__device__ __forceinline__ void split16(float4 v0, float4 v1, float4 v2, float4 v3,
                                        unsigned short* hi, unsigned short* lo){
  uint4v hw0, hw1, lw0, lw1;
  hw0.x=hipack(v0.x,v0.y); hw0.y=hipack(v0.z,v0.w); hw0.z=hipack(v1.x,v1.y); hw0.w=hipack(v1.z,v1.w);
  hw1.x=hipack(v2.x,v2.y); hw1.y=hipack(v2.z,v2.w); hw1.z=hipack(v3.x,v3.y); hw1.w=hipack(v3.z,v3.w);
  lw0.x=lopack(v0.x,v0.y); lw0.y=lopack(v0.z,v0.w); lw0.z=lopack(v1.x,v1.y); lw0.w=lopack(v1.z,v1.w);
  lw1.x=lopack(v2.x,v2.y); lw1.y=lopack(v2.z,v2.w); lw1.z=lopack(v3.x,v3.y); lw1.w=lopack(v3.z,v3.w);
  *(uint4v*)hi = hw0; *(uint4v*)(hi+8) = hw1;
  *(uint4v*)lo = lw0; *(uint4v*)(lo+8) = lw1;
}
__device__ __forceinline__ void split8(float4 v0, float4 v1,
                                       unsigned short* hi, unsigned short* lo){
  uint4v hw, lw;
  hw.x=hipack(v0.x,v0.y); hw.y=hipack(v0.z,v0.w); hw.z=hipack(v1.x,v1.y); hw.w=hipack(v1.z,v1.w);
  lw.x=lopack(v0.x,v0.y); lw.y=lopack(v0.z,v0.w); lw.z=lopack(v1.x,v1.y); lw.w=lopack(v1.z,v1.w);
  *(uint4v*)hi = hw; *(uint4v*)lo = lw;
}

// ===== Forward Kalman filter: 1 wave/batch, MFMA bf16-split matmuls, no barriers =====
__global__ __launch_bounds__(64) void kf_forward(
    const float* __restrict__ Yg, const float* __restrict__ Ug,
    const float* __restrict__ Ag, const float* __restrict__ Bg,
    const float* __restrict__ Cg, const float* __restrict__ mu0g,
    const float* __restrict__ Sig0g,
    float* __restrict__ outg, float* __restrict__ wsSig, float* __restrict__ wsMu)
{
  const int l   = threadIdx.x;
  const int b   = blockIdx.x;
  const int c32 = l & 31;
  const int h   = l >> 5;            // 0/1
  const int c16 = l & 15;
  const int q4  = l >> 4;            // 0..3
  const int kofA = h * 8;            // k-offset in K=16 (32x32 mfma)
  const int kofC = q4 * 8;           // k-offset in K=32 (16x16 mfma)
  const int rA = l >> 1, cA = (l & 1) << 4;
  const int rC = l >> 2, cC = (l & 3) << 3;
  const int row = c16, g = q4;       // GJ mapping

  __shared__ __align__(16) unsigned short Ahi[32][40], Alo[32][40];
  __shared__ __align__(16) unsigned short Chi[16][40], Clo[16][40];
  __shared__ __align__(16) unsigned short Ghi[32][40], Glo[32][40];  // Sigma state
  __shared__ __align__(16) unsigned short Phi[32][40], Plo[32][40];  // Sigma_p
  __shared__ __align__(16) unsigned short Yhi[32][24], Ylo[32][24];  // CS^T
  __shared__ __align__(16) unsigned int   T1P[32][40];               // T1 rows, packed hi|lo
  __shared__ __align__(16) unsigned int   ZP[16][40];                // CS rows, packed
  __shared__ __align__(16) unsigned int   KtTP[32][24];              // (-Kt)^T packed
  __shared__ __align__(16) float SLf[16][20];
  __shared__ __align__(16) float CSf[16][40];
  __shared__ __align__(16) float Bm[32][12];
  __shared__ __align__(16) float muf[32], mupf[32], rvf[16], yvf[16], uvf[8];

  const size_t bt0 = (size_t)b * TT;

  // ---- initial staging ----
  {
    const float* ap = Ag + bt0*1024 + rA*32 + cA;
    split16(*(const float4*)(ap+0), *(const float4*)(ap+4),
            *(const float4*)(ap+8), *(const float4*)(ap+12),
            &Ahi[rA][cA], &Alo[rA][cA]);
    const float* sp0 = Sig0g + rA*32 + cA;
    split16(*(const float4*)(sp0+0), *(const float4*)(sp0+4),
            *(const float4*)(sp0+8), *(const float4*)(sp0+12),
            &Ghi[rA][cA], &Glo[rA][cA]);
    const float* cp = Cg + bt0*512 + rC*32 + cC;
    split8(*(const float4*)(cp+0), *(const float4*)(cp+4),
           &Chi[rC][cC], &Clo[rC][cC]);
    *(float4*)&Bm[l>>1][(l&1)*4] = *(const float4*)(Bg + bt0*256 + (l>>1)*8 + (l&1)*4);
    if (l < 32) muf[l] = mu0g[l];
    if (l < 16) yvf[l] = Yg[bt0*16 + l];
    if (l < 8)  uvf[l] = Ug[bt0*8 + l];
  }

  for (int t = 0; t < TT; ++t) {
    const size_t bt = bt0 + t;

    // ---- P1: T1 = A * Sigma ----
    U8 a_h0, a_h1, a_l0, a_l1, s_h0, s_h1, s_l0, s_l1;
    a_h0.u = *(const uint4v*)&Ahi[c32][0  + kofA];
    a_h1.u = *(const uint4v*)&Ahi[c32][16 + kofA];
    a_l0.u = *(const uint4v*)&Alo[c32][0  + kofA];
    a_l1.u = *(const uint4v*)&Alo[c32][16 + kofA];
    s_h0.u = *(const uint4v*)&Ghi[c32][0  + kofA];
    s_h1.u = *(const uint4v*)&Ghi[c32][16 + kofA];
    s_l0.u = *(const uint4v*)&Glo[c32][0  + kofA];
    s_l1.u = *(const uint4v*)&Glo[c32][16 + kofA];
    f32x16 t1;
    #pragma unroll
    for (int r=0;r<16;++r) t1[r] = 0.f;
    t1 = mfma32(a_h0.b, s_h0.b, t1);
    t1 = mfma32(a_h1.b, s_h1.b, t1);
    t1 = mfma32(a_h0.b, s_l0.b, t1);
    t1 = mfma32(a_h1.b, s_l1.b, t1);
    t1 = mfma32(a_l0.b, s_h0.b, t1);
    t1 = mfma32(a_l1.b, s_h1.b, t1);
    #pragma unroll
    for (int r=0;r<16;++r){
      int rr = (r&3) + 8*(r>>2) + 4*h;
      T1P[rr][c32] = packhl(t1[r]);
    }
    // mu_p = A*mu + B*u  (unpack A frags, dot with mu)
    float part = 0.f;
    {
      float4 m0 = *(const float4*)&muf[kofA];
      float4 m1 = *(const float4*)&muf[kofA+4];
      float4 m2 = *(const float4*)&muf[16+kofA];
      float4 m3 = *(const float4*)&muf[16+kofA+4];
      part = fmaf(blof(a_h0.u.x,a_l0.u.x), m0.x, part);
      part = fmaf(bhif(a_h0.u.x,a_l0.u.x), m0.y, part);
      part = fmaf(blof(a_h0.u.y,a_l0.u.y), m0.z, part);
      part = fmaf(bhif(a_h0.u.y,a_l0.u.y), m0.w, part);
      part = fmaf(blof(a_h0.u.z,a_l0.u.z), m1.x, part);
      part = fmaf(bhif(a_h0.u.z,a_l0.u.z), m1.y, part);
      part = fmaf(blof(a_h0.u.w,a_l0.u.w), m1.z, part);
      part = fmaf(bhif(a_h0.u.w,a_l0.u.w), m1.w, part);
      part = fmaf(blof(a_h1.u.x,a_l1.u.x), m2.x, part);
      part = fmaf(bhif(a_h1.u.x,a_l1.u.x), m2.y, part);
      part = fmaf(blof(a_h1.u.y,a_l1.u.y), m2.z, part);
      part = fmaf(bhif(a_h1.u.y,a_l1.u.y), m2.w, part);
      part = fmaf(blof(a_h1.u.z,a_l1.u.z), m3.x, part);
      part = fmaf(bhif(a_h1.u.z,a_l1.u.z), m3.y, part);
      part = fmaf(blof(a_h1.u.w,a_l1.u.w), m3.z, part);
      part = fmaf(bhif(a_h1.u.w,a_l1.u.w), m3.w, part);
    }
    part += __shfl_xor(part, 32);
    {
      float4 b0 = *(const float4*)&Bm[c32][0];
      float4 b1 = *(const float4*)&Bm[c32][4];
      float4 u0 = *(const float4*)&uvf[0];
      float4 u1 = *(const float4*)&uvf[4];
      part = fmaf(b0.x,u0.x, fmaf(b0.y,u0.y, fmaf(b0.z,u0.z, fmaf(b0.w,u0.w, part))));
      part = fmaf(b1.x,u1.x, fmaf(b1.y,u1.y, fmaf(b1.z,u1.z, fmaf(b1.w,u1.w, part))));
    }
    if (l < 32){ mupf[c32] = part; wsMu[bt*32 + c32] = part; }

    // ---- P2: Sigma_p = A * T1^T + Q ----
    U8 b_h0, b_h1, b_l0, b_l1;
    {
      uint4v p0  = *(const uint4v*)&T1P[c32][0  + kofA];
      uint4v p0b = *(const uint4v*)&T1P[c32][4  + kofA];
      uint4v p1  = *(const uint4v*)&T1P[c32][16 + kofA];
      uint4v p1b = *(const uint4v*)&T1P[c32][20 + kofA];
      b_h0.u = frag_hi(p0, p0b); b_l0.u = frag_lo(p0, p0b);
      b_h1.u = frag_hi(p1, p1b); b_l1.u = frag_lo(p1, p1b);
    }
    f32x16 sp;
    #pragma unroll
    for (int r=0;r<16;++r) sp[r] = 0.f;
    sp = mfma32(a_h0.b, b_h0.b, sp);
    sp = mfma32(a_h1.b, b_h1.b, sp);
    sp = mfma32(a_h0.b, b_l0.b, sp);
    sp = mfma32(a_h1.b, b_l1.b, sp);
    sp = mfma32(a_l0.b, b_h0.b, sp);
    sp = mfma32(a_l1.b, b_h1.b, sp);
    #pragma unroll
    for (int r=0;r<16;++r){
      int rr = (r&3) + 8*(r>>2) + 4*h;
      if (rr == c32) sp[r] += 0.01f;
    }
    {
      float* wp = wsSig + (bt*32 + c32)*32;
      *(float4*)(wp + 0  + 4*h) = make_float4(sp[0], sp[1], sp[2], sp[3]);
      *(float4*)(wp + 8  + 4*h) = make_float4(sp[4], sp[5], sp[6], sp[7]);
      *(float4*)(wp + 16 + 4*h) = make_float4(sp[8], sp[9], sp[10],sp[11]);
      *(float4*)(wp + 24 + 4*h) = make_float4(sp[12],sp[13],sp[14],sp[15]);
      #pragma unroll
      for (int gq=0; gq<4; ++gq){
        uint2v hw, lw;
        hw.x = hipack(sp[4*gq+0], sp[4*gq+1]); hw.y = hipack(sp[4*gq+2], sp[4*gq+3]);
        lw.x = lopack(sp[4*gq+0], sp[4*gq+1]); lw.y = lopack(sp[4*gq+2], sp[4*gq+3]);
        *(uint2v*)&Phi[c32][8*gq + 4*h] = hw;
        *(uint2v*)&Plo[c32][8*gq + 4*h] = lw;
      }
    }

    // ---- P3: CS = C * Sigma_p ----
    U8 c_h, c_l, p_h0, p_l0, p_h1, p_l1;
    c_h.u  = *(const uint4v*)&Chi[c16][kofC];
    c_l.u  = *(const uint4v*)&Clo[c16][kofC];
    p_h0.u = *(const uint4v*)&Phi[c16][kofC];
    p_l0.u = *(const uint4v*)&Plo[c16][kofC];
    p_h1.u = *(const uint4v*)&Phi[16+c16][kofC];
    p_l1.u = *(const uint4v*)&Plo[16+c16][kofC];
    f32x4 cs0, cs1;
    #pragma unroll
    for (int r=0;r<4;++r){ cs0[r]=0.f; cs1[r]=0.f; }
    cs0 = mfma16(c_h.b, p_h0.b, cs0);
    cs0 = mfma16(c_h.b, p_l0.b, cs0);
    cs0 = mfma16(c_l.b, p_h0.b, cs0);
    cs1 = mfma16(c_h.b, p_h1.b, cs1);
    cs1 = mfma16(c_h.b, p_l1.b, cs1);
    cs1 = mfma16(c_l.b, p_h1.b, cs1);
    #pragma unroll
    for (int r=0;r<4;++r){
      int rr = q4*4 + r;
      ZP[rr][c16]     = packhl(cs0[r]);
      ZP[rr][16+c16]  = packhl(cs1[r]);
      CSf[rr][c16]    = cs0[r];
      CSf[rr][16+c16] = cs1[r];
    }
    {
      uint2v hw0, lw0, hw1, lw1;
      hw0.x = hipack(cs0[0],cs0[1]); hw0.y = hipack(cs0[2],cs0[3]);
      lw0.x = lopack(cs0[0],cs0[1]); lw0.y = lopack(cs0[2],cs0[3]);
      hw1.x = hipack(cs1[0],cs1[1]); hw1.y = hipack(cs1[2],cs1[3]);
      lw1.x = lopack(cs1[0],cs1[1]); lw1.y = lopack(cs1[2],cs1[3]);
      *(uint2v*)&Yhi[c16][q4*4]    = hw0; *(uint2v*)&Ylo[c16][q4*4]    = lw0;
      *(uint2v*)&Yhi[16+c16][q4*4] = hw1; *(uint2v*)&Ylo[16+c16][q4*4] = lw1;
    }
    // r = y - C*mu_p
    {
      float prr = 0.f;
      float4 m0 = *(const float4*)&mupf[kofC];
      float4 m1 = *(const float4*)&mupf[kofC+4];
      prr = fmaf(blof(c_h.u.x,c_l.u.x), m0.x, prr);
      prr = fmaf(bhif(c_h.u.x,c_l.u.x), m0.y, prr);
      prr = fmaf(blof(c_h.u.y,c_l.u.y), m0.z, prr);
      prr = fmaf(bhif(c_h.u.y,c_l.u.y), m0.w, prr);
      prr = fmaf(blof(c_h.u.z,c_l.u.z), m1.x, prr);
      prr = fmaf(bhif(c_h.u.z,c_l.u.z), m1.y, prr);
      prr = fmaf(blof(c_h.u.w,c_l.u.w), m1.z, prr);
      prr = fmaf(bhif(c_h.u.w,c_l.u.w), m1.w, prr);
      prr += __shfl_xor(prr, 16);
      prr += __shfl_xor(prr, 32);
      if (l < 16) rvf[l] = yvf[l] - prr;
    }

    // ---- P4: S = CS * C^T + R ----
    {
      U8 z_h, z_l;
      uint4v pz0 = *(const uint4v*)&ZP[c16][kofC];
      uint4v pz1 = *(const uint4v*)&ZP[c16][kofC+4];
      z_h.u = frag_hi(pz0, pz1); z_l.u = frag_lo(pz0, pz1);
      f32x4 ss;
      #pragma unroll
      for (int r=0;r<4;++r) ss[r] = 0.f;
      ss = mfma16(z_h.b, c_h.b, ss);
      ss = mfma16(z_h.b, c_l.b, ss);
      ss = mfma16(z_l.b, c_h.b, ss);
      #pragma unroll
      for (int r=0;r<4;++r){
        int rr = q4*4 + r;
        SLf[rr][c16] = ss[r] + ((rr == c16) ? 0.01f : 0.f);
      }
    }

    // ---- prefetch next-step inputs (latency hidden under GJ+P6) ----
    float4 pa0, pa1, pa2, pa3, pc0, pc1, pbv;
    float py = 0.f, pu = 0.f;
    pa0=pa1=pa2=pa3=make_float4(0.f,0.f,0.f,0.f);
    pc0=pc1=pbv=make_float4(0.f,0.f,0.f,0.f);
    if (t + 1 < TT){
      const float* ap = Ag + (bt+1)*1024 + rA*32 + cA;
      pa0 = *(const float4*)(ap+0);  pa1 = *(const float4*)(ap+4);
      pa2 = *(const float4*)(ap+8);  pa3 = *(const float4*)(ap+12);
      const float* cp = Cg + (bt+1)*512 + rC*32 + cC;
      pc0 = *(const float4*)(cp+0);  pc1 = *(const float4*)(cp+4);
      pbv = *(const float4*)(Bg + (bt+1)*256 + (l>>1)*8 + (l&1)*4);
      if (l < 16) py = Yg[(bt+1)*16 + l];
      if (l < 8)  pu = Ug[(bt+1)*8 + l];
    }

    // ---- P5: register Gauss-Jordan on [sym(S) | CS] ----
    {
      float aug[16];
      if (g == 0){
        float tmp[16];
        #pragma unroll
        for (int q=0;q<4;++q){
          float4 v = *(const float4*)&SLf[row][4*q];
          tmp[4*q]=v.x; tmp[4*q+1]=v.y; tmp[4*q+2]=v.z; tmp[4*q+3]=v.w;
        }
        #pragma unroll
        for (int c2=0;c2<16;++c2) aug[c2] = 0.5f*(tmp[c2] + SLf[c2][row]);
      } else if (g <= 2){
        #pragma unroll
        for (int q=0;q<4;++q){
          float4 v = *(const float4*)&CSf[row][(g-1)*16 + 4*q];
          aug[4*q]=v.x; aug[4*q+1]=v.y; aug[4*q+2]=v.z; aug[4*q+3]=v.w;
        }
      } else {
        #pragma unroll
        for (int c2=0;c2<16;++c2) aug[c2] = 0.f;
      }
      const int psrc = g << 4;
      #pragma unroll
      for (int k=0;k<16;++k){
        float f   = __shfl(aug[k], row);
        float piv = __shfl(aug[k], k);
        float prc = frcp(piv);
        float pr[16];
        #pragma unroll
        for (int c2=0;c2<16;++c2) pr[c2] = __shfl(aug[c2], k + psrc);
        float fn = f * prc;
        #pragma unroll
        for (int c2=0;c2<16;++c2){
          float upd = fmaf(-fn, pr[c2], aug[c2]);
          aug[c2] = (row == k) ? aug[c2]*prc : upd;
        }
      }
      if (g == 1 || g == 2){
        #pragma unroll
        for (int c2=0;c2<16;++c2) KtTP[(g-1)*16 + c2][row] = packhl(-aug[c2]);
      }
    }

    // ---- P6: Sigma_f = Sigma_p - CS^T * Kt  (Kt stored negated) ----
    f32x16 sf = sp;
    {
      U8 y_h, y_l, kt_h, kt_l;
      y_h.u = *(const uint4v*)&Yhi[c32][8*h];
      y_l.u = *(const uint4v*)&Ylo[c32][8*h];
      uint4v k0 = *(const uint4v*)&KtTP[c32][8*h];
      uint4v k1 = *(const uint4v*)&KtTP[c32][8*h+4];
      kt_h.u = frag_hi(k0, k1); kt_l.u = frag_lo(k0, k1);
      sf = mfma32(y_h.b, kt_h.b, sf);
      sf = mfma32(y_h.b, kt_l.b, sf);
      sf = mfma32(y_l.b, kt_h.b, sf);
    }
    // state + outputs
    #pragma unroll
    for (int gq=0; gq<4; ++gq){
      uint2v hw, lw;
      hw.x = hipack(sf[4*gq+0], sf[4*gq+1]); hw.y = hipack(sf[4*gq+2], sf[4*gq+3]);
      lw.x = lopack(sf[4*gq+0], sf[4*gq+1]); lw.y = lopack(sf[4*gq+2], sf[4*gq+3]);
      *(uint2v*)&Ghi[c32][8*gq + 4*h] = hw;
      *(uint2v*)&Glo[c32][8*gq + 4*h] = lw;
    }
    {
      float* ob = outg + (bt*32)*33;
      #pragma unroll
      for (int r=0;r<16;++r){
        int rr = (r&3) + 8*(r>>2) + 4*h;
        ob[rr*33 + 1 + c32] = sf[r];
      }
      // mu_f = mu_p + K*r  (KtTP holds -Kt)
      float mf = mupf[c32];
      uint4v w0 = *(const uint4v*)&KtTP[c32][0];
      uint4v w1 = *(const uint4v*)&KtTP[c32][4];
      uint4v w2 = *(const uint4v*)&KtTP[c32][8];
      uint4v w3 = *(const uint4v*)&KtTP[c32][12];
      float4 r0 = *(const float4*)&rvf[0];
      float4 r1 = *(const float4*)&rvf[4];
      float4 r2 = *(const float4*)&rvf[8];
      float4 r3 = *(const float4*)&rvf[12];
      mf = fmaf(-(bhif(w0.x,0u)+blof(0u,w0.x)), r0.x, mf);
      mf = fmaf(-(bhif(w0.y,0u)+blof(0u,w0.y)), r0.y, mf);
      mf = fmaf(-(bhif(w0.z,0u)+blof(0u,w0.z)), r0.z, mf);
      mf = fmaf(-(bhif(w0.w,0u)+blof(0u,w0.w)), r0.w, mf);
      mf = fmaf(-(bhif(w1.x,0u)+blof(0u,w1.x)), r1.x, mf);
      mf = fmaf(-(bhif(w1.y,0u)+blof(0u,w1.y)), r1.y, mf);
      mf = fmaf(-(bhif(w1.z,0u)+blof(0u,w1.z)), r1.z, mf);
      mf = fmaf(-(bhif(w1.w,0u)+blof(0u,w1.w)), r1.w, mf);
      mf = fmaf(-(bhif(w2.x,0u)+blof(0u,w2.x)), r2.x, mf);
      mf = fmaf(-(bhif(w2.y,0u)+blof(0u,w2.y)), r2.y, mf);
      mf = fmaf(-(bhif(w2.z,0u)+blof(0u,w2.z)), r2.z, mf);
      mf = fmaf(-(bhif(w2.w,0u)+blof(0u,w2.w)), r2.w, mf);
      mf = fmaf(-(bhif(w3.x,0u)+blof(0u,w3.x)), r3.x, mf);
      mf = fmaf(-(bhif(w3.y,0u)+blof(0u,w3.y)), r3.y, mf);
      mf = fmaf(-(bhif(w3.z,0u)+blof(0u,w3.z)), r3.z, mf);
      mf = fmaf(-(bhif(w3.w,0u)+blof(0u,w3.w)), r3.w, mf);
      if (l < 32){ muf[c32] = mf; ob[c32*33] = mf; }
    }

    // ---- P7: stage next-step inputs ----
    if (t + 1 < TT){
      split16(pa0, pa1, pa2, pa3, &Ahi[rA][cA], &Alo[rA][cA]);
      split8(pc0, pc1, &Chi[rC][cC], &Clo[rC][cC]);
      *(float4*)&Bm[l>>1][(l&1)*4] = pbv;
      if (l < 16) yvf[l] = py;
      if (l < 8)  uvf[l] = pu;
    }
  }
}

// ------- Parallel smoother precompute: J_t, E_t, e_t for t=0..T-2 -------
__global__ __launch_bounds__(256) void kf_precomp(
    const float* __restrict__ Ag, float* __restrict__ outg,
    float* __restrict__ wsSig, float* __restrict__ wsMu)
{
  const int t = blockIdx.x;
  const int b = blockIdx.y;
  const int tid = threadIdx.x;
  const int i32 = tid >> 3;
  const int j4 = (tid & 7) << 2;
  __shared__ __align__(16) float Sf[NSZ][LD];
  __shared__ __align__(16) float AT2[NSZ][LD];
  __shared__ __align__(16) float Mm[NSZ][LD];
  __shared__ __align__(16) float Pm[NSZ][LD];
  __shared__ __align__(16) float V[NSZ][LD];
  __shared__ __align__(16) float Jl[NSZ][LD];
  __shared__ __align__(16) float JTs[NSZ][LD];
  __shared__ __align__(16) float prow[NSZ];
  __shared__ __align__(16) float vrow[NSZ];
  __shared__ float mfv[NSZ], mp1[NSZ];
  const size_t bt = (size_t)b*TT + t;
  {
    const float* os = outg + bt*NSZ*(NSZ+1);
    #pragma unroll
    for (int r = 0; r < 4; ++r) {
      int e = tid + 256*r; int i = e >> 5, j = e & 31;
      Sf[i][j] = os[i*(NSZ+1) + 1 + j];
    }
    if (tid < NSZ) mfv[tid] = os[tid*(NSZ+1)];
    float4 a4 = *(const float4*)(Ag + bt*(NSZ*NSZ) + tid*4);
    AT2[j4+0][i32]=a4.x; AT2[j4+1][i32]=a4.y; AT2[j4+2][i32]=a4.z; AT2[j4+3][i32]=a4.w;
    *(float4*)&Pm[i32][j4] = *(const float4*)(wsSig + ((bt+1)*NSZ + i32)*NSZ + j4);
    if (tid < NSZ) mp1[tid] = wsMu[(bt+1)*NSZ + tid];
    float4 vi;
    vi.x = (i32 == j4+0) ? 1.f : 0.f;
    vi.y = (i32 == j4+1) ? 1.f : 0.f;
    vi.z = (i32 == j4+2) ? 1.f : 0.f;
    vi.w = (i32 == j4+3) ? 1.f : 0.f;
    *(float4*)&V[i32][j4] = vi;
  }
  __syncthreads();
  {
    float4 acc = make_float4(0.f,0.f,0.f,0.f);
    #pragma unroll
    for (int k0 = 0; k0 < NSZ; k0 += 4) {
      float4 s = *(const float4*)&Sf[i32][k0];
      fma4(acc, s.x, *(const float4*)&AT2[k0+0][j4]);
      fma4(acc, s.y, *(const float4*)&AT2[k0+1][j4]);
      fma4(acc, s.z, *(const float4*)&AT2[k0+2][j4]);
      fma4(acc, s.w, *(const float4*)&AT2[k0+3][j4]);
    }
    *(float4*)&Mm[i32][j4] = acc;
  }
  __syncthreads();
  for (int k = 0; k < NSZ; ++k) {
    float f = Pm[i32][k];
    if (tid < 8) {
      float rd = frcp(Pm[k][k]);
      #pragma unroll
      for (int m = 0; m < 4; ++m) prow[tid*4+m] = Pm[k][tid*4+m] * rd;
    } else if (tid < 16) {
      float rd = frcp(Pm[k][k]);
      const int c0 = (tid-8)*4;
      #pragma unroll
      for (int m = 0; m < 4; ++m) vrow[c0+m] = V[k][c0+m] * rd;
    }
    __syncthreads();
    if (i32 == k) {
      *(float4*)&Pm[k][j4] = *(const float4*)&prow[j4];
      *(float4*)&V[k][j4] = *(const float4*)&vrow[j4];
    } else {
      float4 p = *(const float4*)&Pm[i32][j4];
      float4 v = *(const float4*)&V[i32][j4];
      fma4(p, -f, *(const float4*)&prow[j4]);
      fma4(v, -f, *(const float4*)&vrow[j4]);
      *(float4*)&Pm[i32][j4] = p;
      *(float4*)&V[i32][j4] = v;
    }
    __syncthreads();
  }
  {
    float4 acc = make_float4(0.f,0.f,0.f,0.f);
    #pragma unroll
    for (int k0 = 0; k0 < NSZ; k0 += 4) {
      float4 m4 = *(const float4*)&Mm[i32][k0];
      fma4(acc, m4.x, *(const float4*)&V[k0+0][j4]);
      fma4(acc, m4.y, *(const float4*)&V[k0+1][j4]);
      fma4(acc, m4.z, *(const float4*)&V[k0+2][j4]);
      fma4(acc, m4.w, *(const float4*)&V[k0+3][j4]);
    }
    *(float4*)&Jl[i32][j4] = acc;
    JTs[j4+0][i32]=acc.x; JTs[j4+1][i32]=acc.y; JTs[j4+2][i32]=acc.z; JTs[j4+3][i32]=acc.w;
    *(float4*)(wsSig + ((bt+1)*NSZ + i32)*NSZ + j4) = acc;
  }
  __syncthreads();
  {
    float4 acc = make_float4(0.f,0.f,0.f,0.f);
    #pragma unroll
    for (int k0 = 0; k0 < NSZ; k0 += 4) {
      float4 m4 = *(const float4*)&Mm[i32][k0];
      fma4(acc, m4.x, *(const float4*)&JTs[k0+0][j4]);
      fma4(acc, m4.y, *(const float4*)&JTs[k0+1][j4]);
      fma4(acc, m4.z, *(const float4*)&JTs[k0+2][j4]);
      fma4(acc, m4.w, *(const float4*)&JTs[k0+3][j4]);
    }
    float* os = outg + bt*NSZ*(NSZ+1);
    os[i32*(NSZ+1)+1+j4+0] = Sf[i32][j4+0] - acc.x;
    os[i32*(NSZ+1)+1+j4+1] = Sf[i32][j4+1] - acc.y;
    os[i32*(NSZ+1)+1+j4+2] = Sf[i32][j4+2] - acc.z;
    os[i32*(NSZ+1)+1+j4+3] = Sf[i32][j4+3] - acc.w;
    if (tid < NSZ) {
      float e2 = mfv[tid];
      #pragma unroll
      for (int k = 0; k < NSZ; ++k) e2 = fmaf(-Jl[tid][k], mp1[k], e2);
      os[tid*(NSZ+1)] = e2;
    }
  }
}

// --------------- Backward smoother recursion: 1 block per batch (R2-proven) ---------------
__global__ __launch_bounds__(256) void kf_backward(
    float* __restrict__ outg, const float* __restrict__ wsSig)
{
  const int b = blockIdx.x;
  const int tid = threadIdx.x;
  const int i32 = tid >> 3;
  const int j4 = (tid & 7) << 2;
  __shared__ __align__(16) float Sigs[NSZ][LD];
  __shared__ __align__(16) float Jl[NSZ][LD];
  __shared__ __align__(16) float JTs[NSZ][LD];
  __shared__ __align__(16) float W[NSZ][LD];
  __shared__ __align__(16) float G[NSZ][LD];
  __shared__ __align__(16) float Eb[NSZ][LD];
  __shared__ float mus[NSZ], ev[NSZ];
  const size_t base = (size_t)b*TT;
  {
    const float* os = outg + (base + TT - 1)*NSZ*(NSZ+1);
    #pragma unroll
    for (int r = 0; r < 4; ++r) {
      int e = tid + 256*r; int i = e >> 5, j = e & 31;
      Sigs[i][j] = os[i*(NSZ+1) + 1 + j];
    }
    if (tid < NSZ) mus[tid] = os[tid*(NSZ+1)];
    float4 jj = *(const float4*)(wsSig + ((base + TT - 1)*NSZ + i32)*NSZ + j4);
    *(float4*)&Jl[i32][j4] = jj;
    JTs[j4+0][i32]=jj.x; JTs[j4+1][i32]=jj.y; JTs[j4+2][i32]=jj.z; JTs[j4+3][i32]=jj.w;
    const float* oe = outg + (base + TT - 2)*NSZ*(NSZ+1);
    Eb[i32][j4+0] = oe[i32*(NSZ+1)+1+j4+0];
    Eb[i32][j4+1] = oe[i32*(NSZ+1)+1+j4+1];
    Eb[i32][j4+2] = oe[i32*(NSZ+1)+1+j4+2];
    Eb[i32][j4+3] = oe[i32*(NSZ+1)+1+j4+3];
    if (tid < NSZ) ev[tid] = oe[tid*(NSZ+1)];
  }
  __syncthreads();

  for (int t = TT - 2; t >= 0; --t) {
    float4 nj = make_float4(0.f,0.f,0.f,0.f);
    float ne0=0.f, ne1=0.f, ne2=0.f, ne3=0.f, nev=0.f;
    if (t > 0) {
      nj = *(const float4*)(wsSig + ((base + t)*NSZ + i32)*NSZ + j4);
      const float* oe = outg + (base + t - 1)*NSZ*(NSZ+1);
      ne0 = oe[i32*(NSZ+1)+1+j4+0];
      ne1 = oe[i32*(NSZ+1)+1+j4+1];
      ne2 = oe[i32*(NSZ+1)+1+j4+2];
      ne3 = oe[i32*(NSZ+1)+1+j4+3];
      if (tid < NSZ) nev = oe[tid*(NSZ+1)];
    }
    {
      float4 acc = make_float4(0.f,0.f,0.f,0.f);
      #pragma unroll
      for (int k0 = 0; k0 < NSZ; k0 += 4) {
        float4 j4v = *(const float4*)&Jl[i32][k0];
        fma4(acc, j4v.x, *(const float4*)&Sigs[k0+0][j4]);
        fma4(acc, j4v.y, *(const float4*)&Sigs[k0+1][j4]);
        fma4(acc, j4v.z, *(const float4*)&Sigs[k0+2][j4]);
        fma4(acc, j4v.w, *(const float4*)&Sigs[k0+3][j4]);
      }
      *(float4*)&W[i32][j4] = acc;
    }
    bar();
    {
      float4 acc = make_float4(0.f,0.f,0.f,0.f);
      #pragma unroll
      for (int k0 = 0; k0 < NSZ; k0 += 4) {
        float4 w4 = *(const float4*)&W[i32][k0];
        fma4(acc, w4.x, *(const float4*)&JTs[k0+0][j4]);
        fma4(acc, w4.y, *(const float4*)&JTs[k0+1][j4]);
        fma4(acc, w4.z, *(const float4*)&JTs[k0+2][j4]);
        fma4(acc, w4.w, *(const float4*)&JTs[k0+3][j4]);
      }
      acc.x += Eb[i32][j4+0];
      acc.y += Eb[i32][j4+1];
      acc.z += Eb[i32][j4+2];
      acc.w += Eb[i32][j4+3];
      *(float4*)&G[i32][j4] = acc;
    }
    bar();
    float4 sf;
    sf.x = 0.5f*(G[i32][j4+0] + G[j4+0][i32]);
    sf.y = 0.5f*(G[i32][j4+1] + G[j4+1][i32]);
    sf.z = 0.5f*(G[i32][j4+2] + G[j4+2][i32]);
    sf.w = 0.5f*(G[i32][j4+3] + G[j4+3][i32]);
    float mn = 0.f;
    if (tid < NSZ) {
      mn = ev[tid];
      #pragma unroll
      for (int k = 0; k < NSZ; ++k) mn = fmaf(Jl[tid][k], mus[k], mn);
    }
    bar();
    *(float4*)&Sigs[i32][j4] = sf;
    {
      float* op = outg + ((base + t)*NSZ + i32)*(NSZ+1) + 1 + j4;
      op[0]=sf.x; op[1]=sf.y; op[2]=sf.z; op[3]=sf.w;
      if (tid < NSZ) {
        mus[tid] = mn;
        outg[((base + t)*NSZ + tid)*(NSZ+1)] = mn;
      }
    }
    if (t > 0) {
      *(float4*)&Jl[i32][j4] = nj;
      JTs[j4+0][i32]=nj.x; JTs[j4+1][i32]=nj.y; JTs[j4+2][i32]=nj.z; JTs[j4+3][i32]=nj.w;
      Eb[i32][j4+0]=ne0; Eb[i32][j4+1]=ne1; Eb[i32][j4+2]=ne2; Eb[i32][j4+3]=ne3;
      if (tid < NSZ) ev[tid] = nev;
    }
    bar();
  }
}

extern "C" void kernel_launch(void* const* d_in, const int* in_sizes, int n_in,
                              void* d_out, int out_size, void* d_ws, size_t ws_size,
                              hipStream_t stream) {
  (void)in_sizes; (void)n_in; (void)out_size; (void)ws_size;
  const float* Yg   = (const float*)d_in[0];
  const float* Ug   = (const float*)d_in[1];
  const float* Ag   = (const float*)d_in[2];
  const float* Bg   = (const float*)d_in[3];
  const float* Cg   = (const float*)d_in[4];
  const float* mu0g = (const float*)d_in[5];
  const float* S0g  = (const float*)d_in[6];
  float* outg = (float*)d_out;
  float* wsSig = (float*)d_ws;
  float* wsMu  = wsSig + (size_t)NB*TT*NSZ*NSZ;

  hipLaunchKernelGGL(kf_forward, dim3(NB), dim3(64), 0, stream,
                     Yg, Ug, Ag, Bg, Cg, mu0g, S0g, outg, wsSig, wsMu);
  hipLaunchKernelGGL(kf_precomp, dim3(TT-1, NB), dim3(256), 0, stream,
                     Ag, outg, wsSig, wsMu);
  hipLaunchKernelGGL(kf_backward, dim3(NB), dim3(256), 0, stream,
                     outg, wsSig);
}

// Round 6
// 955.989 us; speedup vs baseline: 3.0371x; 1.2446x over previous
//
#include <hip/hip_runtime.h>

#define TT 128
#define NB 64
#define NSZ 32
#define MSZ 8
#define PSZ 16
#define LD 36
#define LDC 20

typedef __attribute__((ext_vector_type(8)))  short bf16x8;
typedef __attribute__((ext_vector_type(16))) float f32x16;
typedef __attribute__((ext_vector_type(4)))  float f32x4;
typedef __attribute__((ext_vector_type(4)))  unsigned int uint4v;
typedef __attribute__((ext_vector_type(2)))  unsigned int uint2v;

union U8 { uint4v u; bf16x8 b; };

__device__ __forceinline__ void fma4(float4& a, float s, const float4 v){
  a.x = fmaf(s, v.x, a.x); a.y = fmaf(s, v.y, a.y);
  a.z = fmaf(s, v.z, a.z); a.w = fmaf(s, v.w, a.w);
}
__device__ __forceinline__ float frcp(float x){ return __builtin_amdgcn_rcpf(x); }
__device__ __forceinline__ void bar(){
  asm volatile("s_waitcnt lgkmcnt(0)" ::: "memory");
  __builtin_amdgcn_s_barrier();
  asm volatile("" ::: "memory");
}

// bf16 split helpers: hi = truncated top-16 of f32; lo = bf16(x - f32(hi)).
__device__ __forceinline__ unsigned int hipack(float x0, float x1){
  return __builtin_amdgcn_perm(__float_as_uint(x1), __float_as_uint(x0), 0x07060302u);
}
__device__ __forceinline__ unsigned int lopack(float x0, float x1){
  float l0 = x0 - __uint_as_float(__float_as_uint(x0) & 0xFFFF0000u);
  float l1 = x1 - __uint_as_float(__float_as_uint(x1) & 0xFFFF0000u);
  return __builtin_amdgcn_perm(__float_as_uint(l1), __float_as_uint(l0), 0x07060302u);
}
__device__ __forceinline__ unsigned int packhl(float x){
  unsigned int u = __float_as_uint(x);
  unsigned int h = u & 0xFFFF0000u;
  float xl = x - __uint_as_float(h);
  return h | (__float_as_uint(xl) >> 16);
}
__device__ __forceinline__ uint4v frag_hi(uint4v a, uint4v b){
  uint4v r;
  r.x = __builtin_amdgcn_perm(a.y, a.x, 0x07060302u);
  r.y = __builtin_amdgcn_perm(a.w, a.z, 0x07060302u);
  r.z = __builtin_amdgcn_perm(b.y, b.x, 0x07060302u);
  r.w = __builtin_amdgcn_perm(b.w, b.z, 0x07060302u);
  return r;
}
__device__ __forceinline__ uint4v frag_lo(uint4v a, uint4v b){
  uint4v r;
  r.x = __builtin_amdgcn_perm(a.y, a.x, 0x05040100u);
  r.y = __builtin_amdgcn_perm(a.w, a.z, 0x05040100u);
  r.z = __builtin_amdgcn_perm(b.y, b.x, 0x05040100u);
  r.w = __builtin_amdgcn_perm(b.w, b.z, 0x05040100u);
  return r;
}
__device__ __forceinline__ float blof(unsigned int h, unsigned int l){
  return __uint_as_float(h << 16) + __uint_as_float(l << 16);
}
__device__ __forceinline__ float bhif(unsigned int h, unsigned int l){
  return __uint_as_float(h & 0xFFFF0000u) + __uint_as_float(l & 0xFFFF0000u);
}
__device__ __forceinline__ f32x16 mfma32(bf16x8 a, bf16x8 b, f32x16 c){
  return __builtin_amdgcn_mfma_f32_32x32x16_bf16(a, b, c, 0, 0, 0);
}
__device__ __forceinline__ f32x4 mfma16(bf16x8 a, bf16x8 b, f32x4 c){
  return __builtin_amdgcn_mfma_f32_16x16x32_bf16(a, b, c, 0, 0, 0);
}
__device__ __forceinline__ void split16(float4 v0, float4 v1, float4 v2, float4 v3,
                                        unsigned short* hi, unsigned short* lo){
  uint4v hw0, hw1, lw0, lw1;
  hw0.x=hipack(v0.x,v0.y); hw0.y=hipack(v0.z,v0.w); hw0.z=hipack(v1.x,v1.y); hw0.w=hipack(v1.z,v1.w);
  hw1.x=hipack(v2.x,v2.y); hw1.y=hipack(v2.z,v2.w); hw1.z=hipack(v3.x,v3.y); hw1.w=hipack(v3.z,v3.w);
  lw0.x=lopack(v0.x,v0.y); lw0.y=lopack(v0.z,v0.w); lw0.z=lopack(v1.x,v1.y); lw0.w=lopack(v1.z,v1.w);
  lw1.x=lopack(v2.x,v2.y); lw1.y=lopack(v2.z,v2.w); lw1.z=lopack(v3.x,v3.y); lw1.w=lopack(v3.z,v3.w);
  *(uint4v*)hi = hw0; *(uint4v*)(hi+8) = hw1;
  *(uint4v*)lo = lw0; *(uint4v*)(lo+8) = lw1;
}
__device__ __forceinline__ void split8(float4 v0, float4 v1,
                                       unsigned short* hi, unsigned short* lo){
  uint4v hw, lw;
  hw.x=hipack(v0.x,v0.y); hw.y=hipack(v0.z,v0.w); hw.z=hipack(v1.x,v1.y); hw.w=hipack(v1.z,v1.w);
  lw.x=lopack(v0.x,v0.y); lw.y=lopack(v0.z,v0.w); lw.z=lopack(v1.x,v1.y); lw.w=lopack(v1.z,v1.w);
  *(uint4v*)hi = hw; *(uint4v*)lo = lw;
}

// ===== Forward Kalman filter: 1 wave/batch, MFMA bf16-split matmuls, no barriers =====
__global__ __launch_bounds__(64) void kf_forward(
    const float* __restrict__ Yg, const float* __restrict__ Ug,
    const float* __restrict__ Ag, const float* __restrict__ Bg,
    const float* __restrict__ Cg, const float* __restrict__ mu0g,
    const float* __restrict__ Sig0g,
    float* __restrict__ outg, float* __restrict__ wsSig, float* __restrict__ wsMu)
{
  const int l   = threadIdx.x;
  const int b   = blockIdx.x;
  const int c32 = l & 31;
  const int h   = l >> 5;            // 0/1
  const int c16 = l & 15;
  const int q4  = l >> 4;            // 0..3
  const int kofA = h * 8;
  const int kofC = q4 * 8;
  const int rA = l >> 1, cA = (l & 1) << 4;
  const int rC = l >> 2, cC = (l & 3) << 3;
  const int row = c16, g = q4;

  __shared__ __align__(16) unsigned short Ahi[32][40], Alo[32][40];
  __shared__ __align__(16) unsigned short Chi[16][40], Clo[16][40];
  __shared__ __align__(16) unsigned short Ghi[32][40], Glo[32][40];
  __shared__ __align__(16) unsigned short Phi[32][40], Plo[32][40];
  __shared__ __align__(16) unsigned short Yhi[32][24], Ylo[32][24];
  __shared__ __align__(16) unsigned int   T1P[32][40];
  __shared__ __align__(16) unsigned int   ZP[16][40];
  __shared__ __align__(16) unsigned int   KtTP[32][24];
  __shared__ __align__(16) float SLf[16][20];
  __shared__ __align__(16) float CSf[16][40];
  __shared__ __align__(16) float Bm[32][12];
  __shared__ __align__(16) float muf[32], mupf[32], rvf[16], yvf[16], uvf[8];

  const size_t bt0 = (size_t)b * TT;

  {
    const float* ap = Ag + bt0*1024 + rA*32 + cA;
    split16(*(const float4*)(ap+0), *(const float4*)(ap+4),
            *(const float4*)(ap+8), *(const float4*)(ap+12),
            &Ahi[rA][cA], &Alo[rA][cA]);
    const float* sp0 = Sig0g + rA*32 + cA;
    split16(*(const float4*)(sp0+0), *(const float4*)(sp0+4),
            *(const float4*)(sp0+8), *(const float4*)(sp0+12),
            &Ghi[rA][cA], &Glo[rA][cA]);
    const float* cp = Cg + bt0*512 + rC*32 + cC;
    split8(*(const float4*)(cp+0), *(const float4*)(cp+4),
           &Chi[rC][cC], &Clo[rC][cC]);
    *(float4*)&Bm[l>>1][(l&1)*4] = *(const float4*)(Bg + bt0*256 + (l>>1)*8 + (l&1)*4);
    if (l < 32) muf[l] = mu0g[l];
    if (l < 16) yvf[l] = Yg[bt0*16 + l];
    if (l < 8)  uvf[l] = Ug[bt0*8 + l];
  }

  for (int t = 0; t < TT; ++t) {
    const size_t bt = bt0 + t;

    // ---- P1: T1 = A * Sigma ----
    U8 a_h0, a_h1, a_l0, a_l1, s_h0, s_h1, s_l0, s_l1;
    a_h0.u = *(const uint4v*)&Ahi[c32][0  + kofA];
    a_h1.u = *(const uint4v*)&Ahi[c32][16 + kofA];
    a_l0.u = *(const uint4v*)&Alo[c32][0  + kofA];
    a_l1.u = *(const uint4v*)&Alo[c32][16 + kofA];
    s_h0.u = *(const uint4v*)&Ghi[c32][0  + kofA];
    s_h1.u = *(const uint4v*)&Ghi[c32][16 + kofA];
    s_l0.u = *(const uint4v*)&Glo[c32][0  + kofA];
    s_l1.u = *(const uint4v*)&Glo[c32][16 + kofA];
    f32x16 t1;
    #pragma unroll
    for (int r=0;r<16;++r) t1[r] = 0.f;
    t1 = mfma32(a_h0.b, s_h0.b, t1);
    t1 = mfma32(a_h1.b, s_h1.b, t1);
    t1 = mfma32(a_h0.b, s_l0.b, t1);
    t1 = mfma32(a_h1.b, s_l1.b, t1);
    t1 = mfma32(a_l0.b, s_h0.b, t1);
    t1 = mfma32(a_l1.b, s_h1.b, t1);
    #pragma unroll
    for (int r=0;r<16;++r){
      int rr = (r&3) + 8*(r>>2) + 4*h;
      T1P[rr][c32] = packhl(t1[r]);
    }
    // mu_p = A*mu + B*u
    float part = 0.f;
    {
      float4 m0 = *(const float4*)&muf[kofA];
      float4 m1 = *(const float4*)&muf[kofA+4];
      float4 m2 = *(const float4*)&muf[16+kofA];
      float4 m3 = *(const float4*)&muf[16+kofA+4];
      part = fmaf(blof(a_h0.u.x,a_l0.u.x), m0.x, part);
      part = fmaf(bhif(a_h0.u.x,a_l0.u.x), m0.y, part);
      part = fmaf(blof(a_h0.u.y,a_l0.u.y), m0.z, part);
      part = fmaf(bhif(a_h0.u.y,a_l0.u.y), m0.w, part);
      part = fmaf(blof(a_h0.u.z,a_l0.u.z), m1.x, part);
      part = fmaf(bhif(a_h0.u.z,a_l0.u.z), m1.y, part);
      part = fmaf(blof(a_h0.u.w,a_l0.u.w), m1.z, part);
      part = fmaf(bhif(a_h0.u.w,a_l0.u.w), m1.w, part);
      part = fmaf(blof(a_h1.u.x,a_l1.u.x), m2.x, part);
      part = fmaf(bhif(a_h1.u.x,a_l1.u.x), m2.y, part);
      part = fmaf(blof(a_h1.u.y,a_l1.u.y), m2.z, part);
      part = fmaf(bhif(a_h1.u.y,a_l1.u.y), m2.w, part);
      part = fmaf(blof(a_h1.u.z,a_l1.u.z), m3.x, part);
      part = fmaf(bhif(a_h1.u.z,a_l1.u.z), m3.y, part);
      part = fmaf(blof(a_h1.u.w,a_l1.u.w), m3.z, part);
      part = fmaf(bhif(a_h1.u.w,a_l1.u.w), m3.w, part);
    }
    part += __shfl_xor(part, 32);
    {
      float4 b0 = *(const float4*)&Bm[c32][0];
      float4 b1 = *(const float4*)&Bm[c32][4];
      float4 u0 = *(const float4*)&uvf[0];
      float4 u1 = *(const float4*)&uvf[4];
      part = fmaf(b0.x,u0.x, fmaf(b0.y,u0.y, fmaf(b0.z,u0.z, fmaf(b0.w,u0.w, part))));
      part = fmaf(b1.x,u1.x, fmaf(b1.y,u1.y, fmaf(b1.z,u1.z, fmaf(b1.w,u1.w, part))));
    }
    if (l < 32){ mupf[c32] = part; wsMu[bt*32 + c32] = part; }

    // ---- P2: Sigma_p = A * T1^T + Q ----
    U8 b_h0, b_h1, b_l0, b_l1;
    {
      uint4v p0  = *(const uint4v*)&T1P[c32][0  + kofA];
      uint4v p0b = *(const uint4v*)&T1P[c32][4  + kofA];
      uint4v p1  = *(const uint4v*)&T1P[c32][16 + kofA];
      uint4v p1b = *(const uint4v*)&T1P[c32][20 + kofA];
      b_h0.u = frag_hi(p0, p0b); b_l0.u = frag_lo(p0, p0b);
      b_h1.u = frag_hi(p1, p1b); b_l1.u = frag_lo(p1, p1b);
    }
    f32x16 sp;
    #pragma unroll
    for (int r=0;r<16;++r) sp[r] = 0.f;
    sp = mfma32(a_h0.b, b_h0.b, sp);
    sp = mfma32(a_h1.b, b_h1.b, sp);
    sp = mfma32(a_h0.b, b_l0.b, sp);
    sp = mfma32(a_h1.b, b_l1.b, sp);
    sp = mfma32(a_l0.b, b_h0.b, sp);
    sp = mfma32(a_l1.b, b_h1.b, sp);
    #pragma unroll
    for (int r=0;r<16;++r){
      int rr = (r&3) + 8*(r>>2) + 4*h;
      if (rr == c32) sp[r] += 0.01f;
    }
    {
      float* wp = wsSig + (bt*32 + c32)*32;
      *(float4*)(wp + 0  + 4*h) = make_float4(sp[0], sp[1], sp[2], sp[3]);
      *(float4*)(wp + 8  + 4*h) = make_float4(sp[4], sp[5], sp[6], sp[7]);
      *(float4*)(wp + 16 + 4*h) = make_float4(sp[8], sp[9], sp[10],sp[11]);
      *(float4*)(wp + 24 + 4*h) = make_float4(sp[12],sp[13],sp[14],sp[15]);
      #pragma unroll
      for (int gq=0; gq<4; ++gq){
        uint2v hw, lw;
        hw.x = hipack(sp[4*gq+0], sp[4*gq+1]); hw.y = hipack(sp[4*gq+2], sp[4*gq+3]);
        lw.x = lopack(sp[4*gq+0], sp[4*gq+1]); lw.y = lopack(sp[4*gq+2], sp[4*gq+3]);
        *(uint2v*)&Phi[c32][8*gq + 4*h] = hw;
        *(uint2v*)&Plo[c32][8*gq + 4*h] = lw;
      }
    }

    // ---- P3: CS = C * Sigma_p ----
    U8 c_h, c_l, p_h0, p_l0, p_h1, p_l1;
    c_h.u  = *(const uint4v*)&Chi[c16][kofC];
    c_l.u  = *(const uint4v*)&Clo[c16][kofC];
    p_h0.u = *(const uint4v*)&Phi[c16][kofC];
    p_l0.u = *(const uint4v*)&Plo[c16][kofC];
    p_h1.u = *(const uint4v*)&Phi[16+c16][kofC];
    p_l1.u = *(const uint4v*)&Plo[16+c16][kofC];
    f32x4 cs0, cs1;
    #pragma unroll
    for (int r=0;r<4;++r){ cs0[r]=0.f; cs1[r]=0.f; }
    cs0 = mfma16(c_h.b, p_h0.b, cs0);
    cs0 = mfma16(c_h.b, p_l0.b, cs0);
    cs0 = mfma16(c_l.b, p_h0.b, cs0);
    cs1 = mfma16(c_h.b, p_h1.b, cs1);
    cs1 = mfma16(c_h.b, p_l1.b, cs1);
    cs1 = mfma16(c_l.b, p_h1.b, cs1);
    #pragma unroll
    for (int r=0;r<4;++r){
      int rr = q4*4 + r;
      ZP[rr][c16]     = packhl(cs0[r]);
      ZP[rr][16+c16]  = packhl(cs1[r]);
      CSf[rr][c16]    = cs0[r];
      CSf[rr][16+c16] = cs1[r];
    }
    {
      uint2v hw0, lw0, hw1, lw1;
      hw0.x = hipack(cs0[0],cs0[1]); hw0.y = hipack(cs0[2],cs0[3]);
      lw0.x = lopack(cs0[0],cs0[1]); lw0.y = lopack(cs0[2],cs0[3]);
      hw1.x = hipack(cs1[0],cs1[1]); hw1.y = hipack(cs1[2],cs1[3]);
      lw1.x = lopack(cs1[0],cs1[1]); lw1.y = lopack(cs1[2],cs1[3]);
      *(uint2v*)&Yhi[c16][q4*4]    = hw0; *(uint2v*)&Ylo[c16][q4*4]    = lw0;
      *(uint2v*)&Yhi[16+c16][q4*4] = hw1; *(uint2v*)&Ylo[16+c16][q4*4] = lw1;
    }
    // r = y - C*mu_p
    {
      float prr = 0.f;
      float4 m0 = *(const float4*)&mupf[kofC];
      float4 m1 = *(const float4*)&mupf[kofC+4];
      prr = fmaf(blof(c_h.u.x,c_l.u.x), m0.x, prr);
      prr = fmaf(bhif(c_h.u.x,c_l.u.x), m0.y, prr);
      prr = fmaf(blof(c_h.u.y,c_l.u.y), m0.z, prr);
      prr = fmaf(bhif(c_h.u.y,c_l.u.y), m0.w, prr);
      prr = fmaf(blof(c_h.u.z,c_l.u.z), m1.x, prr);
      prr = fmaf(bhif(c_h.u.z,c_l.u.z), m1.y, prr);
      prr = fmaf(blof(c_h.u.w,c_l.u.w), m1.z, prr);
      prr = fmaf(bhif(c_h.u.w,c_l.u.w), m1.w, prr);
      prr += __shfl_xor(prr, 16);
      prr += __shfl_xor(prr, 32);
      if (l < 16) rvf[l] = yvf[l] - prr;
    }

    // ---- P4: S = CS * C^T + R ----
    {
      U8 z_h, z_l;
      uint4v pz0 = *(const uint4v*)&ZP[c16][kofC];
      uint4v pz1 = *(const uint4v*)&ZP[c16][kofC+4];
      z_h.u = frag_hi(pz0, pz1); z_l.u = frag_lo(pz0, pz1);
      f32x4 ss;
      #pragma unroll
      for (int r=0;r<4;++r) ss[r] = 0.f;
      ss = mfma16(z_h.b, c_h.b, ss);
      ss = mfma16(z_h.b, c_l.b, ss);
      ss = mfma16(z_l.b, c_h.b, ss);
      #pragma unroll
      for (int r=0;r<4;++r){
        int rr = q4*4 + r;
        SLf[rr][c16] = ss[r] + ((rr == c16) ? 0.01f : 0.f);
      }
    }

    // ---- prefetch next-step inputs ----
    float4 pa0, pa1, pa2, pa3, pc0, pc1, pbv;
    float py = 0.f, pu = 0.f;
    pa0=pa1=pa2=pa3=make_float4(0.f,0.f,0.f,0.f);
    pc0=pc1=pbv=make_float4(0.f,0.f,0.f,0.f);
    if (t + 1 < TT){
      const float* ap = Ag + (bt+1)*1024 + rA*32 + cA;
      pa0 = *(const float4*)(ap+0);  pa1 = *(const float4*)(ap+4);
      pa2 = *(const float4*)(ap+8);  pa3 = *(const float4*)(ap+12);
      const float* cp = Cg + (bt+1)*512 + rC*32 + cC;
      pc0 = *(const float4*)(cp+0);  pc1 = *(const float4*)(cp+4);
      pbv = *(const float4*)(Bg + (bt+1)*256 + (l>>1)*8 + (l&1)*4);
      if (l < 16) py = Yg[(bt+1)*16 + l];
      if (l < 8)  pu = Ug[(bt+1)*8 + l];
    }

    // ---- P5: register Gauss-Jordan, NO in-loop pivot normalization ----
    {
      float aug[16];
      if (g == 0){
        float tmp[16];
        #pragma unroll
        for (int q=0;q<4;++q){
          float4 v = *(const float4*)&SLf[row][4*q];
          tmp[4*q]=v.x; tmp[4*q+1]=v.y; tmp[4*q+2]=v.z; tmp[4*q+3]=v.w;
        }
        #pragma unroll
        for (int c2=0;c2<16;++c2) aug[c2] = 0.5f*(tmp[c2] + SLf[c2][row]);
      } else if (g <= 2){
        #pragma unroll
        for (int q=0;q<4;++q){
          float4 v = *(const float4*)&CSf[row][(g-1)*16 + 4*q];
          aug[4*q]=v.x; aug[4*q+1]=v.y; aug[4*q+2]=v.z; aug[4*q+3]=v.w;
        }
      } else {
        #pragma unroll
        for (int c2=0;c2<16;++c2) aug[c2] = 0.f;
      }
      const int psrc = g << 4;
      #pragma unroll
      for (int k=0;k<16;++k){
        float f   = __shfl(aug[k], row);
        float piv = __shfl(aug[k], k);
        float prc = frcp(piv);
        float pr[16];
        #pragma unroll
        for (int c2=0;c2<16;++c2) pr[c2] = __shfl(aug[c2], k + psrc);
        float fn = (row == k) ? 0.f : f*prc;
        #pragma unroll
        for (int c2=0;c2<16;++c2) aug[c2] = fmaf(-fn, pr[c2], aug[c2]);
      }
      // S-part is now diagonal on g0 lanes; recover d_row as the row sum.
      float dsum = 0.f;
      #pragma unroll
      for (int c2=0;c2<16;++c2) dsum += aug[c2];
      float rcpd = frcp(__shfl(dsum, row));
      if (g == 1 || g == 2){
        #pragma unroll
        for (int c2=0;c2<16;++c2) KtTP[(g-1)*16 + c2][row] = packhl(-aug[c2]*rcpd);
      }
    }

    // ---- P6: Sigma_f = Sigma_p - CS^T * Kt ----
    f32x16 sf = sp;
    {
      U8 y_h, y_l, kt_h, kt_l;
      y_h.u = *(const uint4v*)&Yhi[c32][8*h];
      y_l.u = *(const uint4v*)&Ylo[c32][8*h];
      uint4v k0 = *(const uint4v*)&KtTP[c32][8*h];
      uint4v k1 = *(const uint4v*)&KtTP[c32][8*h+4];
      kt_h.u = frag_hi(k0, k1); kt_l.u = frag_lo(k0, k1);
      sf = mfma32(y_h.b, kt_h.b, sf);
      sf = mfma32(y_h.b, kt_l.b, sf);
      sf = mfma32(y_l.b, kt_h.b, sf);
    }
    #pragma unroll
    for (int gq=0; gq<4; ++gq){
      uint2v hw, lw;
      hw.x = hipack(sf[4*gq+0], sf[4*gq+1]); hw.y = hipack(sf[4*gq+2], sf[4*gq+3]);
      lw.x = lopack(sf[4*gq+0], sf[4*gq+1]); lw.y = lopack(sf[4*gq+2], sf[4*gq+3]);
      *(uint2v*)&Ghi[c32][8*gq + 4*h] = hw;
      *(uint2v*)&Glo[c32][8*gq + 4*h] = lw;
    }
    {
      float* ob = outg + (bt*32)*33;
      #pragma unroll
      for (int r=0;r<16;++r){
        int rr = (r&3) + 8*(r>>2) + 4*h;
        ob[rr*33 + 1 + c32] = sf[r];
      }
      float mf = mupf[c32];
      uint4v w0 = *(const uint4v*)&KtTP[c32][0];
      uint4v w1 = *(const uint4v*)&KtTP[c32][4];
      uint4v w2 = *(const uint4v*)&KtTP[c32][8];
      uint4v w3 = *(const uint4v*)&KtTP[c32][12];
      float4 r0 = *(const float4*)&rvf[0];
      float4 r1 = *(const float4*)&rvf[4];
      float4 r2 = *(const float4*)&rvf[8];
      float4 r3 = *(const float4*)&rvf[12];
      mf = fmaf(-(bhif(w0.x,0u)+blof(0u,w0.x)), r0.x, mf);
      mf = fmaf(-(bhif(w0.y,0u)+blof(0u,w0.y)), r0.y, mf);
      mf = fmaf(-(bhif(w0.z,0u)+blof(0u,w0.z)), r0.z, mf);
      mf = fmaf(-(bhif(w0.w,0u)+blof(0u,w0.w)), r0.w, mf);
      mf = fmaf(-(bhif(w1.x,0u)+blof(0u,w1.x)), r1.x, mf);
      mf = fmaf(-(bhif(w1.y,0u)+blof(0u,w1.y)), r1.y, mf);
      mf = fmaf(-(bhif(w1.z,0u)+blof(0u,w1.z)), r1.z, mf);
      mf = fmaf(-(bhif(w1.w,0u)+blof(0u,w1.w)), r1.w, mf);
      mf = fmaf(-(bhif(w2.x,0u)+blof(0u,w2.x)), r2.x, mf);
      mf = fmaf(-(bhif(w2.y,0u)+blof(0u,w2.y)), r2.y, mf);
      mf = fmaf(-(bhif(w2.z,0u)+blof(0u,w2.z)), r2.z, mf);
      mf = fmaf(-(bhif(w2.w,0u)+blof(0u,w2.w)), r2.w, mf);
      mf = fmaf(-(bhif(w3.x,0u)+blof(0u,w3.x)), r3.x, mf);
      mf = fmaf(-(bhif(w3.y,0u)+blof(0u,w3.y)), r3.y, mf);
      mf = fmaf(-(bhif(w3.z,0u)+blof(0u,w3.z)), r3.z, mf);
      mf = fmaf(-(bhif(w3.w,0u)+blof(0u,w3.w)), r3.w, mf);
      if (l < 32){ muf[c32] = mf; ob[c32*33] = mf; }
    }

    // ---- P7: stage next-step inputs ----
    if (t + 1 < TT){
      split16(pa0, pa1, pa2, pa3, &Ahi[rA][cA], &Alo[rA][cA]);
      split8(pc0, pc1, &Chi[rC][cC], &Clo[rC][cC]);
      *(float4*)&Bm[l>>1][(l&1)*4] = pbv;
      if (l < 16) yvf[l] = py;
      if (l < 8)  uvf[l] = pu;
    }
  }
}

// ------- Parallel smoother precompute: J_t, E_t, e_t for t=0..T-2 (unchanged) -------
__global__ __launch_bounds__(256) void kf_precomp(
    const float* __restrict__ Ag, float* __restrict__ outg,
    float* __restrict__ wsSig, float* __restrict__ wsMu)
{
  const int t = blockIdx.x;
  const int b = blockIdx.y;
  const int tid = threadIdx.x;
  const int i32 = tid >> 3;
  const int j4 = (tid & 7) << 2;
  __shared__ __align__(16) float Sf[NSZ][LD];
  __shared__ __align__(16) float AT2[NSZ][LD];
  __shared__ __align__(16) float Mm[NSZ][LD];
  __shared__ __align__(16) float Pm[NSZ][LD];
  __shared__ __align__(16) float V[NSZ][LD];
  __shared__ __align__(16) float Jl[NSZ][LD];
  __shared__ __align__(16) float JTs[NSZ][LD];
  __shared__ __align__(16) float prow[NSZ];
  __shared__ __align__(16) float vrow[NSZ];
  __shared__ float mfv[NSZ], mp1[NSZ];
  const size_t bt = (size_t)b*TT + t;
  {
    const float* os = outg + bt*NSZ*(NSZ+1);
    #pragma unroll
    for (int r = 0; r < 4; ++r) {
      int e = tid + 256*r; int i = e >> 5, j = e & 31;
      Sf[i][j] = os[i*(NSZ+1) + 1 + j];
    }
    if (tid < NSZ) mfv[tid] = os[tid*(NSZ+1)];
    float4 a4 = *(const float4*)(Ag + bt*(NSZ*NSZ) + tid*4);
    AT2[j4+0][i32]=a4.x; AT2[j4+1][i32]=a4.y; AT2[j4+2][i32]=a4.z; AT2[j4+3][i32]=a4.w;
    *(float4*)&Pm[i32][j4] = *(const float4*)(wsSig + ((bt+1)*NSZ + i32)*NSZ + j4);
    if (tid < NSZ) mp1[tid] = wsMu[(bt+1)*NSZ + tid];
    float4 vi;
    vi.x = (i32 == j4+0) ? 1.f : 0.f;
    vi.y = (i32 == j4+1) ? 1.f : 0.f;
    vi.z = (i32 == j4+2) ? 1.f : 0.f;
    vi.w = (i32 == j4+3) ? 1.f : 0.f;
    *(float4*)&V[i32][j4] = vi;
  }
  __syncthreads();
  {
    float4 acc = make_float4(0.f,0.f,0.f,0.f);
    #pragma unroll
    for (int k0 = 0; k0 < NSZ; k0 += 4) {
      float4 s = *(const float4*)&Sf[i32][k0];
      fma4(acc, s.x, *(const float4*)&AT2[k0+0][j4]);
      fma4(acc, s.y, *(const float4*)&AT2[k0+1][j4]);
      fma4(acc, s.z, *(const float4*)&AT2[k0+2][j4]);
      fma4(acc, s.w, *(const float4*)&AT2[k0+3][j4]);
    }
    *(float4*)&Mm[i32][j4] = acc;
  }
  __syncthreads();
  for (int k = 0; k < NSZ; ++k) {
    float f = Pm[i32][k];
    if (tid < 8) {
      float rd = frcp(Pm[k][k]);
      #pragma unroll
      for (int m = 0; m < 4; ++m) prow[tid*4+m] = Pm[k][tid*4+m] * rd;
    } else if (tid < 16) {
      float rd = frcp(Pm[k][k]);
      const int c0 = (tid-8)*4;
      #pragma unroll
      for (int m = 0; m < 4; ++m) vrow[c0+m] = V[k][c0+m] * rd;
    }
    __syncthreads();
    if (i32 == k) {
      *(float4*)&Pm[k][j4] = *(const float4*)&prow[j4];
      *(float4*)&V[k][j4] = *(const float4*)&vrow[j4];
    } else {
      float4 p = *(const float4*)&Pm[i32][j4];
      float4 v = *(const float4*)&V[i32][j4];
      fma4(p, -f, *(const float4*)&prow[j4]);
      fma4(v, -f, *(const float4*)&vrow[j4]);
      *(float4*)&Pm[i32][j4] = p;
      *(float4*)&V[i32][j4] = v;
    }
    __syncthreads();
  }
  {
    float4 acc = make_float4(0.f,0.f,0.f,0.f);
    #pragma unroll
    for (int k0 = 0; k0 < NSZ; k0 += 4) {
      float4 m4 = *(const float4*)&Mm[i32][k0];
      fma4(acc, m4.x, *(const float4*)&V[k0+0][j4]);
      fma4(acc, m4.y, *(const float4*)&V[k0+1][j4]);
      fma4(acc, m4.z, *(const float4*)&V[k0+2][j4]);
      fma4(acc, m4.w, *(const float4*)&V[k0+3][j4]);
    }
    *(float4*)&Jl[i32][j4] = acc;
    JTs[j4+0][i32]=acc.x; JTs[j4+1][i32]=acc.y; JTs[j4+2][i32]=acc.z; JTs[j4+3][i32]=acc.w;
    *(float4*)(wsSig + ((bt+1)*NSZ + i32)*NSZ + j4) = acc;
  }
  __syncthreads();
  {
    float4 acc = make_float4(0.f,0.f,0.f,0.f);
    #pragma unroll
    for (int k0 = 0; k0 < NSZ; k0 += 4) {
      float4 m4 = *(const float4*)&Mm[i32][k0];
      fma4(acc, m4.x, *(const float4*)&JTs[k0+0][j4]);
      fma4(acc, m4.y, *(const float4*)&JTs[k0+1][j4]);
      fma4(acc, m4.z, *(const float4*)&JTs[k0+2][j4]);
      fma4(acc, m4.w, *(const float4*)&JTs[k0+3][j4]);
    }
    float* os = outg + bt*NSZ*(NSZ+1);
    os[i32*(NSZ+1)+1+j4+0] = Sf[i32][j4+0] - acc.x;
    os[i32*(NSZ+1)+1+j4+1] = Sf[i32][j4+1] - acc.y;
    os[i32*(NSZ+1)+1+j4+2] = Sf[i32][j4+2] - acc.z;
    os[i32*(NSZ+1)+1+j4+3] = Sf[i32][j4+3] - acc.w;
    if (tid < NSZ) {
      float e2 = mfv[tid];
      #pragma unroll
      for (int k = 0; k < NSZ; ++k) e2 = fmaf(-Jl[tid][k], mp1[k], e2);
      os[tid*(NSZ+1)] = e2;
    }
  }
}

// ===== Backward smoother: 1 WAVE per batch, MFMA bf16-split, no barriers =====
__global__ __launch_bounds__(64) void kf_backward(
    float* __restrict__ outg, const float* __restrict__ wsSig)
{
  const int l   = threadIdx.x;
  const int b   = blockIdx.x;
  const int c32 = l & 31;
  const int h   = l >> 5;
  const int kofA = h * 8;
  const int rA = l >> 1, cA = (l & 1) << 4;

  __shared__ __align__(16) unsigned short Jhi[32][40], Jlo[32][40];
  __shared__ __align__(16) unsigned int   SP[32][36];   // Sigma_s packed hi|lo, SP[i][k]=Sig_s[k][i]
  __shared__ __align__(16) unsigned int   WP[32][36];   // W rows packed
  __shared__ float muv[32];

  const size_t base = (size_t)b * TT;

  float er[16]; float ev;
  {
    // Sigma_s init = Sigma_f[T-1] (row-major; symmetric so SP convention holds)
    const float* os = outg + (base + TT - 1)*32*33;
    const float* rp = os + rA*33 + 1 + cA;
    float4 v0 = *(const float4*)(rp+0), v1 = *(const float4*)(rp+4),
           v2 = *(const float4*)(rp+8), v3 = *(const float4*)(rp+12);
    uint4v u0, u1;
    u0.x = packhl(v0.x); u0.y = packhl(v0.y); u0.z = packhl(v0.z); u0.w = packhl(v0.w);
    u1.x = packhl(v1.x); u1.y = packhl(v1.y); u1.z = packhl(v1.z); u1.w = packhl(v1.w);
    *(uint4v*)&SP[rA][cA+0] = u0; *(uint4v*)&SP[rA][cA+4] = u1;
    u0.x = packhl(v2.x); u0.y = packhl(v2.y); u0.z = packhl(v2.z); u0.w = packhl(v2.w);
    u1.x = packhl(v3.x); u1.y = packhl(v3.y); u1.z = packhl(v3.z); u1.w = packhl(v3.w);
    *(uint4v*)&SP[rA][cA+8] = u0; *(uint4v*)&SP[rA][cA+12] = u1;
    if (l < 32) muv[l] = os[l*33];
    // J_{T-2} lives at slot base+T-1
    const float* jp = wsSig + ((base + TT - 1)*32 + rA)*32 + cA;
    split16(*(const float4*)(jp+0), *(const float4*)(jp+4),
            *(const float4*)(jp+8), *(const float4*)(jp+12),
            &Jhi[rA][cA], &Jlo[rA][cA]);
    // E/e of t = T-2
    const float* oe = outg + (base + TT - 2)*32*33;
    #pragma unroll
    for (int r=0;r<16;++r){
      int rr = (r&3) + 8*(r>>2) + 4*h;
      er[r] = oe[rr*33 + 1 + c32];
    }
    ev = (l < 32) ? oe[l*33] : 0.f;
  }

  for (int t = TT - 2; t >= 0; --t) {
    // ---- prefetch next iteration: J_{t-1} (slot base+t), E/e (slot t-1) ----
    float4 pj0, pj1, pj2, pj3; float ner[16]; float nev = 0.f;
    if (t > 0) {
      const float* jp = wsSig + ((base + t)*32 + rA)*32 + cA;
      pj0 = *(const float4*)(jp+0);  pj1 = *(const float4*)(jp+4);
      pj2 = *(const float4*)(jp+8);  pj3 = *(const float4*)(jp+12);
      const float* oe = outg + (base + t - 1)*32*33;
      #pragma unroll
      for (int r=0;r<16;++r){
        int rr = (r&3) + 8*(r>>2) + 4*h;
        ner[r] = oe[rr*33 + 1 + c32];
      }
      if (l < 32) nev = oe[l*33];
    } else {
      pj0=pj1=pj2=pj3=make_float4(0.f,0.f,0.f,0.f);
      #pragma unroll
      for (int r=0;r<16;++r) ner[r] = 0.f;
    }

    // ---- J fragments (serve as both A-op rows and B-op for J^T) ----
    U8 a_h0, a_h1, a_l0, a_l1;
    a_h0.u = *(const uint4v*)&Jhi[c32][0  + kofA];
    a_h1.u = *(const uint4v*)&Jhi[c32][16 + kofA];
    a_l0.u = *(const uint4v*)&Jlo[c32][0  + kofA];
    a_l1.u = *(const uint4v*)&Jlo[c32][16 + kofA];
    // ---- Sigma_s fragments (B-op): SP[c32][k] = Sig_s[k][c32] ----
    U8 s_h0, s_l0, s_h1, s_l1;
    {
      uint4v ua = *(const uint4v*)&SP[c32][0  + kofA];
      uint4v ub = *(const uint4v*)&SP[c32][4  + kofA];
      uint4v uc = *(const uint4v*)&SP[c32][16 + kofA];
      uint4v ud = *(const uint4v*)&SP[c32][20 + kofA];
      s_h0.u = frag_hi(ua, ub); s_l0.u = frag_lo(ua, ub);
      s_h1.u = frag_hi(uc, ud); s_l1.u = frag_lo(uc, ud);
    }
    // ---- W = J * Sigma_s ----
    f32x16 w;
    #pragma unroll
    for (int r=0;r<16;++r) w[r] = 0.f;
    w = mfma32(a_h0.b, s_h0.b, w);
    w = mfma32(a_h1.b, s_h1.b, w);
    w = mfma32(a_h0.b, s_l0.b, w);
    w = mfma32(a_h1.b, s_l1.b, w);
    w = mfma32(a_l0.b, s_h0.b, w);
    w = mfma32(a_l1.b, s_h1.b, w);
    #pragma unroll
    for (int r=0;r<16;++r){
      int rr = (r&3) + 8*(r>>2) + 4*h;
      WP[rr][c32] = packhl(w[r]);
    }
    // ---- G = E + W * J^T ----
    U8 w_h0, w_l0, w_h1, w_l1;
    {
      uint4v ua = *(const uint4v*)&WP[c32][0  + kofA];
      uint4v ub = *(const uint4v*)&WP[c32][4  + kofA];
      uint4v uc = *(const uint4v*)&WP[c32][16 + kofA];
      uint4v ud = *(const uint4v*)&WP[c32][20 + kofA];
      w_h0.u = frag_hi(ua, ub); w_l0.u = frag_lo(ua, ub);
      w_h1.u = frag_hi(uc, ud); w_l1.u = frag_lo(uc, ud);
    }
    f32x16 gacc;
    #pragma unroll
    for (int r=0;r<16;++r) gacc[r] = er[r];
    gacc = mfma32(w_h0.b, a_h0.b, gacc);
    gacc = mfma32(w_h1.b, a_h1.b, gacc);
    gacc = mfma32(w_h0.b, a_l0.b, gacc);
    gacc = mfma32(w_h1.b, a_l1.b, gacc);
    gacc = mfma32(w_l0.b, a_h0.b, gacc);
    gacc = mfma32(w_l1.b, a_h1.b, gacc);

    // ---- mu_s = e + J * mu_s ----
    float part = 0.f;
    {
      float4 m0 = *(const float4*)&muv[kofA];
      float4 m1 = *(const float4*)&muv[kofA+4];
      float4 m2 = *(const float4*)&muv[16+kofA];
      float4 m3 = *(const float4*)&muv[16+kofA+4];
      part = fmaf(blof(a_h0.u.x,a_l0.u.x), m0.x, part);
      part = fmaf(bhif(a_h0.u.x,a_l0.u.x), m0.y, part);
      part = fmaf(blof(a_h0.u.y,a_l0.u.y), m0.z, part);
      part = fmaf(bhif(a_h0.u.y,a_l0.u.y), m0.w, part);
      part = fmaf(blof(a_h0.u.z,a_l0.u.z), m1.x, part);
      part = fmaf(bhif(a_h0.u.z,a_l0.u.z), m1.y, part);
      part = fmaf(blof(a_h0.u.w,a_l0.u.w), m1.z, part);
      part = fmaf(bhif(a_h0.u.w,a_l0.u.w), m1.w, part);
      part = fmaf(blof(a_h1.u.x,a_l1.u.x), m2.x, part);
      part = fmaf(bhif(a_h1.u.x,a_l1.u.x), m2.y, part);
      part = fmaf(blof(a_h1.u.y,a_l1.u.y), m2.z, part);
      part = fmaf(bhif(a_h1.u.y,a_l1.u.y), m2.w, part);
      part = fmaf(blof(a_h1.u.z,a_l1.u.z), m3.x, part);
      part = fmaf(bhif(a_h1.u.z,a_l1.u.z), m3.y, part);
      part = fmaf(blof(a_h1.u.w,a_l1.u.w), m3.z, part);
      part = fmaf(bhif(a_h1.u.w,a_l1.u.w), m3.w, part);
    }
    part += __shfl_xor(part, 32);
    float mn = ev + part;

    // ---- outputs + state update ----
    {
      float* ob = outg + ((base + t)*32)*33;
      #pragma unroll
      for (int r=0;r<16;++r){
        int rr = (r&3) + 8*(r>>2) + 4*h;
        ob[rr*33 + 1 + c32] = gacc[r];
      }
      // SP[c32][rr] = packhl(Sig_s_new[rr][c32]) so SP[i][k] = Sig_s[k][i]
      #pragma unroll
      for (int gq=0; gq<4; ++gq){
        uint4v uw;
        uw.x = packhl(gacc[4*gq+0]); uw.y = packhl(gacc[4*gq+1]);
        uw.z = packhl(gacc[4*gq+2]); uw.w = packhl(gacc[4*gq+3]);
        *(uint4v*)&SP[c32][8*gq + 4*h] = uw;
      }
      if (l < 32){ muv[l] = mn; ob[l*33] = mn; }
    }

    // ---- stage next J / E / e ----
    if (t > 0){
      split16(pj0, pj1, pj2, pj3, &Jhi[rA][cA], &Jlo[rA][cA]);
      #pragma unroll
      for (int r=0;r<16;++r) er[r] = ner[r];
      ev = nev;
    }
  }
}

extern "C" void kernel_launch(void* const* d_in, const int* in_sizes, int n_in,
                              void* d_out, int out_size, void* d_ws, size_t ws_size,
                              hipStream_t stream) {
  (void)in_sizes; (void)n_in; (void)out_size; (void)ws_size;
  const float* Yg   = (const float*)d_in[0];
  const float* Ug   = (const float*)d_in[1];
  const float* Ag   = (const float*)d_in[2];
  const float* Bg   = (const float*)d_in[3];
  const float* Cg   = (const float*)d_in[4];
  const float* mu0g = (const float*)d_in[5];
  const float* S0g  = (const float*)d_in[6];
  float* outg = (float*)d_out;
  float* wsSig = (float*)d_ws;
  float* wsMu  = wsSig + (size_t)NB*TT*NSZ*NSZ;

  hipLaunchKernelGGL(kf_forward, dim3(NB), dim3(64), 0, stream,
                     Yg, Ug, Ag, Bg, Cg, mu0g, S0g, outg, wsSig, wsMu);
  hipLaunchKernelGGL(kf_precomp, dim3(TT-1, NB), dim3(256), 0, stream,
                     Ag, outg, wsSig, wsMu);
  hipLaunchKernelGGL(kf_backward, dim3(NB), dim3(64), 0, stream,
                     outg, wsSig);
}

// Round 7
// 727.735 us; speedup vs baseline: 3.9897x; 1.3137x over previous
//
#include <hip/hip_runtime.h>

#define TT 128
#define NB 64
#define NSZ 32
#define MSZ 8
#define PSZ 16

typedef __attribute__((ext_vector_type(8)))  short bf16x8;
typedef __attribute__((ext_vector_type(16))) float f32x16;
typedef __attribute__((ext_vector_type(4)))  float f32x4;
typedef __attribute__((ext_vector_type(4)))  unsigned int uint4v;
typedef __attribute__((ext_vector_type(2)))  unsigned int uint2v;

union U8 { uint4v u; bf16x8 b; };

__device__ __forceinline__ float frcp(float x){ return __builtin_amdgcn_rcpf(x); }
__device__ __forceinline__ float rdl(float x, int lane){
  return __int_as_float(__builtin_amdgcn_readlane(__float_as_int(x), lane));
}
__device__ __forceinline__ void bar(){
  asm volatile("s_waitcnt lgkmcnt(0)" ::: "memory");
  __builtin_amdgcn_s_barrier();
  asm volatile("" ::: "memory");
}

// bf16 split helpers: hi = truncated top-16 of f32; lo = bf16(x - f32(hi)).
__device__ __forceinline__ unsigned int hipack(float x0, float x1){
  return __builtin_amdgcn_perm(__float_as_uint(x1), __float_as_uint(x0), 0x07060302u);
}
__device__ __forceinline__ unsigned int lopack(float x0, float x1){
  float l0 = x0 - __uint_as_float(__float_as_uint(x0) & 0xFFFF0000u);
  float l1 = x1 - __uint_as_float(__float_as_uint(x1) & 0xFFFF0000u);
  return __builtin_amdgcn_perm(__float_as_uint(l1), __float_as_uint(l0), 0x07060302u);
}
__device__ __forceinline__ unsigned int packhl(float x){
  unsigned int u = __float_as_uint(x);
  unsigned int h = u & 0xFFFF0000u;
  float xl = x - __uint_as_float(h);
  return h | (__float_as_uint(xl) >> 16);
}
__device__ __forceinline__ float unpk(unsigned int u){
  return __uint_as_float(u & 0xFFFF0000u) + __uint_as_float(u << 16);
}
__device__ __forceinline__ uint4v frag_hi(uint4v a, uint4v b){
  uint4v r;
  r.x = __builtin_amdgcn_perm(a.y, a.x, 0x07060302u);
  r.y = __builtin_amdgcn_perm(a.w, a.z, 0x07060302u);
  r.z = __builtin_amdgcn_perm(b.y, b.x, 0x07060302u);
  r.w = __builtin_amdgcn_perm(b.w, b.z, 0x07060302u);
  return r;
}
__device__ __forceinline__ uint4v frag_lo(uint4v a, uint4v b){
  uint4v r;
  r.x = __builtin_amdgcn_perm(a.y, a.x, 0x05040100u);
  r.y = __builtin_amdgcn_perm(a.w, a.z, 0x05040100u);
  r.z = __builtin_amdgcn_perm(b.y, b.x, 0x05040100u);
  r.w = __builtin_amdgcn_perm(b.w, b.z, 0x05040100u);
  return r;
}
__device__ __forceinline__ float blof(unsigned int h, unsigned int l){
  return __uint_as_float(h << 16) + __uint_as_float(l << 16);
}
__device__ __forceinline__ float bhif(unsigned int h, unsigned int l){
  return __uint_as_float(h & 0xFFFF0000u) + __uint_as_float(l & 0xFFFF0000u);
}
__device__ __forceinline__ f32x16 mfma32(bf16x8 a, bf16x8 b, f32x16 c){
  return __builtin_amdgcn_mfma_f32_32x32x16_bf16(a, b, c, 0, 0, 0);
}
__device__ __forceinline__ f32x4 mfma16(bf16x8 a, bf16x8 b, f32x4 c){
  return __builtin_amdgcn_mfma_f32_16x16x32_bf16(a, b, c, 0, 0, 0);
}
__device__ __forceinline__ void split16(float4 v0, float4 v1, float4 v2, float4 v3,
                                        unsigned short* hi, unsigned short* lo){
  uint4v hw0, hw1, lw0, lw1;
  hw0.x=hipack(v0.x,v0.y); hw0.y=hipack(v0.z,v0.w); hw0.z=hipack(v1.x,v1.y); hw0.w=hipack(v1.z,v1.w);
  hw1.x=hipack(v2.x,v2.y); hw1.y=hipack(v2.z,v2.w); hw1.z=hipack(v3.x,v3.y); hw1.w=hipack(v3.z,v3.w);
  lw0.x=lopack(v0.x,v0.y); lw0.y=lopack(v0.z,v0.w); lw0.z=lopack(v1.x,v1.y); lw0.w=lopack(v1.z,v1.w);
  lw1.x=lopack(v2.x,v2.y); lw1.y=lopack(v2.z,v2.w); lw1.z=lopack(v3.x,v3.y); lw1.w=lopack(v3.z,v3.w);
  *(uint4v*)hi = hw0; *(uint4v*)(hi+8) = hw1;
  *(uint4v*)lo = lw0; *(uint4v*)(lo+8) = lw1;
}
__device__ __forceinline__ void split8(float4 v0, float4 v1,
                                       unsigned short* hi, unsigned short* lo){
  uint4v hw, lw;
  hw.x=hipack(v0.x,v0.y); hw.y=hipack(v0.z,v0.w); hw.z=hipack(v1.x,v1.y); hw.w=hipack(v1.z,v1.w);
  lw.x=lopack(v0.x,v0.y); lw.y=lopack(v0.z,v0.w); lw.z=lopack(v1.x,v1.y); lw.w=lopack(v1.z,v1.w);
  *(uint4v*)hi = hw; *(uint4v*)lo = lw;
}
// pack 8 f32 (from float4 pair) into hi/lo bf16x8 fragments
#define MK8(v0, v1, HI, LO) do { \
  (HI).u.x = hipack((v0).x,(v0).y); (HI).u.y = hipack((v0).z,(v0).w); \
  (HI).u.z = hipack((v1).x,(v1).y); (HI).u.w = hipack((v1).z,(v1).w); \
  (LO).u.x = lopack((v0).x,(v0).y); (LO).u.y = lopack((v0).z,(v0).w); \
  (LO).u.z = lopack((v1).x,(v1).y); (LO).u.w = lopack((v1).z,(v1).w); \
} while(0)

// ===== Forward Kalman filter: 1 wave/batch, MFMA bf16-split matmuls, no barriers =====
__global__ __launch_bounds__(64) void kf_forward(
    const float* __restrict__ Yg, const float* __restrict__ Ug,
    const float* __restrict__ Ag, const float* __restrict__ Bg,
    const float* __restrict__ Cg, const float* __restrict__ mu0g,
    const float* __restrict__ Sig0g,
    float* __restrict__ outg, float* __restrict__ wsSig, float* __restrict__ wsMu)
{
  const int l   = threadIdx.x;
  const int b   = blockIdx.x;
  const int c32 = l & 31;
  const int h   = l >> 5;
  const int c16 = l & 15;
  const int q4  = l >> 4;
  const int kofA = h * 8;
  const int kofC = q4 * 8;
  const int rA = l >> 1, cA = (l & 1) << 4;
  const int rC = l >> 2, cC = (l & 3) << 3;

  __shared__ __align__(16) unsigned short Ahi[32][40], Alo[32][40];
  __shared__ __align__(16) unsigned short Chi[16][40], Clo[16][40];
  __shared__ __align__(16) unsigned short Ghi[32][40], Glo[32][40];
  __shared__ __align__(16) unsigned short Phi[32][40], Plo[32][40];
  __shared__ __align__(16) unsigned short Yhi[32][24], Ylo[32][24];
  __shared__ __align__(16) unsigned int   T1P[32][40];
  __shared__ __align__(16) unsigned int   ZP[16][40];
  __shared__ __align__(16) unsigned int   KtTP[32][26];
  __shared__ __align__(16) float SLf[16][20];
  __shared__ __align__(16) float CSf[16][40];
  __shared__ __align__(16) float Bm[32][12];
  __shared__ __align__(16) float muf[32], mupf[32], rvf[16], yvf[16], uvf[8];

  const size_t bt0 = (size_t)b * TT;

  {
    const float* ap = Ag + bt0*1024 + rA*32 + cA;
    split16(*(const float4*)(ap+0), *(const float4*)(ap+4),
            *(const float4*)(ap+8), *(const float4*)(ap+12),
            &Ahi[rA][cA], &Alo[rA][cA]);
    const float* sp0 = Sig0g + rA*32 + cA;
    split16(*(const float4*)(sp0+0), *(const float4*)(sp0+4),
            *(const float4*)(sp0+8), *(const float4*)(sp0+12),
            &Ghi[rA][cA], &Glo[rA][cA]);
    const float* cp = Cg + bt0*512 + rC*32 + cC;
    split8(*(const float4*)(cp+0), *(const float4*)(cp+4),
           &Chi[rC][cC], &Clo[rC][cC]);
    *(float4*)&Bm[l>>1][(l&1)*4] = *(const float4*)(Bg + bt0*256 + (l>>1)*8 + (l&1)*4);
    if (l < 32) muf[l] = mu0g[l];
    if (l < 16) yvf[l] = Yg[bt0*16 + l];
    if (l < 8)  uvf[l] = Ug[bt0*8 + l];
  }

  for (int t = 0; t < TT; ++t) {
    const size_t bt = bt0 + t;

    // ---- P1: T1 = A * Sigma (split chains) ----
    U8 a_h0, a_h1, a_l0, a_l1, s_h0, s_h1, s_l0, s_l1;
    a_h0.u = *(const uint4v*)&Ahi[c32][0  + kofA];
    a_h1.u = *(const uint4v*)&Ahi[c32][16 + kofA];
    a_l0.u = *(const uint4v*)&Alo[c32][0  + kofA];
    a_l1.u = *(const uint4v*)&Alo[c32][16 + kofA];
    s_h0.u = *(const uint4v*)&Ghi[c32][0  + kofA];
    s_h1.u = *(const uint4v*)&Ghi[c32][16 + kofA];
    s_l0.u = *(const uint4v*)&Glo[c32][0  + kofA];
    s_l1.u = *(const uint4v*)&Glo[c32][16 + kofA];
    f32x16 t1a, t1b;
    #pragma unroll
    for (int r=0;r<16;++r){ t1a[r] = 0.f; t1b[r] = 0.f; }
    t1a = mfma32(a_h0.b, s_h0.b, t1a);
    t1a = mfma32(a_h0.b, s_l0.b, t1a);
    t1a = mfma32(a_l0.b, s_h0.b, t1a);
    t1b = mfma32(a_h1.b, s_h1.b, t1b);
    t1b = mfma32(a_h1.b, s_l1.b, t1b);
    t1b = mfma32(a_l1.b, s_h1.b, t1b);
    #pragma unroll
    for (int r=0;r<16;++r){
      int rr = (r&3) + 8*(r>>2) + 4*h;
      T1P[rr][c32] = packhl(t1a[r] + t1b[r]);
    }
    // mu_p = A*mu + B*u
    float part = 0.f;
    {
      float4 m0 = *(const float4*)&muf[kofA];
      float4 m1 = *(const float4*)&muf[kofA+4];
      float4 m2 = *(const float4*)&muf[16+kofA];
      float4 m3 = *(const float4*)&muf[16+kofA+4];
      part = fmaf(blof(a_h0.u.x,a_l0.u.x), m0.x, part);
      part = fmaf(bhif(a_h0.u.x,a_l0.u.x), m0.y, part);
      part = fmaf(blof(a_h0.u.y,a_l0.u.y), m0.z, part);
      part = fmaf(bhif(a_h0.u.y,a_l0.u.y), m0.w, part);
      part = fmaf(blof(a_h0.u.z,a_l0.u.z), m1.x, part);
      part = fmaf(bhif(a_h0.u.z,a_l0.u.z), m1.y, part);
      part = fmaf(blof(a_h0.u.w,a_l0.u.w), m1.z, part);
      part = fmaf(bhif(a_h0.u.w,a_l0.u.w), m1.w, part);
      part = fmaf(blof(a_h1.u.x,a_l1.u.x), m2.x, part);
      part = fmaf(bhif(a_h1.u.x,a_l1.u.x), m2.y, part);
      part = fmaf(blof(a_h1.u.y,a_l1.u.y), m2.z, part);
      part = fmaf(bhif(a_h1.u.y,a_l1.u.y), m2.w, part);
      part = fmaf(blof(a_h1.u.z,a_l1.u.z), m3.x, part);
      part = fmaf(bhif(a_h1.u.z,a_l1.u.z), m3.y, part);
      part = fmaf(blof(a_h1.u.w,a_l1.u.w), m3.z, part);
      part = fmaf(bhif(a_h1.u.w,a_l1.u.w), m3.w, part);
    }
    part += __shfl_xor(part, 32);
    {
      float4 b0 = *(const float4*)&Bm[c32][0];
      float4 b1 = *(const float4*)&Bm[c32][4];
      float4 u0 = *(const float4*)&uvf[0];
      float4 u1 = *(const float4*)&uvf[4];
      part = fmaf(b0.x,u0.x, fmaf(b0.y,u0.y, fmaf(b0.z,u0.z, fmaf(b0.w,u0.w, part))));
      part = fmaf(b1.x,u1.x, fmaf(b1.y,u1.y, fmaf(b1.z,u1.z, fmaf(b1.w,u1.w, part))));
    }
    if (l < 32){ mupf[c32] = part; wsMu[bt*32 + c32] = part; }

    // ---- P2: Sigma_p = A * T1^T + Q (split chains) ----
    U8 b_h0, b_h1, b_l0, b_l1;
    {
      uint4v p0  = *(const uint4v*)&T1P[c32][0  + kofA];
      uint4v p0b = *(const uint4v*)&T1P[c32][4  + kofA];
      uint4v p1  = *(const uint4v*)&T1P[c32][16 + kofA];
      uint4v p1b = *(const uint4v*)&T1P[c32][20 + kofA];
      b_h0.u = frag_hi(p0, p0b); b_l0.u = frag_lo(p0, p0b);
      b_h1.u = frag_hi(p1, p1b); b_l1.u = frag_lo(p1, p1b);
    }
    f32x16 spa, spb;
    #pragma unroll
    for (int r=0;r<16;++r){ spa[r] = 0.f; spb[r] = 0.f; }
    spa = mfma32(a_h0.b, b_h0.b, spa);
    spa = mfma32(a_h0.b, b_l0.b, spa);
    spa = mfma32(a_l0.b, b_h0.b, spa);
    spb = mfma32(a_h1.b, b_h1.b, spb);
    spb = mfma32(a_h1.b, b_l1.b, spb);
    spb = mfma32(a_l1.b, b_h1.b, spb);
    f32x16 sp;
    #pragma unroll
    for (int r=0;r<16;++r){
      int rr = (r&3) + 8*(r>>2) + 4*h;
      sp[r] = spa[r] + spb[r] + ((rr == c32) ? 0.01f : 0.f);
    }
    {
      float* wp = wsSig + (bt*32 + c32)*32;
      *(float4*)(wp + 0  + 4*h) = make_float4(sp[0], sp[1], sp[2], sp[3]);
      *(float4*)(wp + 8  + 4*h) = make_float4(sp[4], sp[5], sp[6], sp[7]);
      *(float4*)(wp + 16 + 4*h) = make_float4(sp[8], sp[9], sp[10],sp[11]);
      *(float4*)(wp + 24 + 4*h) = make_float4(sp[12],sp[13],sp[14],sp[15]);
      #pragma unroll
      for (int gq=0; gq<4; ++gq){
        uint2v hw, lw;
        hw.x = hipack(sp[4*gq+0], sp[4*gq+1]); hw.y = hipack(sp[4*gq+2], sp[4*gq+3]);
        lw.x = lopack(sp[4*gq+0], sp[4*gq+1]); lw.y = lopack(sp[4*gq+2], sp[4*gq+3]);
        *(uint2v*)&Phi[c32][8*gq + 4*h] = hw;
        *(uint2v*)&Plo[c32][8*gq + 4*h] = lw;
      }
    }

    // ---- P3: CS = C * Sigma_p ----
    U8 c_h, c_l, p_h0, p_l0, p_h1, p_l1;
    c_h.u  = *(const uint4v*)&Chi[c16][kofC];
    c_l.u  = *(const uint4v*)&Clo[c16][kofC];
    p_h0.u = *(const uint4v*)&Phi[c16][kofC];
    p_l0.u = *(const uint4v*)&Plo[c16][kofC];
    p_h1.u = *(const uint4v*)&Phi[16+c16][kofC];
    p_l1.u = *(const uint4v*)&Plo[16+c16][kofC];
    f32x4 cs0, cs1;
    #pragma unroll
    for (int r=0;r<4;++r){ cs0[r]=0.f; cs1[r]=0.f; }
    cs0 = mfma16(c_h.b, p_h0.b, cs0);
    cs0 = mfma16(c_h.b, p_l0.b, cs0);
    cs0 = mfma16(c_l.b, p_h0.b, cs0);
    cs1 = mfma16(c_h.b, p_h1.b, cs1);
    cs1 = mfma16(c_h.b, p_l1.b, cs1);
    cs1 = mfma16(c_l.b, p_h1.b, cs1);
    #pragma unroll
    for (int r=0;r<4;++r){
      int rr = q4*4 + r;
      ZP[rr][c16]     = packhl(cs0[r]);
      ZP[rr][16+c16]  = packhl(cs1[r]);
      CSf[rr][c16]    = cs0[r];
      CSf[rr][16+c16] = cs1[r];
    }
    {
      uint2v hw0, lw0, hw1, lw1;
      hw0.x = hipack(cs0[0],cs0[1]); hw0.y = hipack(cs0[2],cs0[3]);
      lw0.x = lopack(cs0[0],cs0[1]); lw0.y = lopack(cs0[2],cs0[3]);
      hw1.x = hipack(cs1[0],cs1[1]); hw1.y = hipack(cs1[2],cs1[3]);
      lw1.x = lopack(cs1[0],cs1[1]); lw1.y = lopack(cs1[2],cs1[3]);
      *(uint2v*)&Yhi[c16][q4*4]    = hw0; *(uint2v*)&Ylo[c16][q4*4]    = lw0;
      *(uint2v*)&Yhi[16+c16][q4*4] = hw1; *(uint2v*)&Ylo[16+c16][q4*4] = lw1;
    }
    // r = y - C*mu_p
    {
      float prr = 0.f;
      float4 m0 = *(const float4*)&mupf[kofC];
      float4 m1 = *(const float4*)&mupf[kofC+4];
      prr = fmaf(blof(c_h.u.x,c_l.u.x), m0.x, prr);
      prr = fmaf(bhif(c_h.u.x,c_l.u.x), m0.y, prr);
      prr = fmaf(blof(c_h.u.y,c_l.u.y), m0.z, prr);
      prr = fmaf(bhif(c_h.u.y,c_l.u.y), m0.w, prr);
      prr = fmaf(blof(c_h.u.z,c_l.u.z), m1.x, prr);
      prr = fmaf(bhif(c_h.u.z,c_l.u.z), m1.y, prr);
      prr = fmaf(blof(c_h.u.w,c_l.u.w), m1.z, prr);
      prr = fmaf(bhif(c_h.u.w,c_l.u.w), m1.w, prr);
      prr += __shfl_xor(prr, 16);
      prr += __shfl_xor(prr, 32);
      if (l < 16) rvf[l] = yvf[l] - prr;
    }

    // ---- P4: S = CS * C^T + R ----
    {
      U8 z_h, z_l;
      uint4v pz0 = *(const uint4v*)&ZP[c16][kofC];
      uint4v pz1 = *(const uint4v*)&ZP[c16][kofC+4];
      z_h.u = frag_hi(pz0, pz1); z_l.u = frag_lo(pz0, pz1);
      f32x4 ss;
      #pragma unroll
      for (int r=0;r<4;++r) ss[r] = 0.f;
      ss = mfma16(z_h.b, c_h.b, ss);
      ss = mfma16(z_h.b, c_l.b, ss);
      ss = mfma16(z_l.b, c_h.b, ss);
      #pragma unroll
      for (int r=0;r<4;++r){
        int rr = q4*4 + r;
        SLf[rr][c16] = ss[r] + ((rr == c16) ? 0.01f : 0.f);
      }
    }

    // ---- prefetch next-step inputs ----
    float4 pa0, pa1, pa2, pa3, pc0, pc1, pbv;
    float py = 0.f, pu = 0.f;
    pa0=pa1=pa2=pa3=make_float4(0.f,0.f,0.f,0.f);
    pc0=pc1=pbv=make_float4(0.f,0.f,0.f,0.f);
    if (t + 1 < TT){
      const float* ap = Ag + (bt+1)*1024 + rA*32 + cA;
      pa0 = *(const float4*)(ap+0);  pa1 = *(const float4*)(ap+4);
      pa2 = *(const float4*)(ap+8);  pa3 = *(const float4*)(ap+12);
      const float* cp = Cg + (bt+1)*512 + rC*32 + cC;
      pc0 = *(const float4*)(cp+0);  pc1 = *(const float4*)(cp+4);
      pbv = *(const float4*)(Bg + (bt+1)*256 + (l>>1)*8 + (l&1)*4);
      if (l < 16) py = Yg[(bt+1)*16 + l];
      if (l < 8)  pu = Ug[(bt+1)*8 + l];
    }

    // ---- P5: column-layout Gauss-Jordan via readlane (no shuffles) ----
    {
      float aug[16];
      if (l < 16){
        #pragma unroll
        for (int i=0;i<16;++i) aug[i] = 0.5f*(SLf[i][l] + SLf[l][i]);
      } else if (l < 48){
        #pragma unroll
        for (int i=0;i<16;++i) aug[i] = CSf[i][l-16];
      } else {
        #pragma unroll
        for (int i=0;i<16;++i) aug[i] = 0.f;
      }
      #pragma unroll
      for (int k=0;k<16;++k){
        float piv = rdl(aug[k], k);
        float q = -aug[k] * frcp(piv);
        #pragma unroll
        for (int i=0;i<16;++i){
          if (i == k) continue;
          float s = rdl(aug[i], k);
          aug[i] = fmaf(q, s, aug[i]);
        }
      }
      if (l >= 16 && l < 48){
        #pragma unroll
        for (int i=0;i<16;++i){
          float d = rdl(aug[i], i);
          KtTP[l-16][i] = packhl(-aug[i] * frcp(d));
        }
      }
    }

    // ---- P6: Sigma_f = Sigma_p - CS^T * Kt ----
    f32x16 sf = sp;
    {
      U8 y_h, y_l, kt_h, kt_l;
      y_h.u = *(const uint4v*)&Yhi[c32][8*h];
      y_l.u = *(const uint4v*)&Ylo[c32][8*h];
      uint4v k0, k1;
      { uint2v a0 = *(const uint2v*)&KtTP[c32][8*h];
        uint2v a1 = *(const uint2v*)&KtTP[c32][8*h+2];
        uint2v a2 = *(const uint2v*)&KtTP[c32][8*h+4];
        uint2v a3 = *(const uint2v*)&KtTP[c32][8*h+6];
        k0.x=a0.x; k0.y=a0.y; k0.z=a1.x; k0.w=a1.y;
        k1.x=a2.x; k1.y=a2.y; k1.z=a3.x; k1.w=a3.y; }
      kt_h.u = frag_hi(k0, k1); kt_l.u = frag_lo(k0, k1);
      sf = mfma32(y_h.b, kt_h.b, sf);
      sf = mfma32(y_h.b, kt_l.b, sf);
      sf = mfma32(y_l.b, kt_h.b, sf);
    }
    #pragma unroll
    for (int gq=0; gq<4; ++gq){
      uint2v hw, lw;
      hw.x = hipack(sf[4*gq+0], sf[4*gq+1]); hw.y = hipack(sf[4*gq+2], sf[4*gq+3]);
      lw.x = lopack(sf[4*gq+0], sf[4*gq+1]); lw.y = lopack(sf[4*gq+2], sf[4*gq+3]);
      *(uint2v*)&Ghi[c32][8*gq + 4*h] = hw;
      *(uint2v*)&Glo[c32][8*gq + 4*h] = lw;
    }
    {
      float* ob = outg + (bt*32)*33;
      #pragma unroll
      for (int r=0;r<16;++r){
        int rr = (r&3) + 8*(r>>2) + 4*h;
        ob[rr*33 + 1 + c32] = sf[r];
      }
      float mf = mupf[c32];
      #pragma unroll
      for (int p=0;p<16;++p){
        unsigned int w = KtTP[c32][p];
        mf = fmaf(-unpk(w), rvf[p], mf);
      }
      if (l < 32){ muf[c32] = mf; ob[c32*33] = mf; }
    }

    // ---- P7: stage next-step inputs ----
    if (t + 1 < TT){
      split16(pa0, pa1, pa2, pa3, &Ahi[rA][cA], &Alo[rA][cA]);
      split8(pc0, pc1, &Chi[rC][cC], &Clo[rC][cC]);
      *(float4*)&Bm[l>>1][(l&1)*4] = pbv;
      if (l < 16) yvf[l] = py;
      if (l < 8)  uvf[l] = pu;
    }
  }
}

// ===== Smoother precompute: 1 WAVE per (b,t), readlane-GJ inversion, MFMA =====
__global__ __launch_bounds__(64) void kf_precomp(
    const float* __restrict__ Ag, float* __restrict__ outg,
    float* __restrict__ wsSig, const float* __restrict__ wsMu)
{
  const int t = blockIdx.x;        // 0..126
  const int b = blockIdx.y;
  const int l = threadIdx.x;
  const int c32 = l & 31;
  const int h = l >> 5;
  const int kofA = h * 8;

  __shared__ __align__(16) float        Sffr[1060];      // raw outg slot (32*33=1056)
  __shared__ __align__(16) unsigned int MmP[32][34];
  __shared__ __align__(16) unsigned int VPT[32][34];
  __shared__ __align__(16) unsigned int JP [32][34];
  __shared__ float mp1f[32];

  const size_t bt = (size_t)b*TT + t;
  float* osl = outg + bt*1056;

  // ---- stage Sf block (coalesced) ----
  {
    const float4* src = (const float4*)osl;
    #pragma unroll
    for (int q=0;q<4;++q) *(float4*)&Sffr[(l + 64*q)*4] = src[l + 64*q];
    if (l < 8) *(float4*)&Sffr[(l + 256)*4] = src[l + 256];
    if (l < 32) mp1f[l] = wsMu[(bt+1)*32 + l];
  }

  // ---- Pm column (= row, symmetric) into aug ; V identity ----
  float aug[32];
  if (l < 32){
    const float* pp = wsSig + (bt+1)*1024 + (size_t)l*32;
    #pragma unroll
    for (int q=0;q<8;++q){
      float4 v = *(const float4*)(pp + 4*q);
      aug[4*q]=v.x; aug[4*q+1]=v.y; aug[4*q+2]=v.z; aug[4*q+3]=v.w;
    }
  } else {
    #pragma unroll
    for (int i=0;i<32;++i) aug[i] = (i == l-32) ? 1.f : 0.f;
  }

  // ---- A row c32 (B-operand for Sf*A^T) direct from global ----
  U8 a_h0, a_l0, a_h1, a_l1;
  {
    const float* ap = Ag + bt*1024 + c32*32;
    float4 v0 = *(const float4*)(ap + kofA);
    float4 v1 = *(const float4*)(ap + kofA + 4);
    float4 v2 = *(const float4*)(ap + 16 + kofA);
    float4 v3 = *(const float4*)(ap + 16 + kofA + 4);
    MK8(v0, v1, a_h0, a_l0);
    MK8(v2, v3, a_h1, a_l1);
  }
  // ---- Sf row c32 fragments (A-operand) from LDS ----
  U8 s_h0, s_l0, s_h1, s_l1;
  {
    const float* rp = &Sffr[c32*33 + 1];
    float4 v0, v1, v2, v3;
    v0.x=rp[kofA+0]; v0.y=rp[kofA+1]; v0.z=rp[kofA+2]; v0.w=rp[kofA+3];
    v1.x=rp[kofA+4]; v1.y=rp[kofA+5]; v1.z=rp[kofA+6]; v1.w=rp[kofA+7];
    v2.x=rp[16+kofA+0]; v2.y=rp[16+kofA+1]; v2.z=rp[16+kofA+2]; v2.w=rp[16+kofA+3];
    v3.x=rp[16+kofA+4]; v3.y=rp[16+kofA+5]; v3.z=rp[16+kofA+6]; v3.w=rp[16+kofA+7];
    MK8(v0, v1, s_h0, s_l0);
    MK8(v2, v3, s_h1, s_l1);
  }

  // ---- Mm = Sf * A^T (split chains) ----
  f32x16 ma, mb;
  #pragma unroll
  for (int r=0;r<16;++r){ ma[r]=0.f; mb[r]=0.f; }
  ma = mfma32(s_h0.b, a_h0.b, ma);
  ma = mfma32(s_h0.b, a_l0.b, ma);
  ma = mfma32(s_l0.b, a_h0.b, ma);
  mb = mfma32(s_h1.b, a_h1.b, mb);
  mb = mfma32(s_h1.b, a_l1.b, mb);
  mb = mfma32(s_l1.b, a_h1.b, mb);
  #pragma unroll
  for (int r=0;r<16;++r){
    int rr = (r&3) + 8*(r>>2) + 4*h;
    MmP[rr][c32] = packhl(ma[r] + mb[r]);
  }

  // ---- Gauss-Jordan inversion of Pm via readlane (columns in lanes) ----
  #pragma unroll
  for (int k=0;k<32;++k){
    float piv = rdl(aug[k], k);
    float q = -aug[k] * frcp(piv);
    #pragma unroll
    for (int i=0;i<32;++i){
      if (i == k) continue;
      float s = rdl(aug[i], k);
      aug[i] = fmaf(q, s, aug[i]);
    }
  }
  // V columns -> VPT rows (scaled by 1/d_i)
  if (l >= 32){
    #pragma unroll
    for (int i=0;i<32;++i){
      float d = rdl(aug[i], i);
      VPT[l-32][i] = packhl(aug[i] * frcp(d));
    }
  }

  // ---- J = Mm * V ----
  U8 m_h0, m_l0, m_h1, m_l1;
  {
    uint4v ua, ub, uc, ud;
    ua.x=MmP[c32][kofA+0]; ua.y=MmP[c32][kofA+1]; ua.z=MmP[c32][kofA+2]; ua.w=MmP[c32][kofA+3];
    ub.x=MmP[c32][kofA+4]; ub.y=MmP[c32][kofA+5]; ub.z=MmP[c32][kofA+6]; ub.w=MmP[c32][kofA+7];
    uc.x=MmP[c32][16+kofA+0]; uc.y=MmP[c32][16+kofA+1]; uc.z=MmP[c32][16+kofA+2]; uc.w=MmP[c32][16+kofA+3];
    ud.x=MmP[c32][16+kofA+4]; ud.y=MmP[c32][16+kofA+5]; ud.z=MmP[c32][16+kofA+6]; ud.w=MmP[c32][16+kofA+7];
    m_h0.u = frag_hi(ua, ub); m_l0.u = frag_lo(ua, ub);
    m_h1.u = frag_hi(uc, ud); m_l1.u = frag_lo(uc, ud);
  }
  U8 v_h0, v_l0, v_h1, v_l1;
  {
    uint4v ua, ub, uc, ud;
    ua.x=VPT[c32][kofA+0]; ua.y=VPT[c32][kofA+1]; ua.z=VPT[c32][kofA+2]; ua.w=VPT[c32][kofA+3];
    ub.x=VPT[c32][kofA+4]; ub.y=VPT[c32][kofA+5]; ub.z=VPT[c32][kofA+6]; ub.w=VPT[c32][kofA+7];
    uc.x=VPT[c32][16+kofA+0]; uc.y=VPT[c32][16+kofA+1]; uc.z=VPT[c32][16+kofA+2]; uc.w=VPT[c32][16+kofA+3];
    ud.x=VPT[c32][16+kofA+4]; ud.y=VPT[c32][16+kofA+5]; ud.z=VPT[c32][16+kofA+6]; ud.w=VPT[c32][16+kofA+7];
    v_h0.u = frag_hi(ua, ub); v_l0.u = frag_lo(ua, ub);
    v_h1.u = frag_hi(uc, ud); v_l1.u = frag_lo(uc, ud);
  }
  f32x16 ja, jb;
  #pragma unroll
  for (int r=0;r<16;++r){ ja[r]=0.f; jb[r]=0.f; }
  ja = mfma32(m_h0.b, v_h0.b, ja);
  ja = mfma32(m_h0.b, v_l0.b, ja);
  ja = mfma32(m_l0.b, v_h0.b, ja);
  jb = mfma32(m_h1.b, v_h1.b, jb);
  jb = mfma32(m_h1.b, v_l1.b, jb);
  jb = mfma32(m_l1.b, v_h1.b, jb);
  {
    float* jws = wsSig + (bt+1)*1024;
    #pragma unroll
    for (int r=0;r<16;++r){
      int rr = (r&3) + 8*(r>>2) + 4*h;
      float jv = ja[r] + jb[r];
      jws[rr*32 + c32] = jv;
      JP[rr][c32] = packhl(-jv);
    }
  }

  // ---- E = Sf - Mm*J^T  (B-op = -J^T via JP) ----
  U8 nj_h0, nj_l0, nj_h1, nj_l1;
  {
    uint4v ua, ub, uc, ud;
    ua.x=JP[c32][kofA+0]; ua.y=JP[c32][kofA+1]; ua.z=JP[c32][kofA+2]; ua.w=JP[c32][kofA+3];
    ub.x=JP[c32][kofA+4]; ub.y=JP[c32][kofA+5]; ub.z=JP[c32][kofA+6]; ub.w=JP[c32][kofA+7];
    uc.x=JP[c32][16+kofA+0]; uc.y=JP[c32][16+kofA+1]; uc.z=JP[c32][16+kofA+2]; uc.w=JP[c32][16+kofA+3];
    ud.x=JP[c32][16+kofA+4]; ud.y=JP[c32][16+kofA+5]; ud.z=JP[c32][16+kofA+6]; ud.w=JP[c32][16+kofA+7];
    nj_h0.u = frag_hi(ua, ub); nj_l0.u = frag_lo(ua, ub);
    nj_h1.u = frag_hi(uc, ud); nj_l1.u = frag_lo(uc, ud);
  }
  f32x16 ea, eb;
  #pragma unroll
  for (int r=0;r<16;++r){
    int rr = (r&3) + 8*(r>>2) + 4*h;
    ea[r] = Sffr[rr*33 + 1 + c32];
    eb[r] = 0.f;
  }
  ea = mfma32(m_h0.b, nj_h0.b, ea);
  ea = mfma32(m_h0.b, nj_l0.b, ea);
  ea = mfma32(m_l0.b, nj_h0.b, ea);
  eb = mfma32(m_h1.b, nj_h1.b, eb);
  eb = mfma32(m_h1.b, nj_l1.b, eb);
  eb = mfma32(m_l1.b, nj_h1.b, eb);
  #pragma unroll
  for (int r=0;r<16;++r){
    int rr = (r&3) + 8*(r>>2) + 4*h;
    osl[rr*33 + 1 + c32] = ea[r] + eb[r];
  }

  // ---- e = mf - J*mp1 ----
  {
    float e2 = Sffr[c32*33];
    #pragma unroll
    for (int k=0;k<32;++k)
      e2 = fmaf(unpk(JP[c32][k]), mp1f[k], e2);   // JP holds -J
    if (l < 32) osl[c32*33] = e2;
  }
}

// ===== Backward smoother: 1 WAVE per batch, MFMA bf16-split, no barriers =====
__global__ __launch_bounds__(64) void kf_backward(
    float* __restrict__ outg, const float* __restrict__ wsSig)
{
  const int l   = threadIdx.x;
  const int b   = blockIdx.x;
  const int c32 = l & 31;
  const int h   = l >> 5;
  const int kofA = h * 8;
  const int rA = l >> 1, cA = (l & 1) << 4;

  __shared__ __align__(16) unsigned short Jhi[32][40], Jlo[32][40];
  __shared__ __align__(16) unsigned int   SP[32][36];
  __shared__ __align__(16) unsigned int   WP[32][36];
  __shared__ float muv[32];

  const size_t base = (size_t)b * TT;

  float er[16]; float ev;
  {
    const float* os = outg + (base + TT - 1)*32*33;
    const float* rp = os + rA*33 + 1 + cA;
    float4 v0 = *(const float4*)(rp+0), v1 = *(const float4*)(rp+4),
           v2 = *(const float4*)(rp+8), v3 = *(const float4*)(rp+12);
    uint4v u0, u1;
    u0.x = packhl(v0.x); u0.y = packhl(v0.y); u0.z = packhl(v0.z); u0.w = packhl(v0.w);
    u1.x = packhl(v1.x); u1.y = packhl(v1.y); u1.z = packhl(v1.z); u1.w = packhl(v1.w);
    *(uint4v*)&SP[rA][cA+0] = u0; *(uint4v*)&SP[rA][cA+4] = u1;
    u0.x = packhl(v2.x); u0.y = packhl(v2.y); u0.z = packhl(v2.z); u0.w = packhl(v2.w);
    u1.x = packhl(v3.x); u1.y = packhl(v3.y); u1.z = packhl(v3.z); u1.w = packhl(v3.w);
    *(uint4v*)&SP[rA][cA+8] = u0; *(uint4v*)&SP[rA][cA+12] = u1;
    if (l < 32) muv[l] = os[l*33];
    const float* jp = wsSig + ((base + TT - 1)*32 + rA)*32 + cA;
    split16(*(const float4*)(jp+0), *(const float4*)(jp+4),
            *(const float4*)(jp+8), *(const float4*)(jp+12),
            &Jhi[rA][cA], &Jlo[rA][cA]);
    const float* oe = outg + (base + TT - 2)*32*33;
    #pragma unroll
    for (int r=0;r<16;++r){
      int rr = (r&3) + 8*(r>>2) + 4*h;
      er[r] = oe[rr*33 + 1 + c32];
    }
    ev = (l < 32) ? oe[l*33] : 0.f;
  }

  for (int t = TT - 2; t >= 0; --t) {
    float4 pj0, pj1, pj2, pj3; float ner[16]; float nev = 0.f;
    if (t > 0) {
      const float* jp = wsSig + ((base + t)*32 + rA)*32 + cA;
      pj0 = *(const float4*)(jp+0);  pj1 = *(const float4*)(jp+4);
      pj2 = *(const float4*)(jp+8);  pj3 = *(const float4*)(jp+12);
      const float* oe = outg + (base + t - 1)*32*33;
      #pragma unroll
      for (int r=0;r<16;++r){
        int rr = (r&3) + 8*(r>>2) + 4*h;
        ner[r] = oe[rr*33 + 1 + c32];
      }
      if (l < 32) nev = oe[l*33];
    } else {
      pj0=pj1=pj2=pj3=make_float4(0.f,0.f,0.f,0.f);
      #pragma unroll
      for (int r=0;r<16;++r) ner[r] = 0.f;
    }

    U8 a_h0, a_h1, a_l0, a_l1;
    a_h0.u = *(const uint4v*)&Jhi[c32][0  + kofA];
    a_h1.u = *(const uint4v*)&Jhi[c32][16 + kofA];
    a_l0.u = *(const uint4v*)&Jlo[c32][0  + kofA];
    a_l1.u = *(const uint4v*)&Jlo[c32][16 + kofA];
    U8 s_h0, s_l0, s_h1, s_l1;
    {
      uint4v ua = *(const uint4v*)&SP[c32][0  + kofA];
      uint4v ub = *(const uint4v*)&SP[c32][4  + kofA];
      uint4v uc = *(const uint4v*)&SP[c32][16 + kofA];
      uint4v ud = *(const uint4v*)&SP[c32][20 + kofA];
      s_h0.u = frag_hi(ua, ub); s_l0.u = frag_lo(ua, ub);
      s_h1.u = frag_hi(uc, ud); s_l1.u = frag_lo(uc, ud);
    }
    // W = J * Sigma_s (split chains)
    f32x16 wa, wb;
    #pragma unroll
    for (int r=0;r<16;++r){ wa[r]=0.f; wb[r]=0.f; }
    wa = mfma32(a_h0.b, s_h0.b, wa);
    wa = mfma32(a_h0.b, s_l0.b, wa);
    wa = mfma32(a_l0.b, s_h0.b, wa);
    wb = mfma32(a_h1.b, s_h1.b, wb);
    wb = mfma32(a_h1.b, s_l1.b, wb);
    wb = mfma32(a_l1.b, s_h1.b, wb);
    #pragma unroll
    for (int r=0;r<16;++r){
      int rr = (r&3) + 8*(r>>2) + 4*h;
      WP[rr][c32] = packhl(wa[r] + wb[r]);
    }
    // G = E + W * J^T (split chains)
    U8 w_h0, w_l0, w_h1, w_l1;
    {
      uint4v ua = *(const uint4v*)&WP[c32][0  + kofA];
      uint4v ub = *(const uint4v*)&WP[c32][4  + kofA];
      uint4v uc = *(const uint4v*)&WP[c32][16 + kofA];
      uint4v ud = *(const uint4v*)&WP[c32][20 + kofA];
      w_h0.u = frag_hi(ua, ub); w_l0.u = frag_lo(ua, ub);
      w_h1.u = frag_hi(uc, ud); w_l1.u = frag_lo(uc, ud);
    }
    f32x16 ga, gb;
    #pragma unroll
    for (int r=0;r<16;++r){ ga[r] = er[r]; gb[r] = 0.f; }
    ga = mfma32(w_h0.b, a_h0.b, ga);
    ga = mfma32(w_h0.b, a_l0.b, ga);
    ga = mfma32(w_l0.b, a_h0.b, ga);
    gb = mfma32(w_h1.b, a_h1.b, gb);
    gb = mfma32(w_h1.b, a_l1.b, gb);
    gb = mfma32(w_l1.b, a_h1.b, gb);

    // mu_s = e + J * mu_s
    float part = 0.f;
    {
      float4 m0 = *(const float4*)&muv[kofA];
      float4 m1 = *(const float4*)&muv[kofA+4];
      float4 m2 = *(const float4*)&muv[16+kofA];
      float4 m3 = *(const float4*)&muv[16+kofA+4];
      part = fmaf(blof(a_h0.u.x,a_l0.u.x), m0.x, part);
      part = fmaf(bhif(a_h0.u.x,a_l0.u.x), m0.y, part);
      part = fmaf(blof(a_h0.u.y,a_l0.u.y), m0.z, part);
      part = fmaf(bhif(a_h0.u.y,a_l0.u.y), m0.w, part);
      part = fmaf(blof(a_h0.u.z,a_l0.u.z), m1.x, part);
      part = fmaf(bhif(a_h0.u.z,a_l0.u.z), m1.y, part);
      part = fmaf(blof(a_h0.u.w,a_l0.u.w), m1.z, part);
      part = fmaf(bhif(a_h0.u.w,a_l0.u.w), m1.w, part);
      part = fmaf(blof(a_h1.u.x,a_l1.u.x), m2.x, part);
      part = fmaf(bhif(a_h1.u.x,a_l1.u.x), m2.y, part);
      part = fmaf(blof(a_h1.u.y,a_l1.u.y), m2.z, part);
      part = fmaf(bhif(a_h1.u.y,a_l1.u.y), m2.w, part);
      part = fmaf(blof(a_h1.u.z,a_l1.u.z), m3.x, part);
      part = fmaf(bhif(a_h1.u.z,a_l1.u.z), m3.y, part);
      part = fmaf(blof(a_h1.u.w,a_l1.u.w), m3.z, part);
      part = fmaf(bhif(a_h1.u.w,a_l1.u.w), m3.w, part);
    }
    part += __shfl_xor(part, 32);
    float mn = ev + part;

    {
      float* ob = outg + ((base + t)*32)*33;
      #pragma unroll
      for (int r=0;r<16;++r){
        int rr = (r&3) + 8*(r>>2) + 4*h;
        float gv = ga[r] + gb[r];
        ob[rr*33 + 1 + c32] = gv;
        (void)rr;
      }
      #pragma unroll
      for (int gq=0; gq<4; ++gq){
        uint4v uw;
        uw.x = packhl(ga[4*gq+0]+gb[4*gq+0]); uw.y = packhl(ga[4*gq+1]+gb[4*gq+1]);
        uw.z = packhl(ga[4*gq+2]+gb[4*gq+2]); uw.w = packhl(ga[4*gq+3]+gb[4*gq+3]);
        *(uint4v*)&SP[c32][8*gq + 4*h] = uw;
      }
      if (l < 32){ muv[l] = mn; ob[l*33] = mn; }
    }

    if (t > 0){
      split16(pj0, pj1, pj2, pj3, &Jhi[rA][cA], &Jlo[rA][cA]);
      #pragma unroll
      for (int r=0;r<16;++r) er[r] = ner[r];
      ev = nev;
    }
  }
}

extern "C" void kernel_launch(void* const* d_in, const int* in_sizes, int n_in,
                              void* d_out, int out_size, void* d_ws, size_t ws_size,
                              hipStream_t stream) {
  (void)in_sizes; (void)n_in; (void)out_size; (void)ws_size;
  const float* Yg   = (const float*)d_in[0];
  const float* Ug   = (const float*)d_in[1];
  const float* Ag   = (const float*)d_in[2];
  const float* Bg   = (const float*)d_in[3];
  const float* Cg   = (const float*)d_in[4];
  const float* mu0g = (const float*)d_in[5];
  const float* S0g  = (const float*)d_in[6];
  float* outg = (float*)d_out;
  float* wsSig = (float*)d_ws;
  float* wsMu  = wsSig + (size_t)NB*TT*NSZ*NSZ;

  hipLaunchKernelGGL(kf_forward, dim3(NB), dim3(64), 0, stream,
                     Yg, Ug, Ag, Bg, Cg, mu0g, S0g, outg, wsSig, wsMu);
  hipLaunchKernelGGL(kf_precomp, dim3(TT-1, NB), dim3(64), 0, stream,
                     Ag, outg, wsSig, wsMu);
  hipLaunchKernelGGL(kf_backward, dim3(NB), dim3(64), 0, stream,
                     outg, wsSig);
}

// Round 8
// 703.954 us; speedup vs baseline: 4.1245x; 1.0338x over previous
//
#include <hip/hip_runtime.h>

#define TT 128
#define NB 64
#define NSZ 32
#define MSZ 8
#define PSZ 16

typedef __attribute__((ext_vector_type(8)))  short bf16x8;
typedef __attribute__((ext_vector_type(16))) float f32x16;
typedef __attribute__((ext_vector_type(4)))  float f32x4;
typedef __attribute__((ext_vector_type(4)))  unsigned int uint4v;
typedef __attribute__((ext_vector_type(2)))  unsigned int uint2v;

union U8 { uint4v u; bf16x8 b; };

__device__ __forceinline__ float frcp(float x){ return __builtin_amdgcn_rcpf(x); }
__device__ __forceinline__ float rdl(float x, int lane){
  return __int_as_float(__builtin_amdgcn_readlane(__float_as_int(x), lane));
}

// bf16 split helpers: hi = truncated top-16 of f32; lo = bf16(x - f32(hi)).
__device__ __forceinline__ unsigned int hipack(float x0, float x1){
  return __builtin_amdgcn_perm(__float_as_uint(x1), __float_as_uint(x0), 0x07060302u);
}
__device__ __forceinline__ unsigned int lopack(float x0, float x1){
  float l0 = x0 - __uint_as_float(__float_as_uint(x0) & 0xFFFF0000u);
  float l1 = x1 - __uint_as_float(__float_as_uint(x1) & 0xFFFF0000u);
  return __builtin_amdgcn_perm(__float_as_uint(l1), __float_as_uint(l0), 0x07060302u);
}
__device__ __forceinline__ unsigned int packhl(float x){
  unsigned int u = __float_as_uint(x);
  unsigned int h = u & 0xFFFF0000u;
  float xl = x - __uint_as_float(h);
  return h | (__float_as_uint(xl) >> 16);
}
__device__ __forceinline__ float unpk(unsigned int u){
  return __uint_as_float(u & 0xFFFF0000u) + __uint_as_float(u << 16);
}
__device__ __forceinline__ uint4v frag_hi(uint4v a, uint4v b){
  uint4v r;
  r.x = __builtin_amdgcn_perm(a.y, a.x, 0x07060302u);
  r.y = __builtin_amdgcn_perm(a.w, a.z, 0x07060302u);
  r.z = __builtin_amdgcn_perm(b.y, b.x, 0x07060302u);
  r.w = __builtin_amdgcn_perm(b.w, b.z, 0x07060302u);
  return r;
}
__device__ __forceinline__ uint4v frag_lo(uint4v a, uint4v b){
  uint4v r;
  r.x = __builtin_amdgcn_perm(a.y, a.x, 0x05040100u);
  r.y = __builtin_amdgcn_perm(a.w, a.z, 0x05040100u);
  r.z = __builtin_amdgcn_perm(b.y, b.x, 0x05040100u);
  r.w = __builtin_amdgcn_perm(b.w, b.z, 0x05040100u);
  return r;
}
__device__ __forceinline__ float blof(unsigned int h, unsigned int l){
  return __uint_as_float(h << 16) + __uint_as_float(l << 16);
}
__device__ __forceinline__ float bhif(unsigned int h, unsigned int l){
  return __uint_as_float(h & 0xFFFF0000u) + __uint_as_float(l & 0xFFFF0000u);
}
__device__ __forceinline__ f32x16 mfma32(bf16x8 a, bf16x8 b, f32x16 c){
  return __builtin_amdgcn_mfma_f32_32x32x16_bf16(a, b, c, 0, 0, 0);
}
__device__ __forceinline__ f32x4 mfma16(bf16x8 a, bf16x8 b, f32x4 c){
  return __builtin_amdgcn_mfma_f32_16x16x32_bf16(a, b, c, 0, 0, 0);
}
__device__ __forceinline__ void split16(float4 v0, float4 v1, float4 v2, float4 v3,
                                        unsigned short* hi, unsigned short* lo){
  uint4v hw0, hw1, lw0, lw1;
  hw0.x=hipack(v0.x,v0.y); hw0.y=hipack(v0.z,v0.w); hw0.z=hipack(v1.x,v1.y); hw0.w=hipack(v1.z,v1.w);
  hw1.x=hipack(v2.x,v2.y); hw1.y=hipack(v2.z,v2.w); hw1.z=hipack(v3.x,v3.y); hw1.w=hipack(v3.z,v3.w);
  lw0.x=lopack(v0.x,v0.y); lw0.y=lopack(v0.z,v0.w); lw0.z=lopack(v1.x,v1.y); lw0.w=lopack(v1.z,v1.w);
  lw1.x=lopack(v2.x,v2.y); lw1.y=lopack(v2.z,v2.w); lw1.z=lopack(v3.x,v3.y); lw1.w=lopack(v3.z,v3.w);
  *(uint4v*)hi = hw0; *(uint4v*)(hi+8) = hw1;
  *(uint4v*)lo = lw0; *(uint4v*)(lo+8) = lw1;
}
__device__ __forceinline__ void split8(float4 v0, float4 v1,
                                       unsigned short* hi, unsigned short* lo){
  uint4v hw, lw;
  hw.x=hipack(v0.x,v0.y); hw.y=hipack(v0.z,v0.w); hw.z=hipack(v1.x,v1.y); hw.w=hipack(v1.z,v1.w);
  lw.x=lopack(v0.x,v0.y); lw.y=lopack(v0.z,v0.w); lw.z=lopack(v1.x,v1.y); lw.w=lopack(v1.z,v1.w);
  *(uint4v*)hi = hw; *(uint4v*)lo = lw;
}
// pack 8 f32 (from float4 pair) into hi/lo bf16x8 fragments
#define MK8(v0, v1, HI, LO) do { \
  (HI).u.x = hipack((v0).x,(v0).y); (HI).u.y = hipack((v0).z,(v0).w); \
  (HI).u.z = hipack((v1).x,(v1).y); (HI).u.w = hipack((v1).z,(v1).w); \
  (LO).u.x = lopack((v0).x,(v0).y); (LO).u.y = lopack((v0).z,(v0).w); \
  (LO).u.z = lopack((v1).x,(v1).y); (LO).u.w = lopack((v1).z,(v1).w); \
} while(0)

// Build B-fragments (sets 0 and 1) from a 32x32 D-layout register file `uu`
// using a cross-half shfl: lane (c32,h) reg r holds M[(r&3)+8*(r>>2)+4*h][c32].
// Output: B[k][c32] fragments, set0 k=0..15, set1 k=16..31, split hi/lo.
#define DLAYOUT_TO_BFRAG(uu, h, B_H0, B_L0, B_H1, B_L1) do { \
  float sw_[16]; \
  _Pragma("unroll") \
  for (int r_=0;r_<16;++r_) sw_[r_] = __shfl_xor((uu)[r_], 32); \
  float v0_[8], v1_[8]; \
  v0_[0]=(h)? sw_[4] :(uu)[0];  v0_[1]=(h)? sw_[5] :(uu)[1]; \
  v0_[2]=(h)? sw_[6] :(uu)[2];  v0_[3]=(h)? sw_[7] :(uu)[3]; \
  v0_[4]=(h)? (uu)[4]:sw_[0];   v0_[5]=(h)? (uu)[5]:sw_[1]; \
  v0_[6]=(h)? (uu)[6]:sw_[2];   v0_[7]=(h)? (uu)[7]:sw_[3]; \
  v1_[0]=(h)? sw_[12]:(uu)[8];  v1_[1]=(h)? sw_[13]:(uu)[9]; \
  v1_[2]=(h)? sw_[14]:(uu)[10]; v1_[3]=(h)? sw_[15]:(uu)[11]; \
  v1_[4]=(h)? (uu)[12]:sw_[8];  v1_[5]=(h)? (uu)[13]:sw_[9]; \
  v1_[6]=(h)? (uu)[14]:sw_[10]; v1_[7]=(h)? (uu)[15]:sw_[11]; \
  (B_H0).u.x=hipack(v0_[0],v0_[1]); (B_H0).u.y=hipack(v0_[2],v0_[3]); \
  (B_H0).u.z=hipack(v0_[4],v0_[5]); (B_H0).u.w=hipack(v0_[6],v0_[7]); \
  (B_L0).u.x=lopack(v0_[0],v0_[1]); (B_L0).u.y=lopack(v0_[2],v0_[3]); \
  (B_L0).u.z=lopack(v0_[4],v0_[5]); (B_L0).u.w=lopack(v0_[6],v0_[7]); \
  (B_H1).u.x=hipack(v1_[0],v1_[1]); (B_H1).u.y=hipack(v1_[2],v1_[3]); \
  (B_H1).u.z=hipack(v1_[4],v1_[5]); (B_H1).u.w=hipack(v1_[6],v1_[7]); \
  (B_L1).u.x=lopack(v1_[0],v1_[1]); (B_L1).u.y=lopack(v1_[2],v1_[3]); \
  (B_L1).u.z=lopack(v1_[4],v1_[5]); (B_L1).u.w=lopack(v1_[6],v1_[7]); \
} while(0)

// ===== Forward Kalman filter: 1 wave/batch, MFMA bf16-split matmuls, no barriers =====
__global__ __launch_bounds__(64) void kf_forward(
    const float* __restrict__ Yg, const float* __restrict__ Ug,
    const float* __restrict__ Ag, const float* __restrict__ Bg,
    const float* __restrict__ Cg, const float* __restrict__ mu0g,
    const float* __restrict__ Sig0g,
    float* __restrict__ outg, float* __restrict__ wsSig, float* __restrict__ wsMu)
{
  const int l   = threadIdx.x;
  const int b   = blockIdx.x;
  const int c32 = l & 31;
  const int h   = l >> 5;
  const int c16 = l & 15;
  const int q4  = l >> 4;
  const int kofA = h * 8;
  const int kofC = q4 * 8;
  const int rA = l >> 1, cA = (l & 1) << 4;
  const int rC = l >> 2, cC = (l & 3) << 3;

  __shared__ __align__(16) unsigned short Ahi[32][40], Alo[32][40];
  __shared__ __align__(16) unsigned short Chi[16][40], Clo[16][40];
  __shared__ __align__(16) unsigned short Ghi[32][40], Glo[32][40];
  __shared__ __align__(16) unsigned short Phi[32][40], Plo[32][40];
  __shared__ __align__(16) unsigned short Yhi[32][24], Ylo[32][24];
  __shared__ __align__(16) unsigned int   ZP[16][40];
  __shared__ __align__(16) unsigned int   KtTP[32][26];
  __shared__ __align__(16) float SLf[16][20];
  __shared__ __align__(16) float CSf[16][40];
  __shared__ __align__(16) float Bm[32][12];
  __shared__ __align__(16) float muf[32], mupf[32], rvf[16], yvf[16], uvf[8];

  const size_t bt0 = (size_t)b * TT;

  {
    const float* ap = Ag + bt0*1024 + rA*32 + cA;
    split16(*(const float4*)(ap+0), *(const float4*)(ap+4),
            *(const float4*)(ap+8), *(const float4*)(ap+12),
            &Ahi[rA][cA], &Alo[rA][cA]);
    const float* sp0 = Sig0g + rA*32 + cA;
    split16(*(const float4*)(sp0+0), *(const float4*)(sp0+4),
            *(const float4*)(sp0+8), *(const float4*)(sp0+12),
            &Ghi[rA][cA], &Glo[rA][cA]);
    const float* cp = Cg + bt0*512 + rC*32 + cC;
    split8(*(const float4*)(cp+0), *(const float4*)(cp+4),
           &Chi[rC][cC], &Clo[rC][cC]);
    *(float4*)&Bm[l>>1][(l&1)*4] = *(const float4*)(Bg + bt0*256 + (l>>1)*8 + (l&1)*4);
    if (l < 32) muf[l] = mu0g[l];
    if (l < 16) yvf[l] = Yg[bt0*16 + l];
    if (l < 8)  uvf[l] = Ug[bt0*8 + l];
  }

  for (int t = 0; t < TT; ++t) {
    const size_t bt = bt0 + t;

    // ---- P1': U = Sigma * A^T  (D-layout kept in registers) ----
    U8 a_h0, a_h1, a_l0, a_l1, s_h0, s_h1, s_l0, s_l1;
    a_h0.u = *(const uint4v*)&Ahi[c32][0  + kofA];
    a_h1.u = *(const uint4v*)&Ahi[c32][16 + kofA];
    a_l0.u = *(const uint4v*)&Alo[c32][0  + kofA];
    a_l1.u = *(const uint4v*)&Alo[c32][16 + kofA];
    s_h0.u = *(const uint4v*)&Ghi[c32][0  + kofA];
    s_h1.u = *(const uint4v*)&Ghi[c32][16 + kofA];
    s_l0.u = *(const uint4v*)&Glo[c32][0  + kofA];
    s_l1.u = *(const uint4v*)&Glo[c32][16 + kofA];
    f32x16 t1a, t1b;
    #pragma unroll
    for (int r=0;r<16;++r){ t1a[r] = 0.f; t1b[r] = 0.f; }
    t1a = mfma32(s_h0.b, a_h0.b, t1a);
    t1a = mfma32(s_h0.b, a_l0.b, t1a);
    t1a = mfma32(s_l0.b, a_h0.b, t1a);
    t1b = mfma32(s_h1.b, a_h1.b, t1b);
    t1b = mfma32(s_h1.b, a_l1.b, t1b);
    t1b = mfma32(s_l1.b, a_h1.b, t1b);
    float uu[16];
    #pragma unroll
    for (int r=0;r<16;++r) uu[r] = t1a[r] + t1b[r];
    // mu_p = A*mu + B*u
    float part = 0.f;
    {
      float4 m0 = *(const float4*)&muf[kofA];
      float4 m1 = *(const float4*)&muf[kofA+4];
      float4 m2 = *(const float4*)&muf[16+kofA];
      float4 m3 = *(const float4*)&muf[16+kofA+4];
      part = fmaf(blof(a_h0.u.x,a_l0.u.x), m0.x, part);
      part = fmaf(bhif(a_h0.u.x,a_l0.u.x), m0.y, part);
      part = fmaf(blof(a_h0.u.y,a_l0.u.y), m0.z, part);
      part = fmaf(bhif(a_h0.u.y,a_l0.u.y), m0.w, part);
      part = fmaf(blof(a_h0.u.z,a_l0.u.z), m1.x, part);
      part = fmaf(bhif(a_h0.u.z,a_l0.u.z), m1.y, part);
      part = fmaf(blof(a_h0.u.w,a_l0.u.w), m1.z, part);
      part = fmaf(bhif(a_h0.u.w,a_l0.u.w), m1.w, part);
      part = fmaf(blof(a_h1.u.x,a_l1.u.x), m2.x, part);
      part = fmaf(bhif(a_h1.u.x,a_l1.u.x), m2.y, part);
      part = fmaf(blof(a_h1.u.y,a_l1.u.y), m2.z, part);
      part = fmaf(bhif(a_h1.u.y,a_l1.u.y), m2.w, part);
      part = fmaf(blof(a_h1.u.z,a_l1.u.z), m3.x, part);
      part = fmaf(bhif(a_h1.u.z,a_l1.u.z), m3.y, part);
      part = fmaf(blof(a_h1.u.w,a_l1.u.w), m3.z, part);
      part = fmaf(bhif(a_h1.u.w,a_l1.u.w), m3.w, part);
    }
    part += __shfl_xor(part, 32);
    {
      float4 b0 = *(const float4*)&Bm[c32][0];
      float4 b1 = *(const float4*)&Bm[c32][4];
      float4 u0 = *(const float4*)&uvf[0];
      float4 u1 = *(const float4*)&uvf[4];
      part = fmaf(b0.x,u0.x, fmaf(b0.y,u0.y, fmaf(b0.z,u0.z, fmaf(b0.w,u0.w, part))));
      part = fmaf(b1.x,u1.x, fmaf(b1.y,u1.y, fmaf(b1.z,u1.z, fmaf(b1.w,u1.w, part))));
    }
    if (l < 32){ mupf[c32] = part; wsMu[bt*32 + c32] = part; }

    // ---- P2': Sigma_p = A * U + Q  (B-frags of U built in-register) ----
    U8 b_h0, b_h1, b_l0, b_l1;
    DLAYOUT_TO_BFRAG(uu, h, b_h0, b_l0, b_h1, b_l1);
    f32x16 spa, spb;
    #pragma unroll
    for (int r=0;r<16;++r){ spa[r] = 0.f; spb[r] = 0.f; }
    spa = mfma32(a_h0.b, b_h0.b, spa);
    spa = mfma32(a_h0.b, b_l0.b, spa);
    spa = mfma32(a_l0.b, b_h0.b, spa);
    spb = mfma32(a_h1.b, b_h1.b, spb);
    spb = mfma32(a_h1.b, b_l1.b, spb);
    spb = mfma32(a_l1.b, b_h1.b, spb);
    f32x16 sp;
    #pragma unroll
    for (int r=0;r<16;++r){
      int rr = (r&3) + 8*(r>>2) + 4*h;
      sp[r] = spa[r] + spb[r] + ((rr == c32) ? 0.01f : 0.f);
    }
    {
      float* wp = wsSig + (bt*32 + c32)*32;
      *(float4*)(wp + 0  + 4*h) = make_float4(sp[0], sp[1], sp[2], sp[3]);
      *(float4*)(wp + 8  + 4*h) = make_float4(sp[4], sp[5], sp[6], sp[7]);
      *(float4*)(wp + 16 + 4*h) = make_float4(sp[8], sp[9], sp[10],sp[11]);
      *(float4*)(wp + 24 + 4*h) = make_float4(sp[12],sp[13],sp[14],sp[15]);
      #pragma unroll
      for (int gq=0; gq<4; ++gq){
        uint2v hw, lw;
        hw.x = hipack(sp[4*gq+0], sp[4*gq+1]); hw.y = hipack(sp[4*gq+2], sp[4*gq+3]);
        lw.x = lopack(sp[4*gq+0], sp[4*gq+1]); lw.y = lopack(sp[4*gq+2], sp[4*gq+3]);
        *(uint2v*)&Phi[c32][8*gq + 4*h] = hw;
        *(uint2v*)&Plo[c32][8*gq + 4*h] = lw;
      }
    }

    // ---- P3: CS = C * Sigma_p ----
    U8 c_h, c_l, p_h0, p_l0, p_h1, p_l1;
    c_h.u  = *(const uint4v*)&Chi[c16][kofC];
    c_l.u  = *(const uint4v*)&Clo[c16][kofC];
    p_h0.u = *(const uint4v*)&Phi[c16][kofC];
    p_l0.u = *(const uint4v*)&Plo[c16][kofC];
    p_h1.u = *(const uint4v*)&Phi[16+c16][kofC];
    p_l1.u = *(const uint4v*)&Plo[16+c16][kofC];
    f32x4 cs0, cs1;
    #pragma unroll
    for (int r=0;r<4;++r){ cs0[r]=0.f; cs1[r]=0.f; }
    cs0 = mfma16(c_h.b, p_h0.b, cs0);
    cs0 = mfma16(c_h.b, p_l0.b, cs0);
    cs0 = mfma16(c_l.b, p_h0.b, cs0);
    cs1 = mfma16(c_h.b, p_h1.b, cs1);
    cs1 = mfma16(c_h.b, p_l1.b, cs1);
    cs1 = mfma16(c_l.b, p_h1.b, cs1);
    #pragma unroll
    for (int r=0;r<4;++r){
      int rr = q4*4 + r;
      ZP[rr][c16]     = packhl(cs0[r]);
      ZP[rr][16+c16]  = packhl(cs1[r]);
      CSf[rr][c16]    = cs0[r];
      CSf[rr][16+c16] = cs1[r];
    }
    {
      uint2v hw0, lw0, hw1, lw1;
      hw0.x = hipack(cs0[0],cs0[1]); hw0.y = hipack(cs0[2],cs0[3]);
      lw0.x = lopack(cs0[0],cs0[1]); lw0.y = lopack(cs0[2],cs0[3]);
      hw1.x = hipack(cs1[0],cs1[1]); hw1.y = hipack(cs1[2],cs1[3]);
      lw1.x = lopack(cs1[0],cs1[1]); lw1.y = lopack(cs1[2],cs1[3]);
      *(uint2v*)&Yhi[c16][q4*4]    = hw0; *(uint2v*)&Ylo[c16][q4*4]    = lw0;
      *(uint2v*)&Yhi[16+c16][q4*4] = hw1; *(uint2v*)&Ylo[16+c16][q4*4] = lw1;
    }
    // r = y - C*mu_p
    {
      float prr = 0.f;
      float4 m0 = *(const float4*)&mupf[kofC];
      float4 m1 = *(const float4*)&mupf[kofC+4];
      prr = fmaf(blof(c_h.u.x,c_l.u.x), m0.x, prr);
      prr = fmaf(bhif(c_h.u.x,c_l.u.x), m0.y, prr);
      prr = fmaf(blof(c_h.u.y,c_l.u.y), m0.z, prr);
      prr = fmaf(bhif(c_h.u.y,c_l.u.y), m0.w, prr);
      prr = fmaf(blof(c_h.u.z,c_l.u.z), m1.x, prr);
      prr = fmaf(bhif(c_h.u.z,c_l.u.z), m1.y, prr);
      prr = fmaf(blof(c_h.u.w,c_l.u.w), m1.z, prr);
      prr = fmaf(bhif(c_h.u.w,c_l.u.w), m1.w, prr);
      prr += __shfl_xor(prr, 16);
      prr += __shfl_xor(prr, 32);
      if (l < 16) rvf[l] = yvf[l] - prr;
    }

    // ---- P4: S = CS * C^T + R ----
    {
      U8 z_h, z_l;
      uint4v pz0 = *(const uint4v*)&ZP[c16][kofC];
      uint4v pz1 = *(const uint4v*)&ZP[c16][kofC+4];
      z_h.u = frag_hi(pz0, pz1); z_l.u = frag_lo(pz0, pz1);
      f32x4 ss;
      #pragma unroll
      for (int r=0;r<4;++r) ss[r] = 0.f;
      ss = mfma16(z_h.b, c_h.b, ss);
      ss = mfma16(z_h.b, c_l.b, ss);
      ss = mfma16(z_l.b, c_h.b, ss);
      #pragma unroll
      for (int r=0;r<4;++r){
        int rr = q4*4 + r;
        SLf[rr][c16] = ss[r] + ((rr == c16) ? 0.01f : 0.f);
      }
    }

    // ---- prefetch next-step inputs ----
    float4 pa0, pa1, pa2, pa3, pc0, pc1, pbv;
    float py = 0.f, pu = 0.f;
    pa0=pa1=pa2=pa3=make_float4(0.f,0.f,0.f,0.f);
    pc0=pc1=pbv=make_float4(0.f,0.f,0.f,0.f);
    if (t + 1 < TT){
      const float* ap = Ag + (bt+1)*1024 + rA*32 + cA;
      pa0 = *(const float4*)(ap+0);  pa1 = *(const float4*)(ap+4);
      pa2 = *(const float4*)(ap+8);  pa3 = *(const float4*)(ap+12);
      const float* cp = Cg + (bt+1)*512 + rC*32 + cC;
      pc0 = *(const float4*)(cp+0);  pc1 = *(const float4*)(cp+4);
      pbv = *(const float4*)(Bg + (bt+1)*256 + (l>>1)*8 + (l&1)*4);
      if (l < 16) py = Yg[(bt+1)*16 + l];
      if (l < 8)  pu = Ug[(bt+1)*8 + l];
    }

    // ---- P5: column-layout Gauss-Jordan via readlane (no shuffles) ----
    {
      float aug[16];
      if (l < 16){
        #pragma unroll
        for (int i=0;i<16;++i) aug[i] = 0.5f*(SLf[i][l] + SLf[l][i]);
      } else if (l < 48){
        #pragma unroll
        for (int i=0;i<16;++i) aug[i] = CSf[i][l-16];
      } else {
        #pragma unroll
        for (int i=0;i<16;++i) aug[i] = 0.f;
      }
      #pragma unroll
      for (int k=0;k<16;++k){
        float piv = rdl(aug[k], k);
        float q = -aug[k] * frcp(piv);
        #pragma unroll
        for (int i=0;i<16;++i){
          if (i == k) continue;
          float s = rdl(aug[i], k);
          aug[i] = fmaf(q, s, aug[i]);
        }
      }
      if (l >= 16 && l < 48){
        #pragma unroll
        for (int i=0;i<16;++i){
          float d = rdl(aug[i], i);
          KtTP[l-16][i] = packhl(-aug[i] * frcp(d));
        }
      }
    }

    // ---- P6: Sigma_f = Sigma_p - CS^T * Kt ----
    f32x16 sf = sp;
    {
      U8 y_h, y_l, kt_h, kt_l;
      y_h.u = *(const uint4v*)&Yhi[c32][8*h];
      y_l.u = *(const uint4v*)&Ylo[c32][8*h];
      uint4v k0, k1;
      { uint2v a0 = *(const uint2v*)&KtTP[c32][8*h];
        uint2v a1 = *(const uint2v*)&KtTP[c32][8*h+2];
        uint2v a2 = *(const uint2v*)&KtTP[c32][8*h+4];
        uint2v a3 = *(const uint2v*)&KtTP[c32][8*h+6];
        k0.x=a0.x; k0.y=a0.y; k0.z=a1.x; k0.w=a1.y;
        k1.x=a2.x; k1.y=a2.y; k1.z=a3.x; k1.w=a3.y; }
      kt_h.u = frag_hi(k0, k1); kt_l.u = frag_lo(k0, k1);
      sf = mfma32(y_h.b, kt_h.b, sf);
      sf = mfma32(y_h.b, kt_l.b, sf);
      sf = mfma32(y_l.b, kt_h.b, sf);
    }
    #pragma unroll
    for (int gq=0; gq<4; ++gq){
      uint2v hw, lw;
      hw.x = hipack(sf[4*gq+0], sf[4*gq+1]); hw.y = hipack(sf[4*gq+2], sf[4*gq+3]);
      lw.x = lopack(sf[4*gq+0], sf[4*gq+1]); lw.y = lopack(sf[4*gq+2], sf[4*gq+3]);
      *(uint2v*)&Ghi[c32][8*gq + 4*h] = hw;
      *(uint2v*)&Glo[c32][8*gq + 4*h] = lw;
    }
    {
      float* ob = outg + (bt*32)*33;
      #pragma unroll
      for (int r=0;r<16;++r){
        int rr = (r&3) + 8*(r>>2) + 4*h;
        ob[rr*33 + 1 + c32] = sf[r];
      }
      float mf = mupf[c32];
      #pragma unroll
      for (int p=0;p<16;++p){
        unsigned int w = KtTP[c32][p];
        mf = fmaf(-unpk(w), rvf[p], mf);
      }
      if (l < 32){ muf[c32] = mf; ob[c32*33] = mf; }
    }

    // ---- P7: stage next-step inputs ----
    if (t + 1 < TT){
      split16(pa0, pa1, pa2, pa3, &Ahi[rA][cA], &Alo[rA][cA]);
      split8(pc0, pc1, &Chi[rC][cC], &Clo[rC][cC]);
      *(float4*)&Bm[l>>1][(l&1)*4] = pbv;
      if (l < 16) yvf[l] = py;
      if (l < 8)  uvf[l] = pu;
    }
  }
}

// ===== Smoother precompute: 1 WAVE per (b,t), readlane-GJ inversion, MFMA =====
__global__ __launch_bounds__(64) void kf_precomp(
    const float* __restrict__ Ag, float* __restrict__ outg,
    float* __restrict__ wsSig, const float* __restrict__ wsMu)
{
  const int t = blockIdx.x;        // 0..126
  const int b = blockIdx.y;
  const int l = threadIdx.x;
  const int c32 = l & 31;
  const int h = l >> 5;
  const int kofA = h * 8;

  __shared__ __align__(16) float        Sffr[1060];
  __shared__ __align__(16) unsigned int MmP[32][34];
  __shared__ __align__(16) unsigned int VPT[32][34];
  __shared__ __align__(16) unsigned int JP [32][34];
  __shared__ float mp1f[32];

  const size_t bt = (size_t)b*TT + t;
  float* osl = outg + bt*1056;

  {
    const float4* src = (const float4*)osl;
    #pragma unroll
    for (int q=0;q<4;++q) *(float4*)&Sffr[(l + 64*q)*4] = src[l + 64*q];
    if (l < 8) *(float4*)&Sffr[(l + 256)*4] = src[l + 256];
    if (l < 32) mp1f[l] = wsMu[(bt+1)*32 + l];
  }

  float aug[32];
  if (l < 32){
    const float* pp = wsSig + (bt+1)*1024 + (size_t)l*32;
    #pragma unroll
    for (int q=0;q<8;++q){
      float4 v = *(const float4*)(pp + 4*q);
      aug[4*q]=v.x; aug[4*q+1]=v.y; aug[4*q+2]=v.z; aug[4*q+3]=v.w;
    }
  } else {
    #pragma unroll
    for (int i=0;i<32;++i) aug[i] = (i == l-32) ? 1.f : 0.f;
  }

  U8 a_h0, a_l0, a_h1, a_l1;
  {
    const float* ap = Ag + bt*1024 + c32*32;
    float4 v0 = *(const float4*)(ap + kofA);
    float4 v1 = *(const float4*)(ap + kofA + 4);
    float4 v2 = *(const float4*)(ap + 16 + kofA);
    float4 v3 = *(const float4*)(ap + 16 + kofA + 4);
    MK8(v0, v1, a_h0, a_l0);
    MK8(v2, v3, a_h1, a_l1);
  }
  U8 s_h0, s_l0, s_h1, s_l1;
  {
    const float* rp = &Sffr[c32*33 + 1];
    float4 v0, v1, v2, v3;
    v0.x=rp[kofA+0]; v0.y=rp[kofA+1]; v0.z=rp[kofA+2]; v0.w=rp[kofA+3];
    v1.x=rp[kofA+4]; v1.y=rp[kofA+5]; v1.z=rp[kofA+6]; v1.w=rp[kofA+7];
    v2.x=rp[16+kofA+0]; v2.y=rp[16+kofA+1]; v2.z=rp[16+kofA+2]; v2.w=rp[16+kofA+3];
    v3.x=rp[16+kofA+4]; v3.y=rp[16+kofA+5]; v3.z=rp[16+kofA+6]; v3.w=rp[16+kofA+7];
    MK8(v0, v1, s_h0, s_l0);
    MK8(v2, v3, s_h1, s_l1);
  }

  f32x16 ma, mb;
  #pragma unroll
  for (int r=0;r<16;++r){ ma[r]=0.f; mb[r]=0.f; }
  ma = mfma32(s_h0.b, a_h0.b, ma);
  ma = mfma32(s_h0.b, a_l0.b, ma);
  ma = mfma32(s_l0.b, a_h0.b, ma);
  mb = mfma32(s_h1.b, a_h1.b, mb);
  mb = mfma32(s_h1.b, a_l1.b, mb);
  mb = mfma32(s_l1.b, a_h1.b, mb);
  #pragma unroll
  for (int r=0;r<16;++r){
    int rr = (r&3) + 8*(r>>2) + 4*h;
    MmP[rr][c32] = packhl(ma[r] + mb[r]);
  }

  #pragma unroll
  for (int k=0;k<32;++k){
    float piv = rdl(aug[k], k);
    float q = -aug[k] * frcp(piv);
    #pragma unroll
    for (int i=0;i<32;++i){
      if (i == k) continue;
      float s = rdl(aug[i], k);
      aug[i] = fmaf(q, s, aug[i]);
    }
  }
  if (l >= 32){
    #pragma unroll
    for (int i=0;i<32;++i){
      float d = rdl(aug[i], i);
      VPT[l-32][i] = packhl(aug[i] * frcp(d));
    }
  }

  U8 m_h0, m_l0, m_h1, m_l1;
  {
    uint4v ua, ub, uc, ud;
    ua.x=MmP[c32][kofA+0]; ua.y=MmP[c32][kofA+1]; ua.z=MmP[c32][kofA+2]; ua.w=MmP[c32][kofA+3];
    ub.x=MmP[c32][kofA+4]; ub.y=MmP[c32][kofA+5]; ub.z=MmP[c32][kofA+6]; ub.w=MmP[c32][kofA+7];
    uc.x=MmP[c32][16+kofA+0]; uc.y=MmP[c32][16+kofA+1]; uc.z=MmP[c32][16+kofA+2]; uc.w=MmP[c32][16+kofA+3];
    ud.x=MmP[c32][16+kofA+4]; ud.y=MmP[c32][16+kofA+5]; ud.z=MmP[c32][16+kofA+6]; ud.w=MmP[c32][16+kofA+7];
    m_h0.u = frag_hi(ua, ub); m_l0.u = frag_lo(ua, ub);
    m_h1.u = frag_hi(uc, ud); m_l1.u = frag_lo(uc, ud);
  }
  U8 v_h0, v_l0, v_h1, v_l1;
  {
    uint4v ua, ub, uc, ud;
    ua.x=VPT[c32][kofA+0]; ua.y=VPT[c32][kofA+1]; ua.z=VPT[c32][kofA+2]; ua.w=VPT[c32][kofA+3];
    ub.x=VPT[c32][kofA+4]; ub.y=VPT[c32][kofA+5]; ub.z=VPT[c32][kofA+6]; ub.w=VPT[c32][kofA+7];
    uc.x=VPT[c32][16+kofA+0]; uc.y=VPT[c32][16+kofA+1]; uc.z=VPT[c32][16+kofA+2]; uc.w=VPT[c32][16+kofA+3];
    ud.x=VPT[c32][16+kofA+4]; ud.y=VPT[c32][16+kofA+5]; ud.z=VPT[c32][16+kofA+6]; ud.w=VPT[c32][16+kofA+7];
    v_h0.u = frag_hi(ua, ub); v_l0.u = frag_lo(ua, ub);
    v_h1.u = frag_hi(uc, ud); v_l1.u = frag_lo(uc, ud);
  }
  f32x16 ja, jb;
  #pragma unroll
  for (int r=0;r<16;++r){ ja[r]=0.f; jb[r]=0.f; }
  ja = mfma32(m_h0.b, v_h0.b, ja);
  ja = mfma32(m_h0.b, v_l0.b, ja);
  ja = mfma32(m_l0.b, v_h0.b, ja);
  jb = mfma32(m_h1.b, v_h1.b, jb);
  jb = mfma32(m_h1.b, v_l1.b, jb);
  jb = mfma32(m_l1.b, v_h1.b, jb);
  {
    float* jws = wsSig + (bt+1)*1024;
    #pragma unroll
    for (int r=0;r<16;++r){
      int rr = (r&3) + 8*(r>>2) + 4*h;
      float jv = ja[r] + jb[r];
      jws[rr*32 + c32] = jv;
      JP[rr][c32] = packhl(-jv);
    }
  }

  U8 nj_h0, nj_l0, nj_h1, nj_l1;
  {
    uint4v ua, ub, uc, ud;
    ua.x=JP[c32][kofA+0]; ua.y=JP[c32][kofA+1]; ua.z=JP[c32][kofA+2]; ua.w=JP[c32][kofA+3];
    ub.x=JP[c32][kofA+4]; ub.y=JP[c32][kofA+5]; ub.z=JP[c32][kofA+6]; ub.w=JP[c32][kofA+7];
    uc.x=JP[c32][16+kofA+0]; uc.y=JP[c32][16+kofA+1]; uc.z=JP[c32][16+kofA+2]; uc.w=JP[c32][16+kofA+3];
    ud.x=JP[c32][16+kofA+4]; ud.y=JP[c32][16+kofA+5]; ud.z=JP[c32][16+kofA+6]; ud.w=JP[c32][16+kofA+7];
    nj_h0.u = frag_hi(ua, ub); nj_l0.u = frag_lo(ua, ub);
    nj_h1.u = frag_hi(uc, ud); nj_l1.u = frag_lo(uc, ud);
  }
  f32x16 ea, eb;
  #pragma unroll
  for (int r=0;r<16;++r){
    int rr = (r&3) + 8*(r>>2) + 4*h;
    ea[r] = Sffr[rr*33 + 1 + c32];
    eb[r] = 0.f;
  }
  ea = mfma32(m_h0.b, nj_h0.b, ea);
  ea = mfma32(m_h0.b, nj_l0.b, ea);
  ea = mfma32(m_l0.b, nj_h0.b, ea);
  eb = mfma32(m_h1.b, nj_h1.b, eb);
  eb = mfma32(m_h1.b, nj_l1.b, eb);
  eb = mfma32(m_l1.b, nj_h1.b, eb);
  #pragma unroll
  for (int r=0;r<16;++r){
    int rr = (r&3) + 8*(r>>2) + 4*h;
    osl[rr*33 + 1 + c32] = ea[r] + eb[r];
  }

  {
    float e2 = Sffr[c32*33];
    #pragma unroll
    for (int k=0;k<32;++k)
      e2 = fmaf(unpk(JP[c32][k]), mp1f[k], e2);
    if (l < 32) osl[c32*33] = e2;
  }
}

// ===== Backward smoother: 1 WAVE per batch, in-register W' forwarding =====
__global__ __launch_bounds__(64) void kf_backward(
    float* __restrict__ outg, const float* __restrict__ wsSig)
{
  const int l   = threadIdx.x;
  const int b   = blockIdx.x;
  const int c32 = l & 31;
  const int h   = l >> 5;
  const int kofA = h * 8;
  const int rA = l >> 1, cA = (l & 1) << 4;

  __shared__ __align__(16) unsigned short Jhi[32][40], Jlo[32][40];
  __shared__ __align__(16) unsigned int   SP[32][36];
  __shared__ float muv[32];

  const size_t base = (size_t)b * TT;

  float er[16]; float ev;
  {
    const float* os = outg + (base + TT - 1)*32*33;
    const float* rp = os + rA*33 + 1 + cA;
    float4 v0 = *(const float4*)(rp+0), v1 = *(const float4*)(rp+4),
           v2 = *(const float4*)(rp+8), v3 = *(const float4*)(rp+12);
    uint4v u0, u1;
    u0.x = packhl(v0.x); u0.y = packhl(v0.y); u0.z = packhl(v0.z); u0.w = packhl(v0.w);
    u1.x = packhl(v1.x); u1.y = packhl(v1.y); u1.z = packhl(v1.z); u1.w = packhl(v1.w);
    *(uint4v*)&SP[rA][cA+0] = u0; *(uint4v*)&SP[rA][cA+4] = u1;
    u0.x = packhl(v2.x); u0.y = packhl(v2.y); u0.z = packhl(v2.z); u0.w = packhl(v2.w);
    u1.x = packhl(v3.x); u1.y = packhl(v3.y); u1.z = packhl(v3.z); u1.w = packhl(v3.w);
    *(uint4v*)&SP[rA][cA+8] = u0; *(uint4v*)&SP[rA][cA+12] = u1;
    if (l < 32) muv[l] = os[l*33];
    const float* jp = wsSig + ((base + TT - 1)*32 + rA)*32 + cA;
    split16(*(const float4*)(jp+0), *(const float4*)(jp+4),
            *(const float4*)(jp+8), *(const float4*)(jp+12),
            &Jhi[rA][cA], &Jlo[rA][cA]);
    const float* oe = outg + (base + TT - 2)*32*33;
    #pragma unroll
    for (int r=0;r<16;++r){
      int rr = (r&3) + 8*(r>>2) + 4*h;
      er[r] = oe[rr*33 + 1 + c32];
    }
    ev = (l < 32) ? oe[l*33] : 0.f;
  }

  for (int t = TT - 2; t >= 0; --t) {
    float4 pj0, pj1, pj2, pj3; float ner[16]; float nev = 0.f;
    if (t > 0) {
      const float* jp = wsSig + ((base + t)*32 + rA)*32 + cA;
      pj0 = *(const float4*)(jp+0);  pj1 = *(const float4*)(jp+4);
      pj2 = *(const float4*)(jp+8);  pj3 = *(const float4*)(jp+12);
      const float* oe = outg + (base + t - 1)*32*33;
      #pragma unroll
      for (int r=0;r<16;++r){
        int rr = (r&3) + 8*(r>>2) + 4*h;
        ner[r] = oe[rr*33 + 1 + c32];
      }
      if (l < 32) nev = oe[l*33];
    } else {
      pj0=pj1=pj2=pj3=make_float4(0.f,0.f,0.f,0.f);
      #pragma unroll
      for (int r=0;r<16;++r) ner[r] = 0.f;
    }

    U8 a_h0, a_h1, a_l0, a_l1;
    a_h0.u = *(const uint4v*)&Jhi[c32][0  + kofA];
    a_h1.u = *(const uint4v*)&Jhi[c32][16 + kofA];
    a_l0.u = *(const uint4v*)&Jlo[c32][0  + kofA];
    a_l1.u = *(const uint4v*)&Jlo[c32][16 + kofA];
    U8 s_h0, s_l0, s_h1, s_l1;
    {
      uint4v ua = *(const uint4v*)&SP[c32][0  + kofA];
      uint4v ub = *(const uint4v*)&SP[c32][4  + kofA];
      uint4v uc = *(const uint4v*)&SP[c32][16 + kofA];
      uint4v ud = *(const uint4v*)&SP[c32][20 + kofA];
      s_h0.u = frag_hi(ua, ub); s_l0.u = frag_lo(ua, ub);
      s_h1.u = frag_hi(uc, ud); s_l1.u = frag_lo(uc, ud);
    }
    // W' = Sigma_s * J^T  (A-op = Sigma_s rows via symmetry, B-op = J rows)
    f32x16 wa, wb;
    #pragma unroll
    for (int r=0;r<16;++r){ wa[r]=0.f; wb[r]=0.f; }
    wa = mfma32(s_h0.b, a_h0.b, wa);
    wa = mfma32(s_h0.b, a_l0.b, wa);
    wa = mfma32(s_l0.b, a_h0.b, wa);
    wb = mfma32(s_h1.b, a_h1.b, wb);
    wb = mfma32(s_h1.b, a_l1.b, wb);
    wb = mfma32(s_l1.b, a_h1.b, wb);
    float ww[16];
    #pragma unroll
    for (int r=0;r<16;++r) ww[r] = wa[r] + wb[r];

    // G = E + J * W'  (B-frags of W' built in-register)
    U8 bw_h0, bw_l0, bw_h1, bw_l1;
    DLAYOUT_TO_BFRAG(ww, h, bw_h0, bw_l0, bw_h1, bw_l1);
    f32x16 ga, gb;
    #pragma unroll
    for (int r=0;r<16;++r){ ga[r] = er[r]; gb[r] = 0.f; }
    ga = mfma32(a_h0.b, bw_h0.b, ga);
    ga = mfma32(a_h0.b, bw_l0.b, ga);
    ga = mfma32(a_l0.b, bw_h0.b, ga);
    gb = mfma32(a_h1.b, bw_h1.b, gb);
    gb = mfma32(a_h1.b, bw_l1.b, gb);
    gb = mfma32(a_l1.b, bw_h1.b, gb);

    // mu_s = e + J * mu_s
    float part = 0.f;
    {
      float4 m0 = *(const float4*)&muv[kofA];
      float4 m1 = *(const float4*)&muv[kofA+4];
      float4 m2 = *(const float4*)&muv[16+kofA];
      float4 m3 = *(const float4*)&muv[16+kofA+4];
      part = fmaf(blof(a_h0.u.x,a_l0.u.x), m0.x, part);
      part = fmaf(bhif(a_h0.u.x,a_l0.u.x), m0.y, part);
      part = fmaf(blof(a_h0.u.y,a_l0.u.y), m0.z, part);
      part = fmaf(bhif(a_h0.u.y,a_l0.u.y), m0.w, part);
      part = fmaf(blof(a_h0.u.z,a_l0.u.z), m1.x, part);
      part = fmaf(bhif(a_h0.u.z,a_l0.u.z), m1.y, part);
      part = fmaf(blof(a_h0.u.w,a_l0.u.w), m1.z, part);
      part = fmaf(bhif(a_h0.u.w,a_l0.u.w), m1.w, part);
      part = fmaf(blof(a_h1.u.x,a_l1.u.x), m2.x, part);
      part = fmaf(bhif(a_h1.u.x,a_l1.u.x), m2.y, part);
      part = fmaf(blof(a_h1.u.y,a_l1.u.y), m2.z, part);
      part = fmaf(bhif(a_h1.u.y,a_l1.u.y), m2.w, part);
      part = fmaf(blof(a_h1.u.z,a_l1.u.z), m3.x, part);
      part = fmaf(bhif(a_h1.u.z,a_l1.u.z), m3.y, part);
      part = fmaf(blof(a_h1.u.w,a_l1.u.w), m3.z, part);
      part = fmaf(bhif(a_h1.u.w,a_l1.u.w), m3.w, part);
    }
    part += __shfl_xor(part, 32);
    float mn = ev + part;

    {
      float* ob = outg + ((base + t)*32)*33;
      #pragma unroll
      for (int r=0;r<16;++r){
        int rr = (r&3) + 8*(r>>2) + 4*h;
        ob[rr*33 + 1 + c32] = ga[r] + gb[r];
      }
      #pragma unroll
      for (int gq=0; gq<4; ++gq){
        uint4v uw;
        uw.x = packhl(ga[4*gq+0]+gb[4*gq+0]); uw.y = packhl(ga[4*gq+1]+gb[4*gq+1]);
        uw.z = packhl(ga[4*gq+2]+gb[4*gq+2]); uw.w = packhl(ga[4*gq+3]+gb[4*gq+3]);
        *(uint4v*)&SP[c32][8*gq + 4*h] = uw;
      }
      if (l < 32){ muv[l] = mn; ob[l*33] = mn; }
    }

    if (t > 0){
      split16(pj0, pj1, pj2, pj3, &Jhi[rA][cA], &Jlo[rA][cA]);
      #pragma unroll
      for (int r=0;r<16;++r) er[r] = ner[r];
      ev = nev;
    }
  }
}

extern "C" void kernel_launch(void* const* d_in, const int* in_sizes, int n_in,
                              void* d_out, int out_size, void* d_ws, size_t ws_size,
                              hipStream_t stream) {
  (void)in_sizes; (void)n_in; (void)out_size; (void)ws_size;
  const float* Yg   = (const float*)d_in[0];
  const float* Ug   = (const float*)d_in[1];
  const float* Ag   = (const float*)d_in[2];
  const float* Bg   = (const float*)d_in[3];
  const float* Cg   = (const float*)d_in[4];
  const float* mu0g = (const float*)d_in[5];
  const float* S0g  = (const float*)d_in[6];
  float* outg = (float*)d_out;
  float* wsSig = (float*)d_ws;
  float* wsMu  = wsSig + (size_t)NB*TT*NSZ*NSZ;

  hipLaunchKernelGGL(kf_forward, dim3(NB), dim3(64), 0, stream,
                     Yg, Ug, Ag, Bg, Cg, mu0g, S0g, outg, wsSig, wsMu);
  hipLaunchKernelGGL(kf_precomp, dim3(TT-1, NB), dim3(64), 0, stream,
                     Ag, outg, wsSig, wsMu);
  hipLaunchKernelGGL(kf_backward, dim3(NB), dim3(64), 0, stream,
                     outg, wsSig);
}